// Round 2
// baseline (758.312 us; speedup 1.0000x reference)
//
#include <hip/hip_runtime.h>
#include <hip/hip_bf16.h>

typedef __hip_bfloat16 bf16;
typedef short bf16x8 __attribute__((ext_vector_type(8)));
typedef float f32x4 __attribute__((ext_vector_type(4)));

#define MFMA16(a, b, c) __builtin_amdgcn_mfma_f32_16x16x32_bf16((a), (b), (c), 0, 0, 0)

__device__ __forceinline__ short f2bs(float f) {
  bf16 h = __float2bfloat16(f);
  return __builtin_bit_cast(short, h);
}

// ---------------------------------------------------------------------------
// Detect whether float inputs are stored as f32 (flag=1) or bf16 (flag=0).
// Wqa ~ N(0, 0.02): as bf16 all |x| < 1e3. As f32, even shorts are mantissa
// garbage -> huge/NaN bf16 patterns with ~certainty over 2048 shorts.
// ---------------------------------------------------------------------------
__global__ void detect_mode(const void* wqa, int* flag) {
  __shared__ int any;
  if (threadIdx.x == 0) any = 0;
  __syncthreads();
  const bf16* p = (const bf16*)wqa;
  #pragma unroll
  for (int k = 0; k < 8; ++k) {
    float v = __bfloat162float(p[threadIdx.x * 8 + k]);
    if (!(fabsf(v) <= 1e3f)) any = 1;  // catches NaN too
  }
  __syncthreads();
  if (threadIdx.x == 0) *flag = any;
}

// Convert one float input to packed bf16 (8 elems/thread). n8 = n/8.
__global__ void cvt_in(const void* __restrict__ src, bf16* __restrict__ dst,
                       int n8, const int* __restrict__ flag) {
  int i = blockIdx.x * 256 + threadIdx.x;
  if (i >= n8) return;
  if (*flag) {
    const float4* s = (const float4*)src;
    float4 a = s[2 * i], b = s[2 * i + 1];
    union { uint4 v; short s[8]; } o;
    o.s[0] = f2bs(a.x); o.s[1] = f2bs(a.y); o.s[2] = f2bs(a.z); o.s[3] = f2bs(a.w);
    o.s[4] = f2bs(b.x); o.s[5] = f2bs(b.y); o.s[6] = f2bs(b.z); o.s[7] = f2bs(b.w);
    ((uint4*)dst)[i] = o.v;
  } else {
    ((uint4*)dst)[i] = ((const uint4*)src)[i];
  }
}

// ---------------------------------------------------------------------------
// Generic GEMM: C[M,N] = A[M,K](bf16, row stride lda) @ B[K,N](bf16).
// BM=128, BN=64, BK=32. 256 threads = 4 waves. If f32out&&*f32out, C is f32.
// ---------------------------------------------------------------------------
__global__ __launch_bounds__(256) void gemm_bf16(
    const bf16* __restrict__ A, const bf16* __restrict__ B, void* __restrict__ Cv,
    int M, int N, int K, int lda, const int* __restrict__ f32out)
{
  __shared__ __align__(16) short As[128][40];
  __shared__ __align__(16) short Bt[64][40];   // Bt[n][k], k XOR-swizzled by (n>>3)&3
  const int tid = threadIdx.x;
  const int lane = tid & 63, w = tid >> 6;
  const int l15 = lane & 15, l4 = lane >> 4;
  const long bm = (long)blockIdx.y * 128;
  const long bn = (long)blockIdx.x * 64;

  f32x4 acc[2][4] = {};

  const int arow = tid >> 1, ac8 = (tid & 1) * 16;
  const int bkr = tid >> 3, bn8 = (tid & 7) * 8;

  for (int k0 = 0; k0 < K; k0 += 32) {
    __syncthreads();
    {
      const uint4* src = (const uint4*)(A + (bm + arow) * (long)lda + k0 + ac8);
      *(uint4*)&As[arow][ac8]     = src[0];
      *(uint4*)&As[arow][ac8 + 8] = src[1];
    }
    {
      union { uint4 v; short s[8]; } u;
      u.v = *(const uint4*)(B + (long)(k0 + bkr) * N + bn + bn8);
      const int swz = ((bn8 >> 3) & 3) << 3;
      #pragma unroll
      for (int i = 0; i < 8; ++i)
        Bt[bn8 + i][bkr ^ swz] = u.s[i];
    }
    __syncthreads();
    bf16x8 a0 = *(const bf16x8*)&As[w * 32 + l15][l4 * 8];
    bf16x8 a1 = *(const bf16x8*)&As[w * 32 + 16 + l15][l4 * 8];
    #pragma unroll
    for (int ni = 0; ni < 4; ++ni) {
      int n = ni * 16 + l15;
      int kb = (l4 * 8) ^ (((n >> 3) & 3) << 3);
      bf16x8 bb = *(const bf16x8*)&Bt[n][kb];
      acc[0][ni] = MFMA16(a0, bb, acc[0][ni]);
      acc[1][ni] = MFMA16(a1, bb, acc[1][ni]);
    }
  }
  const bool of32 = f32out && (*f32out != 0);
  #pragma unroll
  for (int mi = 0; mi < 2; ++mi)
    #pragma unroll
    for (int ni = 0; ni < 4; ++ni)
      #pragma unroll
      for (int r = 0; r < 4; ++r) {
        long row = bm + w * 32 + mi * 16 + l4 * 4 + r;
        long col = bn + ni * 16 + l15;
        float v = acc[mi][ni][r];
        if (of32) ((float*)Cv)[row * N + col] = v;
        else      ((bf16*)Cv)[row * N + col] = __float2bfloat16(v);
      }
}

// ---------------------------------------------------------------------------
template<int C>
__global__ __launch_bounds__(256) void rmsnorm_ip(bf16* __restrict__ x,
                                                  const bf16* __restrict__ w,
                                                  int stride)
{
  constexpr int PER = C / 256;
  const int row = blockIdx.x, tid = threadIdx.x;
  bf16* xr = x + (long)row * stride;
  float v[PER];
  float ss = 0.f;
  #pragma unroll
  for (int k = 0; k < PER; ++k) {
    float f = __bfloat162float(xr[tid + k * 256]);
    v[k] = f; ss += f * f;
  }
  #pragma unroll
  for (int off = 1; off < 64; off <<= 1) ss += __shfl_xor(ss, off);
  __shared__ float red[4];
  if ((tid & 63) == 0) red[tid >> 6] = ss;
  __syncthreads();
  float tot = red[0] + red[1] + red[2] + red[3];
  float scale = rsqrtf(tot / (float)C + 1e-6f);
  #pragma unroll
  for (int k = 0; k < PER; ++k)
    xr[tid + k * 256] =
        __float2bfloat16(v[k] * scale * __bfloat162float(w[tid + k * 256]));
}

// ---------------------------------------------------------------------------
// GPT-J interleaved RoPE. pos = t & 2047 (positions = tile(arange(S), B)).
// ---------------------------------------------------------------------------
__global__ __launch_bounds__(512) void rope_kernel(bf16* __restrict__ q,
                                                   const bf16* __restrict__ kvns,
                                                   bf16* __restrict__ kpe)
{
  const int t = blockIdx.x;
  const int h = threadIdx.x >> 5, i = threadIdx.x & 31;
  float p = (float)(t & 2047);
  float freq = powf(10000.0f, -(float)i / 32.0f);
  float sn, cs;
  sincosf(p * freq, &sn, &cs);
  bf16* b = q + (long)t * 3072 + h * 192 + 128 + 2 * i;
  float x1 = __bfloat162float(b[0]), x2 = __bfloat162float(b[1]);
  b[0] = __float2bfloat16(x1 * cs - x2 * sn);
  b[1] = __float2bfloat16(x2 * cs + x1 * sn);
  if (h == 0) {
    const bf16* kb = kvns + (long)t * 576 + 512 + 2 * i;
    float y1 = __bfloat162float(kb[0]), y2 = __bfloat162float(kb[1]);
    bf16* kd = kpe + (long)t * 64 + 2 * i;
    kd[0] = __float2bfloat16(y1 * cs - y2 * sn);
    kd[1] = __float2bfloat16(y2 * cs + y1 * sn);
  }
}

// ---------------------------------------------------------------------------
// Causal flash attention. Grid (S/64, B*H). 4 waves; wave w owns 16 q-rows.
// ---------------------------------------------------------------------------
__global__ __launch_bounds__(256) void attn_kernel(const bf16* __restrict__ q,
                                                   const bf16* __restrict__ kv,
                                                   const bf16* __restrict__ kpe,
                                                   bf16* __restrict__ attn)
{
  __shared__ __align__(16) short Ks[32][200];
  __shared__ __align__(16) short Vt[128][40];
  __shared__ __align__(16) short Ps[4][16][40];
  const float SCALE = 0.07216878364870323f;     // 192^-0.5
  const int tid = threadIdx.x;
  const int lane = tid & 63, w = tid >> 6;
  const int l15 = lane & 15, l4 = lane >> 4;
  const int qb = blockIdx.x;
  const int bh = blockIdx.y, b = bh >> 4, h = bh & 15;

  bf16x8 qf[6];
  {
    long t = (long)b * 2048 + qb * 64 + w * 16 + l15;
    const short* qrow = (const short*)q + t * 3072 + h * 192;
    #pragma unroll
    for (int kc = 0; kc < 6; ++kc)
      qf[kc] = *(const bf16x8*)(qrow + kc * 32 + l4 * 8);
  }

  f32x4 o[8] = {};
  float m[4] = {-1e30f, -1e30f, -1e30f, -1e30f};
  float lsum[4] = {0.f, 0.f, 0.f, 0.f};
  const int rmaxw = qb * 64 + w * 16 + 15;
  const int nch = qb * 2 + 2;

  for (int ck = 0; ck < nch; ++ck) {
    const int k0 = ck * 32;
    __syncthreads();
    {
      int row = tid >> 3, seg = tid & 7;
      const uint4* srcn = (const uint4*)((const short*)kv +
          ((long)(b * 2048 + k0 + row) * 16 + h) * 256 + seg * 16);
      *(uint4*)&Ks[row][seg * 16]     = srcn[0];
      *(uint4*)&Ks[row][seg * 16 + 8] = srcn[1];
      const uint4* srcp = (const uint4*)((const short*)kpe +
          (long)(b * 2048 + k0 + row) * 64 + seg * 8);
      *(uint4*)&Ks[row][128 + seg * 8] = srcp[0];
    }
    {
      int key = tid >> 3, seg = tid & 7;
      union { uint4 v; short s[8]; } u0, u1;
      const uint4* src = (const uint4*)((const short*)kv +
          ((long)(b * 2048 + k0 + key) * 16 + h) * 256 + 128 + seg * 16);
      u0.v = src[0]; u1.v = src[1];
      #pragma unroll
      for (int i = 0; i < 8; ++i) Vt[seg * 16 + i][key] = u0.s[i];
      #pragma unroll
      for (int i = 0; i < 8; ++i) Vt[seg * 16 + 8 + i][key] = u1.s[i];
    }
    __syncthreads();

    if (k0 <= rmaxw) {
      f32x4 s0 = {}, s1 = {};
      #pragma unroll
      for (int kc = 0; kc < 6; ++kc) {
        bf16x8 b0 = *(const bf16x8*)&Ks[l15][kc * 32 + l4 * 8];
        bf16x8 b1 = *(const bf16x8*)&Ks[16 + l15][kc * 32 + l4 * 8];
        s0 = MFMA16(qf[kc], b0, s0);
        s1 = MFMA16(qf[kc], b1, s1);
      }
      const int rowb = qb * 64 + w * 16 + l4 * 4;
      #pragma unroll
      for (int r = 0; r < 4; ++r) {
        int row = rowb + r;
        float v0 = (k0 + l15      <= row) ? s0[r] * SCALE : -1e30f;
        float v1 = (k0 + 16 + l15 <= row) ? s1[r] * SCALE : -1e30f;
        float cm = fmaxf(v0, v1);
        #pragma unroll
        for (int off = 1; off < 16; off <<= 1) cm = fmaxf(cm, __shfl_xor(cm, off));
        float mn = fmaxf(m[r], cm);
        float alpha = __expf(m[r] - mn);
        float p0 = __expf(v0 - mn), p1 = __expf(v1 - mn);
        float ps = p0 + p1;
        #pragma unroll
        for (int off = 1; off < 16; off <<= 1) ps += __shfl_xor(ps, off);
        lsum[r] = lsum[r] * alpha + ps;
        m[r] = mn;
        #pragma unroll
        for (int f = 0; f < 8; ++f) o[f][r] *= alpha;
        Ps[w][l4 * 4 + r][l15]      = f2bs(p0);
        Ps[w][l4 * 4 + r][16 + l15] = f2bs(p1);
      }
      asm volatile("s_waitcnt lgkmcnt(0)" ::: "memory");
      __builtin_amdgcn_sched_barrier(0);
      bf16x8 pa = *(const bf16x8*)&Ps[w][l15][l4 * 8];
      #pragma unroll
      for (int f = 0; f < 8; ++f) {
        bf16x8 bv = *(const bf16x8*)&Vt[f * 16 + l15][l4 * 8];
        o[f] = MFMA16(pa, bv, o[f]);
      }
    }
  }

  #pragma unroll
  for (int r = 0; r < 4; ++r) {
    float inv = 1.0f / lsum[r];
    long t = (long)b * 2048 + qb * 64 + w * 16 + l4 * 4 + r;
    bf16* dst = attn + t * 2048 + h * 128;
    #pragma unroll
    for (int f = 0; f < 8; ++f)
      dst[f * 16 + l15] = __float2bfloat16(o[f][r] * inv);
  }
}

// ---------------------------------------------------------------------------
extern "C" void kernel_launch(void* const* d_in, const int* in_sizes, int n_in,
                              void* d_out, int out_size, void* d_ws, size_t ws_size,
                              hipStream_t stream) {
  const int T = 4096;
  int* flag = (int*)d_ws;
  bf16* base = (bf16*)((char*)d_ws + 16);

  // converted inputs
  bf16* hs_c   = base;                      // 4096*2048
  bf16* Wqa_c  = hs_c   + 8388608;          // 2048*1536
  bf16* qln_c  = Wqa_c  + 3145728;          // 1536
  bf16* Wqb_c  = qln_c  + 1536;             // 1536*3072
  bf16* Wkva_c = Wqb_c  + 4718592;          // 2048*576
  bf16* kvln_c = Wkva_c + 1179648;          // 512
  bf16* Wkvb_c = kvln_c + 512;              // 512*4096
  bf16* Wo_c   = Wkvb_c + 2097152;          // 2048*2048
  // intermediates
  bf16* ckq  = Wo_c + 4194304;              // T x 1536
  bf16* q    = ckq  + (size_t)T * 1536;     // T x 3072
  bf16* kvns = q    + (size_t)T * 3072;     // T x 576
  bf16* kpe  = kvns + (size_t)T * 576;      // T x 64
  bf16* kv   = kpe  + (size_t)T * 64;       // T x 4096
  bf16* attn = kv   + (size_t)T * 4096;     // T x 2048

  detect_mode<<<1, 256, 0, stream>>>(d_in[2], flag);

  struct { const void* src; bf16* dst; int n8; } cv[8] = {
    {d_in[1], hs_c,   8388608 / 8}, {d_in[2], Wqa_c,  3145728 / 8},
    {d_in[3], qln_c,  1536 / 8},    {d_in[4], Wqb_c,  4718592 / 8},
    {d_in[5], Wkva_c, 1179648 / 8}, {d_in[6], kvln_c, 512 / 8},
    {d_in[7], Wkvb_c, 2097152 / 8}, {d_in[8], Wo_c,   4194304 / 8},
  };
  for (int i = 0; i < 8; ++i)
    cvt_in<<<(cv[i].n8 + 255) / 256, 256, 0, stream>>>(cv[i].src, cv[i].dst, cv[i].n8, flag);

  gemm_bf16<<<dim3(1536 / 64, T / 128), 256, 0, stream>>>(hs_c, Wqa_c, ckq, T, 1536, 2048, 2048, nullptr);
  rmsnorm_ip<1536><<<T, 256, 0, stream>>>(ckq, qln_c, 1536);
  gemm_bf16<<<dim3(3072 / 64, T / 128), 256, 0, stream>>>(ckq, Wqb_c, q, T, 3072, 1536, 1536, nullptr);
  gemm_bf16<<<dim3(576 / 64, T / 128), 256, 0, stream>>>(hs_c, Wkva_c, kvns, T, 576, 2048, 2048, nullptr);
  rmsnorm_ip<512><<<T, 256, 0, stream>>>(kvns, kvln_c, 576);
  gemm_bf16<<<dim3(4096 / 64, T / 128), 256, 0, stream>>>(kvns, Wkvb_c, kv, T, 4096, 512, 576, nullptr);
  rope_kernel<<<T, 512, 0, stream>>>(q, kvns, kpe);
  attn_kernel<<<dim3(2048 / 64, 32), 256, 0, stream>>>(q, kv, kpe, attn);
  gemm_bf16<<<dim3(2048 / 64, T / 128), 256, 0, stream>>>(attn, Wo_c, d_out, T, 2048, 2048, 2048, flag);
}

// Round 7
// 555.859 us; speedup vs baseline: 1.3642x; 1.3642x over previous
//
#include <hip/hip_runtime.h>
#include <hip/hip_bf16.h>

typedef __hip_bfloat16 bf16;
typedef short bf16x8 __attribute__((ext_vector_type(8)));
typedef float f32x4 __attribute__((ext_vector_type(4)));

#define MFMA16(a, b, c) __builtin_amdgcn_mfma_f32_16x16x32_bf16((a), (b), (c), 0, 0, 0)

__device__ __forceinline__ short f2bs(float f) {
  bf16 h = __float2bfloat16(f);
  return __builtin_bit_cast(short, h);
}

// ---------------------------------------------------------------------------
// f32 -> bf16 conversion, 8 elems/thread, vectorized.
// ---------------------------------------------------------------------------
__global__ __launch_bounds__(256) void cvt_f32_bf16(const float* __restrict__ src,
                                                    bf16* __restrict__ dst, int n8) {
  int i = blockIdx.x * 256 + threadIdx.x;
  if (i >= n8) return;
  const float4* s = (const float4*)src;
  float4 a = s[2 * i], b = s[2 * i + 1];
  union { uint4 v; short sh[8]; } o;
  o.sh[0] = f2bs(a.x); o.sh[1] = f2bs(a.y); o.sh[2] = f2bs(a.z); o.sh[3] = f2bs(a.w);
  o.sh[4] = f2bs(b.x); o.sh[5] = f2bs(b.y); o.sh[6] = f2bs(b.z); o.sh[7] = f2bs(b.w);
  ((uint4*)dst)[i] = o.v;
}

// ---------------------------------------------------------------------------
// gemm_v3: C[M,N] = A[M,K] @ B[K,N]. BM=BN=128, BK=32. 4 waves, quadrant per
// wave. r2-proven staging formulas, tile widened. F32OUT selects C dtype.
// ---------------------------------------------------------------------------
template<bool F32OUT>
__global__ __launch_bounds__(256) void gemm_v3(
    const bf16* __restrict__ A, const bf16* __restrict__ B, void* __restrict__ Cv,
    int N, int K, int lda)
{
  __shared__ __align__(16) short As[128][40];
  __shared__ __align__(16) short Bt[128][40];   // Bt[n][k], k XOR-swizzled by (n>>3)&3
  const int tid = threadIdx.x, lane = tid & 63, w = tid >> 6;
  const int l15 = lane & 15, l4 = lane >> 4;
  const int wr = w >> 1, wc = w & 1;
  const long bm = (long)blockIdx.y * 128, bn = (long)blockIdx.x * 128;
  f32x4 acc[4][4] = {};

  const int arow = tid >> 1, ac8 = (tid & 1) * 16;
  const int bkr = tid >> 4, bn8 = (tid & 15) * 8;

  for (int k0 = 0; k0 < K; k0 += 32) {
    __syncthreads();
    {  // stage A tile 128x32 (2 x 16B per thread)
      const uint4* src = (const uint4*)(A + (bm + arow) * (long)lda + k0 + ac8);
      *(uint4*)&As[arow][ac8]     = src[0];
      *(uint4*)&As[arow][ac8 + 8] = src[1];
    }
    {  // stage B tile 32x128 transposed (2 k-rows per thread)
      const int swz = ((bn8 >> 3) & 3) << 3;
      union { uint4 v; short s[8]; } u;
      u.v = *(const uint4*)(B + (long)(k0 + bkr) * N + bn + bn8);
      #pragma unroll
      for (int i = 0; i < 8; ++i) Bt[bn8 + i][bkr ^ swz] = u.s[i];
      u.v = *(const uint4*)(B + (long)(k0 + 16 + bkr) * N + bn + bn8);
      #pragma unroll
      for (int i = 0; i < 8; ++i) Bt[bn8 + i][(16 + bkr) ^ swz] = u.s[i];
    }
    __syncthreads();
    bf16x8 a[4], b[4];
    #pragma unroll
    for (int mi = 0; mi < 4; ++mi)
      a[mi] = *(const bf16x8*)&As[wr * 64 + mi * 16 + l15][l4 * 8];
    #pragma unroll
    for (int ni = 0; ni < 4; ++ni) {
      int n = wc * 64 + ni * 16 + l15;
      int kb = (l4 * 8) ^ (((n >> 3) & 3) << 3);
      b[ni] = *(const bf16x8*)&Bt[n][kb];
    }
    #pragma unroll
    for (int mi = 0; mi < 4; ++mi)
      #pragma unroll
      for (int ni = 0; ni < 4; ++ni)
        acc[mi][ni] = MFMA16(a[mi], b[ni], acc[mi][ni]);
  }
  #pragma unroll
  for (int mi = 0; mi < 4; ++mi)
    #pragma unroll
    for (int ni = 0; ni < 4; ++ni)
      #pragma unroll
      for (int r = 0; r < 4; ++r) {
        long row = bm + wr * 64 + mi * 16 + l4 * 4 + r;
        long col = bn + wc * 64 + ni * 16 + l15;
        float v = acc[mi][ni][r];
        if (F32OUT) ((float*)Cv)[row * N + col] = v;
        else        ((bf16*)Cv)[row * N + col] = __float2bfloat16(v);
      }
}

// ---------------------------------------------------------------------------
// r2-proven GEMM (BM=128, BN=64, BK=32) for the N=576 case. Verbatim.
// ---------------------------------------------------------------------------
__global__ __launch_bounds__(256) void gemm_bf16(
    const bf16* __restrict__ A, const bf16* __restrict__ B, bf16* __restrict__ C,
    int N, int K, int lda)
{
  __shared__ __align__(16) short As[128][40];
  __shared__ __align__(16) short Bt[64][40];
  const int tid = threadIdx.x;
  const int lane = tid & 63, w = tid >> 6;
  const int l15 = lane & 15, l4 = lane >> 4;
  const long bm = (long)blockIdx.y * 128;
  const long bn = (long)blockIdx.x * 64;

  f32x4 acc[2][4] = {};
  const int arow = tid >> 1, ac8 = (tid & 1) * 16;
  const int bkr = tid >> 3, bn8 = (tid & 7) * 8;

  for (int k0 = 0; k0 < K; k0 += 32) {
    __syncthreads();
    {
      const uint4* src = (const uint4*)(A + (bm + arow) * (long)lda + k0 + ac8);
      *(uint4*)&As[arow][ac8]     = src[0];
      *(uint4*)&As[arow][ac8 + 8] = src[1];
    }
    {
      union { uint4 v; short s[8]; } u;
      u.v = *(const uint4*)(B + (long)(k0 + bkr) * N + bn + bn8);
      const int swz = ((bn8 >> 3) & 3) << 3;
      #pragma unroll
      for (int i = 0; i < 8; ++i)
        Bt[bn8 + i][bkr ^ swz] = u.s[i];
    }
    __syncthreads();
    bf16x8 a0 = *(const bf16x8*)&As[w * 32 + l15][l4 * 8];
    bf16x8 a1 = *(const bf16x8*)&As[w * 32 + 16 + l15][l4 * 8];
    #pragma unroll
    for (int ni = 0; ni < 4; ++ni) {
      int n = ni * 16 + l15;
      int kb = (l4 * 8) ^ (((n >> 3) & 3) << 3);
      bf16x8 bb = *(const bf16x8*)&Bt[n][kb];
      acc[0][ni] = MFMA16(a0, bb, acc[0][ni]);
      acc[1][ni] = MFMA16(a1, bb, acc[1][ni]);
    }
  }
  #pragma unroll
  for (int mi = 0; mi < 2; ++mi)
    #pragma unroll
    for (int ni = 0; ni < 4; ++ni)
      #pragma unroll
      for (int r = 0; r < 4; ++r) {
        long row = bm + w * 32 + mi * 16 + l4 * 4 + r;
        long col = bn + ni * 16 + l15;
        C[row * N + col] = __float2bfloat16(acc[mi][ni][r]);
      }
}

// ---------------------------------------------------------------------------
template<int C>
__global__ __launch_bounds__(256) void rmsnorm_ip(bf16* __restrict__ x,
                                                  const bf16* __restrict__ w,
                                                  int stride)
{
  constexpr int PER = C / 256;
  const int row = blockIdx.x, tid = threadIdx.x;
  bf16* xr = x + (long)row * stride;
  float v[PER];
  float ss = 0.f;
  #pragma unroll
  for (int k = 0; k < PER; ++k) {
    float f = __bfloat162float(xr[tid + k * 256]);
    v[k] = f; ss += f * f;
  }
  #pragma unroll
  for (int off = 1; off < 64; off <<= 1) ss += __shfl_xor(ss, off);
  __shared__ float red[4];
  if ((tid & 63) == 0) red[tid >> 6] = ss;
  __syncthreads();
  float tot = red[0] + red[1] + red[2] + red[3];
  float scale = rsqrtf(tot / (float)C + 1e-6f);
  #pragma unroll
  for (int k = 0; k < PER; ++k)
    xr[tid + k * 256] =
        __float2bfloat16(v[k] * scale * __bfloat162float(w[tid + k * 256]));
}

// ---------------------------------------------------------------------------
// GPT-J interleaved RoPE (stride 576). pos = t & 2047.
// ---------------------------------------------------------------------------
__global__ __launch_bounds__(512) void rope_kernel(bf16* __restrict__ q,
                                                   const bf16* __restrict__ kvns,
                                                   bf16* __restrict__ kpe)
{
  const int t = blockIdx.x;
  const int h = threadIdx.x >> 5, i = threadIdx.x & 31;
  float p = (float)(t & 2047);
  float freq = powf(10000.0f, -(float)i / 32.0f);
  float sn, cs;
  sincosf(p * freq, &sn, &cs);
  bf16* b = q + (long)t * 3072 + h * 192 + 128 + 2 * i;
  float x1 = __bfloat162float(b[0]), x2 = __bfloat162float(b[1]);
  b[0] = __float2bfloat16(x1 * cs - x2 * sn);
  b[1] = __float2bfloat16(x2 * cs + x1 * sn);
  if (h == 0) {
    const bf16* kb = kvns + (long)t * 576 + 512 + 2 * i;
    float y1 = __bfloat162float(kb[0]), y2 = __bfloat162float(kb[1]);
    bf16* kd = kpe + (long)t * 64 + 2 * i;
    kd[0] = __float2bfloat16(y1 * cs - y2 * sn);
    kd[1] = __float2bfloat16(y2 * cs + y1 * sn);
  }
}

// ---------------------------------------------------------------------------
// Causal flash attention — r2-proven body, pair loop over q-tiles (p, 31-p)
// for uniform load (66 chunks/block). Grid (16, 32).
// ---------------------------------------------------------------------------
__global__ __launch_bounds__(256) void attn_kernel(const bf16* __restrict__ q,
                                                   const bf16* __restrict__ kv,
                                                   const bf16* __restrict__ kpe,
                                                   bf16* __restrict__ attn)
{
  __shared__ __align__(16) short Ks[32][200];
  __shared__ __align__(16) short Vt[128][40];
  __shared__ __align__(16) short Ps[4][16][40];
  const float SCALE = 0.07216878364870323f;     // 192^-0.5
  const int tid = threadIdx.x;
  const int lane = tid & 63, w = tid >> 6;
  const int l15 = lane & 15, l4 = lane >> 4;
  const int p = blockIdx.x;
  const int bh = blockIdx.y, b = bh >> 4, h = bh & 15;

  #pragma unroll
  for (int half = 0; half < 2; ++half) {
    const int qb = half ? (31 - p) : p;

    bf16x8 qf[6];
    {
      long t = (long)b * 2048 + qb * 64 + w * 16 + l15;
      const short* qrow = (const short*)q + t * 3072 + h * 192;
      #pragma unroll
      for (int kc = 0; kc < 6; ++kc)
        qf[kc] = *(const bf16x8*)(qrow + kc * 32 + l4 * 8);
    }

    f32x4 o[8] = {};
    float m[4] = {-1e30f, -1e30f, -1e30f, -1e30f};
    float lsum[4] = {0.f, 0.f, 0.f, 0.f};
    const int rmaxw = qb * 64 + w * 16 + 15;
    const int nch = qb * 2 + 2;

    for (int ck = 0; ck < nch; ++ck) {
      const int k0 = ck * 32;
      __syncthreads();
      {
        int row = tid >> 3, seg = tid & 7;
        const uint4* srcn = (const uint4*)((const short*)kv +
            ((long)(b * 2048 + k0 + row) * 16 + h) * 256 + seg * 16);
        *(uint4*)&Ks[row][seg * 16]     = srcn[0];
        *(uint4*)&Ks[row][seg * 16 + 8] = srcn[1];
        const uint4* srcp = (const uint4*)((const short*)kpe +
            (long)(b * 2048 + k0 + row) * 64 + seg * 8);
        *(uint4*)&Ks[row][128 + seg * 8] = srcp[0];
      }
      {
        int key = tid >> 3, seg = tid & 7;
        union { uint4 v; short s[8]; } u0, u1;
        const uint4* src = (const uint4*)((const short*)kv +
            ((long)(b * 2048 + k0 + key) * 16 + h) * 256 + 128 + seg * 16);
        u0.v = src[0]; u1.v = src[1];
        #pragma unroll
        for (int i = 0; i < 8; ++i) Vt[seg * 16 + i][key] = u0.s[i];
        #pragma unroll
        for (int i = 0; i < 8; ++i) Vt[seg * 16 + 8 + i][key] = u1.s[i];
      }
      __syncthreads();

      if (k0 <= rmaxw) {
        f32x4 s0 = {}, s1 = {};
        #pragma unroll
        for (int kc = 0; kc < 6; ++kc) {
          bf16x8 b0 = *(const bf16x8*)&Ks[l15][kc * 32 + l4 * 8];
          bf16x8 b1 = *(const bf16x8*)&Ks[16 + l15][kc * 32 + l4 * 8];
          s0 = MFMA16(qf[kc], b0, s0);
          s1 = MFMA16(qf[kc], b1, s1);
        }
        const int rowb = qb * 64 + w * 16 + l4 * 4;
        #pragma unroll
        for (int r = 0; r < 4; ++r) {
          int row = rowb + r;
          float v0 = (k0 + l15      <= row) ? s0[r] * SCALE : -1e30f;
          float v1 = (k0 + 16 + l15 <= row) ? s1[r] * SCALE : -1e30f;
          float cm = fmaxf(v0, v1);
          #pragma unroll
          for (int off = 1; off < 16; off <<= 1) cm = fmaxf(cm, __shfl_xor(cm, off));
          float mn = fmaxf(m[r], cm);
          float alpha = __expf(m[r] - mn);
          float p0 = __expf(v0 - mn), p1 = __expf(v1 - mn);
          float ps = p0 + p1;
          #pragma unroll
          for (int off = 1; off < 16; off <<= 1) ps += __shfl_xor(ps, off);
          lsum[r] = lsum[r] * alpha + ps;
          m[r] = mn;
          #pragma unroll
          for (int f = 0; f < 8; ++f) o[f][r] *= alpha;
          Ps[w][l4 * 4 + r][l15]      = f2bs(p0);
          Ps[w][l4 * 4 + r][16 + l15] = f2bs(p1);
        }
        asm volatile("s_waitcnt lgkmcnt(0)" ::: "memory");
        __builtin_amdgcn_sched_barrier(0);
        bf16x8 pa = *(const bf16x8*)&Ps[w][l15][l4 * 8];
        #pragma unroll
        for (int f = 0; f < 8; ++f) {
          bf16x8 bv = *(const bf16x8*)&Vt[f * 16 + l15][l4 * 8];
          o[f] = MFMA16(pa, bv, o[f]);
        }
      }
    }

    #pragma unroll
    for (int r = 0; r < 4; ++r) {
      float inv = 1.0f / lsum[r];
      long t = (long)b * 2048 + qb * 64 + w * 16 + l4 * 4 + r;
      bf16* dst = attn + t * 2048 + h * 128;
      #pragma unroll
      for (int f = 0; f < 8; ++f)
        dst[f * 16 + l15] = __float2bfloat16(o[f][r] * inv);
    }
  }
}

// ---------------------------------------------------------------------------
extern "C" void kernel_launch(void* const* d_in, const int* in_sizes, int n_in,
                              void* d_out, int out_size, void* d_ws, size_t ws_size,
                              hipStream_t stream) {
  const int T = 4096;

  // converted bf16 inputs in ws
  bf16* hs_c   = (bf16*)d_ws;               // 8388608
  bf16* Wqa_c  = hs_c   + 8388608;          // 3145728
  bf16* qln_c  = Wqa_c  + 3145728;          // 1536
  bf16* Wqb_c  = qln_c  + 1536;             // 4718592
  bf16* Wkva_c = Wqb_c  + 4718592;          // 1179648
  bf16* kvln_c = Wkva_c + 1179648;          // 512
  bf16* Wkvb_c = kvln_c + 512;              // 2097152
  bf16* Wo_c   = Wkvb_c + 2097152;          // 4194304
  // intermediates
  bf16* ckq  = Wo_c + 4194304;              // T x 1536
  bf16* q    = ckq  + (size_t)T * 1536;     // T x 3072
  bf16* kvns = q    + (size_t)T * 3072;     // T x 576
  bf16* kpe  = kvns + (size_t)T * 576;      // T x 64
  bf16* kv   = kpe  + (size_t)T * 64;       // T x 4096
  bf16* attn = kv   + (size_t)T * 4096;     // T x 2048

  // inputs are FLOAT32 on device -> convert everything to bf16 once
  struct { const void* src; bf16* dst; int n8; } cv[8] = {
    {d_in[1], hs_c,   8388608 / 8}, {d_in[2], Wqa_c,  3145728 / 8},
    {d_in[3], qln_c,  1536 / 8},    {d_in[4], Wqb_c,  4718592 / 8},
    {d_in[5], Wkva_c, 1179648 / 8}, {d_in[6], kvln_c, 512 / 8},
    {d_in[7], Wkvb_c, 2097152 / 8}, {d_in[8], Wo_c,   4194304 / 8},
  };
  for (int i = 0; i < 8; ++i)
    cvt_f32_bf16<<<(cv[i].n8 + 255) / 256, 256, 0, stream>>>(
        (const float*)cv[i].src, cv[i].dst, cv[i].n8);

  // 1) ckq = hs @ Wqa
  gemm_v3<false><<<dim3(12, 32), 256, 0, stream>>>(hs_c, Wqa_c, ckq, 1536, 2048, 2048);
  rmsnorm_ip<1536><<<T, 256, 0, stream>>>(ckq, qln_c, 1536);
  // 2) q = q_c @ Wqb
  gemm_v3<false><<<dim3(24, 32), 256, 0, stream>>>(ckq, Wqb_c, q, 3072, 1536, 1536);
  // 3) kvns = hs @ Wkva (N=576)
  gemm_bf16<<<dim3(9, 32), 256, 0, stream>>>(hs_c, Wkva_c, kvns, 576, 2048, 2048);
  rmsnorm_ip<512><<<T, 256, 0, stream>>>(kvns, kvln_c, 576);
  // 4) kv = kv_c_normed @ Wkvb
  gemm_v3<false><<<dim3(32, 32), 256, 0, stream>>>(kvns, Wkvb_c, kv, 4096, 512, 576);
  // 5) rope
  rope_kernel<<<T, 512, 0, stream>>>(q, kvns, kpe);
  // 6) attention (paired q-tiles)
  attn_kernel<<<dim3(16, 32), 256, 0, stream>>>(q, kv, kpe, attn);
  // 7) out = attn @ Wo  -- OUTPUT IS FLOAT32
  gemm_v3<true><<<dim3(16, 32), 256, 0, stream>>>(attn, Wo_c, d_out, 2048, 2048, 2048);
}

// Round 8
// 492.269 us; speedup vs baseline: 1.5404x; 1.1292x over previous
//
#include <hip/hip_runtime.h>
#include <hip/hip_bf16.h>

typedef __hip_bfloat16 bf16;
typedef short bf16x8 __attribute__((ext_vector_type(8)));
typedef float f32x4 __attribute__((ext_vector_type(4)));

#define MFMA16(a, b, c) __builtin_amdgcn_mfma_f32_16x16x32_bf16((a), (b), (c), 0, 0, 0)

__device__ __forceinline__ short f2bs(float f) {
  bf16 h = __float2bfloat16(f);
  return __builtin_bit_cast(short, h);
}

// async global->LDS, 16B per lane; LDS dest = wave-uniform base + lane*16
__device__ __forceinline__ void gload16(const void* g, const void* l) {
  __builtin_amdgcn_global_load_lds(
      (const __attribute__((address_space(1))) unsigned int*)g,
      (__attribute__((address_space(3))) unsigned int*)l, 16, 0, 0);
}

// ---------------------------------------------------------------------------
// f32 -> bf16 flat conversion, 8 elems/thread.
// ---------------------------------------------------------------------------
__global__ __launch_bounds__(256) void cvt_f32_bf16(const float* __restrict__ src,
                                                    bf16* __restrict__ dst, int n8) {
  int i = blockIdx.x * 256 + threadIdx.x;
  if (i >= n8) return;
  const float4* s = (const float4*)src;
  float4 a = s[2 * i], b = s[2 * i + 1];
  union { uint4 v; short sh[8]; } o;
  o.sh[0] = f2bs(a.x); o.sh[1] = f2bs(a.y); o.sh[2] = f2bs(a.z); o.sh[3] = f2bs(a.w);
  o.sh[4] = f2bs(b.x); o.sh[5] = f2bs(b.y); o.sh[6] = f2bs(b.z); o.sh[7] = f2bs(b.w);
  ((uint4*)dst)[i] = o.v;
}

// ---------------------------------------------------------------------------
// Fused f32->bf16 + transpose: dst[N][K](bf16) = src[K][N](f32)^T. 64x64 tiles.
// ---------------------------------------------------------------------------
__global__ __launch_bounds__(256) void t_cvt(const float* __restrict__ src,
                                             bf16* __restrict__ dst, int K, int N) {
  __shared__ __align__(16) short Ts[64][72];
  const long n0 = (long)blockIdx.x * 64, k0 = (long)blockIdx.y * 64;
  const int r = threadIdx.x >> 2, c4 = threadIdx.x & 3;
  const float* s = src + (k0 + r) * (long)N + n0 + c4 * 16;
  #pragma unroll
  for (int j = 0; j < 4; ++j) {
    float4 v = *(const float4*)(s + j * 4);
    Ts[r][c4 * 16 + j * 4 + 0] = f2bs(v.x);
    Ts[r][c4 * 16 + j * 4 + 1] = f2bs(v.y);
    Ts[r][c4 * 16 + j * 4 + 2] = f2bs(v.z);
    Ts[r][c4 * 16 + j * 4 + 3] = f2bs(v.w);
  }
  __syncthreads();
  union { uint4 v; short sh[8]; } o0, o1;
  #pragma unroll
  for (int j = 0; j < 8; ++j) o0.sh[j] = Ts[c4 * 16 + j][r];
  #pragma unroll
  for (int j = 0; j < 8; ++j) o1.sh[j] = Ts[c4 * 16 + 8 + j][r];
  *(uint4*)(dst + (n0 + r) * (long)K + k0 + c4 * 16)     = o0.v;
  *(uint4*)(dst + (n0 + r) * (long)K + k0 + c4 * 16 + 8) = o1.v;
}

// ---------------------------------------------------------------------------
// m97-structure GEMM: C = A[M,K] @ BT[N,K]^T. BM=BN=128, BK=32, 4 waves.
// global_load_lds staging into linear LDS [128][32] (64B pitch).
// ---------------------------------------------------------------------------
template<bool F32OUT>
__global__ __launch_bounds__(256) void gemm_v2(
    const bf16* __restrict__ A, const bf16* __restrict__ BT, void* __restrict__ Cv,
    int N, int K, int lda, int ldb)
{
  __shared__ __align__(16) short As[128 * 32];
  __shared__ __align__(16) short Bs[128 * 32];
  const int tid = threadIdx.x, lane = tid & 63, w = tid >> 6;
  const int l15 = lane & 15, l4 = lane >> 4;
  const int wr = w >> 1, wc = w & 1;
  const long bm = (long)blockIdx.y * 128, bn = (long)blockIdx.x * 128;
  f32x4 acc[4][4] = {};
  const int srow = tid >> 2, sslot = tid & 3;
  const unsigned lb0 = __builtin_amdgcn_readfirstlane((w * 64) * 16);
  const unsigned lb1 = __builtin_amdgcn_readfirstlane((256 + w * 64) * 16);

  for (int k0 = 0; k0 < K; k0 += 32) {
    __syncthreads();
    gload16(A + (bm + srow) * (long)lda + k0 + sslot * 8,       (char*)As + lb0);
    gload16(A + (bm + 64 + srow) * (long)lda + k0 + sslot * 8,  (char*)As + lb1);
    gload16(BT + (bn + srow) * (long)ldb + k0 + sslot * 8,      (char*)Bs + lb0);
    gload16(BT + (bn + 64 + srow) * (long)ldb + k0 + sslot * 8, (char*)Bs + lb1);
    __syncthreads();
    bf16x8 a[4], b[4];
    #pragma unroll
    for (int mi = 0; mi < 4; ++mi)
      a[mi] = *(const bf16x8*)&As[(wr * 64 + mi * 16 + l15) * 32 + l4 * 8];
    #pragma unroll
    for (int ni = 0; ni < 4; ++ni)
      b[ni] = *(const bf16x8*)&Bs[(wc * 64 + ni * 16 + l15) * 32 + l4 * 8];
    #pragma unroll
    for (int mi = 0; mi < 4; ++mi)
      #pragma unroll
      for (int ni = 0; ni < 4; ++ni)
        acc[mi][ni] = MFMA16(a[mi], b[ni], acc[mi][ni]);
  }
  #pragma unroll
  for (int mi = 0; mi < 4; ++mi)
    #pragma unroll
    for (int ni = 0; ni < 4; ++ni)
      #pragma unroll
      for (int r = 0; r < 4; ++r) {
        long row = bm + wr * 64 + mi * 16 + l4 * 4 + r;
        long col = bn + wc * 64 + ni * 16 + l15;
        float v = acc[mi][ni][r];
        if (F32OUT) ((float*)Cv)[row * N + col] = v;
        else        ((bf16*)Cv)[row * N + col] = __float2bfloat16(v);
      }
}

// ---------------------------------------------------------------------------
// r2-proven GEMM (BM=128, BN=64, BK=32), direct B[K][N], for N=576.
// ---------------------------------------------------------------------------
__global__ __launch_bounds__(256) void gemm_bf16(
    const bf16* __restrict__ A, const bf16* __restrict__ B, bf16* __restrict__ C,
    int N, int K, int lda)
{
  __shared__ __align__(16) short As[128][40];
  __shared__ __align__(16) short Bt[64][40];
  const int tid = threadIdx.x;
  const int lane = tid & 63, w = tid >> 6;
  const int l15 = lane & 15, l4 = lane >> 4;
  const long bm = (long)blockIdx.y * 128;
  const long bn = (long)blockIdx.x * 64;

  f32x4 acc[2][4] = {};
  const int arow = tid >> 1, ac8 = (tid & 1) * 16;
  const int bkr = tid >> 3, bn8 = (tid & 7) * 8;

  for (int k0 = 0; k0 < K; k0 += 32) {
    __syncthreads();
    {
      const uint4* src = (const uint4*)(A + (bm + arow) * (long)lda + k0 + ac8);
      *(uint4*)&As[arow][ac8]     = src[0];
      *(uint4*)&As[arow][ac8 + 8] = src[1];
    }
    {
      union { uint4 v; short s[8]; } u;
      u.v = *(const uint4*)(B + (long)(k0 + bkr) * N + bn + bn8);
      const int swz = ((bn8 >> 3) & 3) << 3;
      #pragma unroll
      for (int i = 0; i < 8; ++i)
        Bt[bn8 + i][bkr ^ swz] = u.s[i];
    }
    __syncthreads();
    bf16x8 a0 = *(const bf16x8*)&As[w * 32 + l15][l4 * 8];
    bf16x8 a1 = *(const bf16x8*)&As[w * 32 + 16 + l15][l4 * 8];
    #pragma unroll
    for (int ni = 0; ni < 4; ++ni) {
      int n = ni * 16 + l15;
      int kb = (l4 * 8) ^ (((n >> 3) & 3) << 3);
      bf16x8 bb = *(const bf16x8*)&Bt[n][kb];
      acc[0][ni] = MFMA16(a0, bb, acc[0][ni]);
      acc[1][ni] = MFMA16(a1, bb, acc[1][ni]);
    }
  }
  #pragma unroll
  for (int mi = 0; mi < 2; ++mi)
    #pragma unroll
    for (int ni = 0; ni < 4; ++ni)
      #pragma unroll
      for (int r = 0; r < 4; ++r) {
        long row = bm + w * 32 + mi * 16 + l4 * 4 + r;
        long col = bn + ni * 16 + l15;
        C[row * N + col] = __float2bfloat16(acc[mi][ni][r]);
      }
}

// ---------------------------------------------------------------------------
template<int C>
__global__ __launch_bounds__(256) void rmsnorm_ip(bf16* __restrict__ x,
                                                  const bf16* __restrict__ w,
                                                  int stride)
{
  constexpr int PER = C / 256;
  const int row = blockIdx.x, tid = threadIdx.x;
  bf16* xr = x + (long)row * stride;
  float v[PER];
  float ss = 0.f;
  #pragma unroll
  for (int k = 0; k < PER; ++k) {
    float f = __bfloat162float(xr[tid + k * 256]);
    v[k] = f; ss += f * f;
  }
  #pragma unroll
  for (int off = 1; off < 64; off <<= 1) ss += __shfl_xor(ss, off);
  __shared__ float red[4];
  if ((tid & 63) == 0) red[tid >> 6] = ss;
  __syncthreads();
  float tot = red[0] + red[1] + red[2] + red[3];
  float scale = rsqrtf(tot / (float)C + 1e-6f);
  #pragma unroll
  for (int k = 0; k < PER; ++k)
    xr[tid + k * 256] =
        __float2bfloat16(v[k] * scale * __bfloat162float(w[tid + k * 256]));
}

// ---------------------------------------------------------------------------
// RoPE on q_pe in place. pos = t & 2047.
// ---------------------------------------------------------------------------
__global__ __launch_bounds__(512) void rope_q(bf16* __restrict__ q)
{
  const int t = blockIdx.x;
  const int h = threadIdx.x >> 5, i = threadIdx.x & 31;
  float p = (float)(t & 2047);
  float freq = powf(10000.0f, -(float)i / 32.0f);
  float sn, cs;
  sincosf(p * freq, &sn, &cs);
  bf16* b = q + (long)t * 3072 + h * 192 + 128 + 2 * i;
  float x1 = __bfloat162float(b[0]), x2 = __bfloat162float(b[1]);
  b[0] = __float2bfloat16(x1 * cs - x2 * sn);
  b[1] = __float2bfloat16(x2 * cs + x1 * sn);
}

// ---------------------------------------------------------------------------
// Build Kf[bh][t][192] = [k_nope(128) | roped k_pe(64)], rows pre-swizzled:
// stored 16B-slot s holds content slot s ^ (t&7).
// ---------------------------------------------------------------------------
__global__ __launch_bounds__(256) void prep_kf(const bf16* __restrict__ kv,
                                               const bf16* __restrict__ kvns,
                                               bf16* __restrict__ Kf)
{
  __shared__ short pe[64];
  const int t = blockIdx.x, tid = threadIdx.x;
  if (tid < 32) {
    int i = tid;
    float p = (float)(t & 2047);
    float freq = powf(10000.0f, -(float)i / 32.0f);
    float sn, cs;
    sincosf(p * freq, &sn, &cs);
    float y1 = __bfloat162float(kvns[(long)t * 576 + 512 + 2 * i]);
    float y2 = __bfloat162float(kvns[(long)t * 576 + 512 + 2 * i + 1]);
    pe[2 * i]     = f2bs(y1 * cs - y2 * sn);
    pe[2 * i + 1] = f2bs(y2 * cs + y1 * sn);
  }
  __syncthreads();
  const int b = t >> 11, ts = t & 2047;
  const int swz = t & 7;
  #pragma unroll
  for (int uu = 0; uu < 2; ++uu) {
    int u = uu * 256 + tid;
    if (u >= 384) break;
    int h = u / 24, s = u % 24;
    int cs = s ^ swz;          // content slot (XOR keeps 0..15 / 16..23 ranges)
    uint4 val;
    if (cs < 16) val = *(const uint4*)(kv + (long)t * 4096 + h * 256 + cs * 8);
    else         val = *(const uint4*)&pe[(cs - 16) * 8];
    *(uint4*)(Kf + ((long)(b * 16 + h) * 2048 + ts) * 192 + s * 8) = val;
  }
}

// ---------------------------------------------------------------------------
// Build Vt[bh][d][2048] = V^T, 64-key blocks pre-swizzled: within each 128B
// block, stored 16B-slot s holds content slot s ^ (d&7).
// ---------------------------------------------------------------------------
__global__ __launch_bounds__(256) void prep_vt(const bf16* __restrict__ kv,
                                               bf16* __restrict__ Vt)
{
  __shared__ __align__(16) short Ts[64][136];
  const int kb = blockIdx.x, bh = blockIdx.y, b = bh >> 4, h = bh & 15;
  const int k0 = kb * 64, tid = threadIdx.x;
  #pragma unroll
  for (int j = 0; j < 4; ++j) {
    int u = j * 256 + tid;
    int kr = u >> 4, seg = u & 15;
    *(uint4*)&Ts[kr][seg * 8] = *(const uint4*)(kv +
        (long)(b * 2048 + k0 + kr) * 4096 + h * 256 + 128 + seg * 8);
  }
  __syncthreads();
  #pragma unroll
  for (int j = 0; j < 4; ++j) {
    int u = j * 256 + tid;
    int d = u >> 3, s = u & 7;
    int cs = s ^ (d & 7);
    union { uint4 v; short sh[8]; } o;
    #pragma unroll
    for (int jj = 0; jj < 8; ++jj) o.sh[jj] = Ts[cs * 8 + jj][d];
    *(uint4*)(Vt + ((long)bh * 128 + d) * 2048 + k0 + s * 8) = o.v;
  }
}

// ---------------------------------------------------------------------------
// Causal flash attention. Grid (16 pairs, 32 bh); q-tiles p and 31-p.
// KVBLK=64; K/V staged via global_load_lds from pre-swizzled Kf/Vt.
// ---------------------------------------------------------------------------
__global__ __launch_bounds__(256) void attn_v2(const bf16* __restrict__ q,
                                               const bf16* __restrict__ Kf,
                                               const bf16* __restrict__ Vt,
                                               bf16* __restrict__ attn)
{
  __shared__ __align__(16) short Ks[64 * 192];
  __shared__ __align__(16) short Vs[128 * 64];
  __shared__ __align__(16) short Ps[4][16 * 64];
  const float SC = 0.07216878364870323f;  // 192^-0.5
  const int tid = threadIdx.x, lane = tid & 63, w = tid >> 6;
  const int l15 = lane & 15, l4 = lane >> 4;
  const int p = blockIdx.x, bh = blockIdx.y, b = bh >> 4, h = bh & 15;
  const unsigned lbase = __builtin_amdgcn_readfirstlane(w * 64 * 16);

  #pragma unroll
  for (int half = 0; half < 2; ++half) {
    const int qt = half ? (31 - p) : p;
    const long qrow0 = (long)b * 2048 + qt * 64;

    bf16x8 qf[6];
    {
      const short* qrow = (const short*)q + (qrow0 + w * 16 + l15) * 3072 + h * 192;
      #pragma unroll
      for (int kc = 0; kc < 6; ++kc)
        qf[kc] = *(const bf16x8*)(qrow + kc * 32 + l4 * 8);
    }
    f32x4 o[8] = {};
    float mreg[4] = {-1e30f, -1e30f, -1e30f, -1e30f};
    float ls[4] = {0.f, 0.f, 0.f, 0.f};
    const int nch = qt + 1;

    for (int c = 0; c < nch; ++c) {
      const int k0 = c * 64;
      __syncthreads();
      {  // stage K: 64 rows x 384B contiguous
        const char* ksrc = (const char*)(Kf + ((long)bh * 2048 + k0) * 192);
        #pragma unroll
        for (int j = 0; j < 6; ++j)
          gload16(ksrc + (j * 256 + tid) * 16, (char*)Ks + j * 4096 + lbase);
      }
      {  // stage V: 128 rows x 128B, row stride 4096B
        #pragma unroll
        for (int j = 0; j < 4; ++j) {
          int seg = j * 256 + tid;
          const bf16* vsrc = Vt + ((long)bh * 128 + (seg >> 3)) * 2048 + k0 + (seg & 7) * 8;
          gload16(vsrc, (char*)Vs + j * 4096 + lbase);
        }
      }
      __syncthreads();

      f32x4 s[4] = {};
      #pragma unroll
      for (int kc = 0; kc < 6; ++kc)
        #pragma unroll
        for (int kg = 0; kg < 4; ++kg) {
          int row = kg * 16 + l15;
          int slot = (kc * 4 + l4) ^ (l15 & 7);
          bf16x8 kb = *(const bf16x8*)&Ks[row * 192 + slot * 8];
          s[kg] = MFMA16(qf[kc], kb, s[kg]);
        }

      const bool diag = (c == qt);
      #pragma unroll
      for (int r = 0; r < 4; ++r) {
        const int qrow = l4 * 4 + r;
        const int rowt = qt * 64 + w * 16 + qrow;
        float vk[4];
        #pragma unroll
        for (int kg = 0; kg < 4; ++kg) {
          vk[kg] = s[kg][r] * SC;
          if (diag && (k0 + kg * 16 + l15 > rowt)) vk[kg] = -1e30f;
        }
        float cm = fmaxf(fmaxf(vk[0], vk[1]), fmaxf(vk[2], vk[3]));
        #pragma unroll
        for (int off = 1; off < 16; off <<= 1) cm = fmaxf(cm, __shfl_xor(cm, off));
        float mn = fmaxf(mreg[r], cm);
        float al = __expf(mreg[r] - mn);
        float pk[4], ps = 0.f;
        #pragma unroll
        for (int kg = 0; kg < 4; ++kg) { pk[kg] = __expf(vk[kg] - mn); ps += pk[kg]; }
        #pragma unroll
        for (int off = 1; off < 16; off <<= 1) ps += __shfl_xor(ps, off);
        ls[r] = ls[r] * al + ps;
        mreg[r] = mn;
        #pragma unroll
        for (int f = 0; f < 8; ++f) o[f][r] *= al;
        #pragma unroll
        for (int kg = 0; kg < 4; ++kg) {
          int key = kg * 16 + l15;
          int sl = (key >> 3) ^ (qrow & 7);
          Ps[w][qrow * 64 + sl * 8 + (key & 7)] = f2bs(pk[kg]);
        }
      }
      asm volatile("s_waitcnt lgkmcnt(0)" ::: "memory");
      __builtin_amdgcn_sched_barrier(0);

      #pragma unroll
      for (int ks = 0; ks < 2; ++ks) {
        int psl = (ks * 4 + l4) ^ (l15 & 7);
        bf16x8 pa = *(const bf16x8*)&Ps[w][l15 * 64 + psl * 8];
        #pragma unroll
        for (int f = 0; f < 8; ++f) {
          int vrow = f * 16 + l15;
          int vsl = (ks * 4 + l4) ^ (l15 & 7);
          bf16x8 bv = *(const bf16x8*)&Vs[vrow * 64 + vsl * 8];
          o[f] = MFMA16(pa, bv, o[f]);
        }
      }
    }

    #pragma unroll
    for (int r = 0; r < 4; ++r) {
      float inv = 1.0f / ls[r];
      long t = qrow0 + w * 16 + l4 * 4 + r;
      bf16* dst = attn + t * 2048 + h * 128;
      #pragma unroll
      for (int f = 0; f < 8; ++f)
        dst[f * 16 + l15] = __float2bfloat16(o[f][r] * inv);
    }
  }
}

// ---------------------------------------------------------------------------
extern "C" void kernel_launch(void* const* d_in, const int* in_sizes, int n_in,
                              void* d_out, int out_size, void* d_ws, size_t ws_size,
                              hipStream_t stream) {
  const int T = 4096;
  const float* hs_f   = (const float*)d_in[1];
  const float* Wqa_f  = (const float*)d_in[2];
  const float* qln_f  = (const float*)d_in[3];
  const float* Wqb_f  = (const float*)d_in[4];
  const float* Wkva_f = (const float*)d_in[5];
  const float* kvln_f = (const float*)d_in[6];
  const float* Wkvb_f = (const float*)d_in[7];
  const float* Wo_f   = (const float*)d_in[8];

  bf16* base = (bf16*)d_ws;
  bf16* hs_c   = base;                      // 8388608   (dead after gemm3)  | Kf overlay
  bf16* Wkva_c = base + 8388608;            // 1179648   (dead after gemm3)  |
  bf16* ckq    = base + 9568256;            // 6291456   (dead after gemm2)  |
  bf16* qln_c  = base + 15859712;           // 1536
  bf16* kvln_c = base + 15861248;           // 512
  bf16* arena  = base + 15861760;           // 4718592 (W^T staging, serially reused)
  bf16* q      = base + 20580352;           // 12582912
  bf16* kvns   = base + 33163264;           // 2359296 (T x 576)
  bf16* kv     = base + 35522560;           // 16777216 | attn out overlay (first 8388608)
  bf16* Vt     = base + 52299776;           // 8388608
  bf16* Kf     = base;                      // 12582912, overlays hs_c/Wkva_c/ckq[0:3.0M]
  bf16* attnb  = kv;                        // 8388608, kv dead after preps

  // ---- input conversion ----
  cvt_f32_bf16<<<(8388608 / 8 + 255) / 256, 256, 0, stream>>>(hs_f, hs_c, 8388608 / 8);
  cvt_f32_bf16<<<(1179648 / 8 + 255) / 256, 256, 0, stream>>>(Wkva_f, Wkva_c, 1179648 / 8);
  cvt_f32_bf16<<<1, 256, 0, stream>>>(qln_f, qln_c, 1536 / 8);
  cvt_f32_bf16<<<1, 256, 0, stream>>>(kvln_f, kvln_c, 512 / 8);

  // 1) ckq = hs @ Wqa
  t_cvt<<<dim3(24, 32), 256, 0, stream>>>(Wqa_f, arena, 2048, 1536);
  gemm_v2<false><<<dim3(12, 32), 256, 0, stream>>>(hs_c, arena, ckq, 1536, 2048, 2048, 2048);
  rmsnorm_ip<1536><<<T, 256, 0, stream>>>(ckq, qln_c, 1536);
  // 2) q = q_c @ Wqb
  t_cvt<<<dim3(48, 24), 256, 0, stream>>>(Wqb_f, arena, 1536, 3072);
  gemm_v2<false><<<dim3(24, 32), 256, 0, stream>>>(ckq, arena, q, 3072, 1536, 1536, 1536);
  // 3) kvns = hs @ Wkva (N=576, direct-B kernel)
  gemm_bf16<<<dim3(9, 32), 256, 0, stream>>>(hs_c, Wkva_c, kvns, 576, 2048, 2048);
  rmsnorm_ip<512><<<T, 256, 0, stream>>>(kvns, kvln_c, 576);
  // 4) kv = kv_c_normed @ Wkvb
  t_cvt<<<dim3(64, 8), 256, 0, stream>>>(Wkvb_f, arena, 512, 4096);
  gemm_v2<false><<<dim3(32, 32), 256, 0, stream>>>(kvns, arena, kv, 4096, 512, 576, 512);
  // 5) rope + K/V assembly (hs_c/Wkva_c/ckq dead -> Kf overlay safe)
  rope_q<<<T, 512, 0, stream>>>(q);
  prep_kf<<<T, 256, 0, stream>>>(kv, kvns, Kf);
  prep_vt<<<dim3(32, 32), 256, 0, stream>>>(kv, Vt);
  // 6) attention (writes over kv region; kv dead)
  attn_v2<<<dim3(16, 32), 256, 0, stream>>>(q, Kf, Vt, attnb);
  // 7) out = attn @ Wo (f32 output)
  t_cvt<<<dim3(32, 32), 256, 0, stream>>>(Wo_f, arena, 2048, 2048);
  gemm_v2<true><<<dim3(16, 32), 256, 0, stream>>>(attnb, arena, d_out, 2048, 2048, 2048, 2048);
}

// Round 10
// 488.292 us; speedup vs baseline: 1.5530x; 1.0081x over previous
//
#include <hip/hip_runtime.h>
#include <hip/hip_bf16.h>

typedef __hip_bfloat16 bf16;
typedef short bf16x8 __attribute__((ext_vector_type(8)));
typedef float f32x4 __attribute__((ext_vector_type(4)));

#define MFMA16(a, b, c) __builtin_amdgcn_mfma_f32_16x16x32_bf16((a), (b), (c), 0, 0, 0)

__device__ __forceinline__ short f2bs(float f) {
  bf16 h = __float2bfloat16(f);
  return __builtin_bit_cast(short, h);
}

// async global->LDS, 16B per lane; LDS dest = wave-uniform base + lane*16
__device__ __forceinline__ void gload16(const void* g, const void* l) {
  __builtin_amdgcn_global_load_lds(
      (const __attribute__((address_space(1))) unsigned int*)g,
      (__attribute__((address_space(3))) unsigned int*)l, 16, 0, 0);
}

// ---------------------------------------------------------------------------
__global__ __launch_bounds__(256) void cvt_f32_bf16(const float* __restrict__ src,
                                                    bf16* __restrict__ dst, int n8) {
  int i = blockIdx.x * 256 + threadIdx.x;
  if (i >= n8) return;
  const float4* s = (const float4*)src;
  float4 a = s[2 * i], b = s[2 * i + 1];
  union { uint4 v; short sh[8]; } o;
  o.sh[0] = f2bs(a.x); o.sh[1] = f2bs(a.y); o.sh[2] = f2bs(a.z); o.sh[3] = f2bs(a.w);
  o.sh[4] = f2bs(b.x); o.sh[5] = f2bs(b.y); o.sh[6] = f2bs(b.z); o.sh[7] = f2bs(b.w);
  ((uint4*)dst)[i] = o.v;
}

// ---------------------------------------------------------------------------
// Fused f32->bf16 + transpose: dst[N][K](bf16) = src[K][N](f32)^T. 64x64 tiles.
// ---------------------------------------------------------------------------
__global__ __launch_bounds__(256) void t_cvt(const float* __restrict__ src,
                                             bf16* __restrict__ dst, int K, int N) {
  __shared__ __align__(16) short Ts[64][72];
  const long n0 = (long)blockIdx.x * 64, k0 = (long)blockIdx.y * 64;
  const int r = threadIdx.x >> 2, c4 = threadIdx.x & 3;
  const float* s = src + (k0 + r) * (long)N + n0 + c4 * 16;
  #pragma unroll
  for (int j = 0; j < 4; ++j) {
    float4 v = *(const float4*)(s + j * 4);
    Ts[r][c4 * 16 + j * 4 + 0] = f2bs(v.x);
    Ts[r][c4 * 16 + j * 4 + 1] = f2bs(v.y);
    Ts[r][c4 * 16 + j * 4 + 2] = f2bs(v.z);
    Ts[r][c4 * 16 + j * 4 + 3] = f2bs(v.w);
  }
  __syncthreads();
  union { uint4 v; short sh[8]; } o0, o1;
  #pragma unroll
  for (int j = 0; j < 8; ++j) o0.sh[j] = Ts[c4 * 16 + j][r];
  #pragma unroll
  for (int j = 0; j < 8; ++j) o1.sh[j] = Ts[c4 * 16 + 8 + j][r];
  *(uint4*)(dst + (n0 + r) * (long)K + k0 + c4 * 16)     = o0.v;
  *(uint4*)(dst + (n0 + r) * (long)K + k0 + c4 * 16 + 8) = o1.v;
}

// ---------------------------------------------------------------------------
// m97-structure GEMM: C = A[M,K] @ BT[N,K]^T. BM=BN=128, BK=32, 4 waves.
// ---------------------------------------------------------------------------
template<bool F32OUT>
__global__ __launch_bounds__(256) void gemm_v2(
    const bf16* __restrict__ A, const bf16* __restrict__ BT, void* __restrict__ Cv,
    int N, int K, int lda, int ldb)
{
  __shared__ __align__(16) short As[128 * 32];
  __shared__ __align__(16) short Bs[128 * 32];
  const int tid = threadIdx.x, lane = tid & 63, w = tid >> 6;
  const int l15 = lane & 15, l4 = lane >> 4;
  const int wr = w >> 1, wc = w & 1;
  const long bm = (long)blockIdx.y * 128, bn = (long)blockIdx.x * 128;
  f32x4 acc[4][4] = {};
  const int srow = tid >> 2, sslot = tid & 3;
  const unsigned lb0 = __builtin_amdgcn_readfirstlane((w * 64) * 16);
  const unsigned lb1 = __builtin_amdgcn_readfirstlane((256 + w * 64) * 16);

  for (int k0 = 0; k0 < K; k0 += 32) {
    __syncthreads();
    gload16(A + (bm + srow) * (long)lda + k0 + sslot * 8,       (char*)As + lb0);
    gload16(A + (bm + 64 + srow) * (long)lda + k0 + sslot * 8,  (char*)As + lb1);
    gload16(BT + (bn + srow) * (long)ldb + k0 + sslot * 8,      (char*)Bs + lb0);
    gload16(BT + (bn + 64 + srow) * (long)ldb + k0 + sslot * 8, (char*)Bs + lb1);
    __syncthreads();
    bf16x8 a[4], b[4];
    #pragma unroll
    for (int mi = 0; mi < 4; ++mi)
      a[mi] = *(const bf16x8*)&As[(wr * 64 + mi * 16 + l15) * 32 + l4 * 8];
    #pragma unroll
    for (int ni = 0; ni < 4; ++ni)
      b[ni] = *(const bf16x8*)&Bs[(wc * 64 + ni * 16 + l15) * 32 + l4 * 8];
    #pragma unroll
    for (int mi = 0; mi < 4; ++mi)
      #pragma unroll
      for (int ni = 0; ni < 4; ++ni)
        acc[mi][ni] = MFMA16(a[mi], b[ni], acc[mi][ni]);
  }
  #pragma unroll
  for (int mi = 0; mi < 4; ++mi)
    #pragma unroll
    for (int ni = 0; ni < 4; ++ni)
      #pragma unroll
      for (int r = 0; r < 4; ++r) {
        long row = bm + wr * 64 + mi * 16 + l4 * 4 + r;
        long col = bn + wc * 64 + ni * 16 + l15;
        float v = acc[mi][ni][r];
        if (F32OUT) ((float*)Cv)[row * N + col] = v;
        else        ((bf16*)Cv)[row * N + col] = __float2bfloat16(v);
      }
}

// ---------------------------------------------------------------------------
// r2-proven GEMM (BM=128, BN=64, BK=32), direct B[K][N], for N=576.
// ---------------------------------------------------------------------------
__global__ __launch_bounds__(256) void gemm_bf16(
    const bf16* __restrict__ A, const bf16* __restrict__ B, bf16* __restrict__ C,
    int N, int K, int lda)
{
  __shared__ __align__(16) short As[128][40];
  __shared__ __align__(16) short Bt[64][40];
  const int tid = threadIdx.x;
  const int lane = tid & 63, w = tid >> 6;
  const int l15 = lane & 15, l4 = lane >> 4;
  const long bm = (long)blockIdx.y * 128;
  const long bn = (long)blockIdx.x * 64;

  f32x4 acc[2][4] = {};
  const int arow = tid >> 1, ac8 = (tid & 1) * 16;
  const int bkr = tid >> 3, bn8 = (tid & 7) * 8;

  for (int k0 = 0; k0 < K; k0 += 32) {
    __syncthreads();
    {
      const uint4* src = (const uint4*)(A + (bm + arow) * (long)lda + k0 + ac8);
      *(uint4*)&As[arow][ac8]     = src[0];
      *(uint4*)&As[arow][ac8 + 8] = src[1];
    }
    {
      union { uint4 v; short s[8]; } u;
      u.v = *(const uint4*)(B + (long)(k0 + bkr) * N + bn + bn8);
      const int swz = ((bn8 >> 3) & 3) << 3;
      #pragma unroll
      for (int i = 0; i < 8; ++i)
        Bt[bn8 + i][bkr ^ swz] = u.s[i];
    }
    __syncthreads();
    bf16x8 a0 = *(const bf16x8*)&As[w * 32 + l15][l4 * 8];
    bf16x8 a1 = *(const bf16x8*)&As[w * 32 + 16 + l15][l4 * 8];
    #pragma unroll
    for (int ni = 0; ni < 4; ++ni) {
      int n = ni * 16 + l15;
      int kb = (l4 * 8) ^ (((n >> 3) & 3) << 3);
      bf16x8 bb = *(const bf16x8*)&Bt[n][kb];
      acc[0][ni] = MFMA16(a0, bb, acc[0][ni]);
      acc[1][ni] = MFMA16(a1, bb, acc[1][ni]);
    }
  }
  #pragma unroll
  for (int mi = 0; mi < 2; ++mi)
    #pragma unroll
    for (int ni = 0; ni < 4; ++ni)
      #pragma unroll
      for (int r = 0; r < 4; ++r) {
        long row = bm + w * 32 + mi * 16 + l4 * 4 + r;
        long col = bn + ni * 16 + l15;
        C[row * N + col] = __float2bfloat16(acc[mi][ni][r]);
      }
}

// ---------------------------------------------------------------------------
template<int C>
__global__ __launch_bounds__(256) void rmsnorm_ip(bf16* __restrict__ x,
                                                  const bf16* __restrict__ w,
                                                  int stride)
{
  constexpr int PER = C / 256;
  const int row = blockIdx.x, tid = threadIdx.x;
  bf16* xr = x + (long)row * stride;
  float v[PER];
  float ss = 0.f;
  #pragma unroll
  for (int k = 0; k < PER; ++k) {
    float f = __bfloat162float(xr[tid + k * 256]);
    v[k] = f; ss += f * f;
  }
  #pragma unroll
  for (int off = 1; off < 64; off <<= 1) ss += __shfl_xor(ss, off);
  __shared__ float red[4];
  if ((tid & 63) == 0) red[tid >> 6] = ss;
  __syncthreads();
  float tot = red[0] + red[1] + red[2] + red[3];
  float scale = rsqrtf(tot / (float)C + 1e-6f);
  #pragma unroll
  for (int k = 0; k < PER; ++k)
    xr[tid + k * 256] =
        __float2bfloat16(v[k] * scale * __bfloat162float(w[tid + k * 256]));
}

// ---------------------------------------------------------------------------
__global__ __launch_bounds__(512) void rope_q(bf16* __restrict__ q)
{
  const int t = blockIdx.x;
  const int h = threadIdx.x >> 5, i = threadIdx.x & 31;
  float p = (float)(t & 2047);
  float freq = powf(10000.0f, -(float)i / 32.0f);
  float sn, cs;
  sincosf(p * freq, &sn, &cs);
  bf16* b = q + (long)t * 3072 + h * 192 + 128 + 2 * i;
  float x1 = __bfloat162float(b[0]), x2 = __bfloat162float(b[1]);
  b[0] = __float2bfloat16(x1 * cs - x2 * sn);
  b[1] = __float2bfloat16(x2 * cs + x1 * sn);
}

// ---------------------------------------------------------------------------
// Build Kf[bh][t][192], rows pre-swizzled: stored 16B-slot s = content s^(t&7).
// ---------------------------------------------------------------------------
__global__ __launch_bounds__(256) void prep_kf(const bf16* __restrict__ kv,
                                               const bf16* __restrict__ kvns,
                                               bf16* __restrict__ Kf)
{
  __shared__ short pe[64];
  const int t = blockIdx.x, tid = threadIdx.x;
  if (tid < 32) {
    int i = tid;
    float p = (float)(t & 2047);
    float freq = powf(10000.0f, -(float)i / 32.0f);
    float sn, cs;
    sincosf(p * freq, &sn, &cs);
    float y1 = __bfloat162float(kvns[(long)t * 576 + 512 + 2 * i]);
    float y2 = __bfloat162float(kvns[(long)t * 576 + 512 + 2 * i + 1]);
    pe[2 * i]     = f2bs(y1 * cs - y2 * sn);
    pe[2 * i + 1] = f2bs(y2 * cs + y1 * sn);
  }
  __syncthreads();
  const int b = t >> 11, ts = t & 2047;
  const int swz = t & 7;
  #pragma unroll
  for (int uu = 0; uu < 2; ++uu) {
    int u = uu * 256 + tid;
    if (u >= 384) break;
    int h = u / 24, s = u % 24;
    int cs = s ^ swz;
    uint4 val;
    if (cs < 16) val = *(const uint4*)(kv + (long)t * 4096 + h * 256 + cs * 8);
    else         val = *(const uint4*)&pe[(cs - 16) * 8];
    *(uint4*)(Kf + ((long)(b * 16 + h) * 2048 + ts) * 192 + s * 8) = val;
  }
}

// ---------------------------------------------------------------------------
// Build Vt[bh][d][2048] = V^T, 64-key blocks pre-swizzled by (d&7).
// ---------------------------------------------------------------------------
__global__ __launch_bounds__(256) void prep_vt(const bf16* __restrict__ kv,
                                               bf16* __restrict__ Vt)
{
  __shared__ __align__(16) short Ts[64][136];
  const int kb = blockIdx.x, bh = blockIdx.y, b = bh >> 4, h = bh & 15;
  const int k0 = kb * 64, tid = threadIdx.x;
  #pragma unroll
  for (int j = 0; j < 4; ++j) {
    int u = j * 256 + tid;
    int kr = u >> 4, seg = u & 15;
    *(uint4*)&Ts[kr][seg * 8] = *(const uint4*)(kv +
        (long)(b * 2048 + k0 + kr) * 4096 + h * 256 + 128 + seg * 8);
  }
  __syncthreads();
  #pragma unroll
  for (int j = 0; j < 4; ++j) {
    int u = j * 256 + tid;
    int d = u >> 3, s = u & 7;
    int cs = s ^ (d & 7);
    union { uint4 v; short sh[8]; } o;
    #pragma unroll
    for (int jj = 0; jj < 8; ++jj) o.sh[jj] = Ts[cs * 8 + jj][d];
    *(uint4*)(Vt + ((long)bh * 128 + d) * 2048 + k0 + s * 8) = o.v;
  }
}

// ---------------------------------------------------------------------------
// attn_v3: pipelined staging. V(c) issued before QK (drains at mid-barrier);
// K(c+1) issued after mid-barrier (drains at end-barrier, under PV).
// XCD swizzle: each XCD owns 4 bh's Kf/Vt. Defer-max THR=8. setprio on MFMA.
// ---------------------------------------------------------------------------
__global__ __launch_bounds__(256) void attn_v3(const bf16* __restrict__ q,
                                               const bf16* __restrict__ Kf,
                                               const bf16* __restrict__ Vt,
                                               bf16* __restrict__ attn)
{
  __shared__ __align__(16) short Ks[64 * 192];
  __shared__ __align__(16) short Vs[128 * 64];
  __shared__ __align__(16) short Ps[4][16 * 64];
  const float SC = 0.07216878364870323f;  // 192^-0.5
  const int tid = threadIdx.x, lane = tid & 63, w = tid >> 6;
  const int l15 = lane & 15, l4 = lane >> 4;
  // XCD swizzle: linear id -> XCD gets contiguous 64-block span (4 bh)
  const int lin = blockIdx.y * 16 + blockIdx.x;
  const int swz = (lin & 7) * 64 + (lin >> 3);
  const int p = swz & 15, bh = swz >> 4, b = bh >> 4, h = bh & 15;
  const unsigned lbase = __builtin_amdgcn_readfirstlane(w * 64 * 16);

  #pragma unroll
  for (int half = 0; half < 2; ++half) {
    const int qt = half ? (31 - p) : p;
    const long qrow0 = (long)b * 2048 + qt * 64;

    bf16x8 qf[6];
    {
      const short* qrow = (const short*)q + (qrow0 + w * 16 + l15) * 3072 + h * 192;
      #pragma unroll
      for (int kc = 0; kc < 6; ++kc)
        qf[kc] = *(const bf16x8*)(qrow + kc * 32 + l4 * 8);
    }
    f32x4 o[8] = {};
    float mreg[4] = {-1e30f, -1e30f, -1e30f, -1e30f};
    float ls[4] = {0.f, 0.f, 0.f, 0.f};
    const int nch = qt + 1;

    {  // prologue: stage K chunk 0
      const char* ksrc = (const char*)(Kf + (long)bh * 2048 * 192);
      #pragma unroll
      for (int j = 0; j < 6; ++j)
        gload16(ksrc + (j * 256 + tid) * 16, (char*)Ks + j * 4096 + lbase);
    }
    __syncthreads();

    for (int c = 0; c < nch; ++c) {
      const int k0 = c * 64;
      {  // issue V(c) stage — drains at mid-barrier, hidden under QK+softmax
        #pragma unroll
        for (int j = 0; j < 4; ++j) {
          int seg = j * 256 + tid;
          const bf16* vsrc = Vt + ((long)bh * 128 + (seg >> 3)) * 2048 + k0 + (seg & 7) * 8;
          gload16(vsrc, (char*)Vs + j * 4096 + lbase);
        }
      }
      __builtin_amdgcn_s_setprio(1);
      f32x4 s[4] = {};
      #pragma unroll
      for (int kc = 0; kc < 6; ++kc)
        #pragma unroll
        for (int kg = 0; kg < 4; ++kg) {
          int row = kg * 16 + l15;
          int slot = (kc * 4 + l4) ^ (l15 & 7);
          bf16x8 kb = *(const bf16x8*)&Ks[row * 192 + slot * 8];
          s[kg] = MFMA16(qf[kc], kb, s[kg]);
        }
      __builtin_amdgcn_s_setprio(0);

      const bool diag = (c == qt);
      #pragma unroll
      for (int r = 0; r < 4; ++r) {
        const int qrow = l4 * 4 + r;
        const int rowt = qt * 64 + w * 16 + qrow;
        float vk[4];
        #pragma unroll
        for (int kg = 0; kg < 4; ++kg) {
          vk[kg] = s[kg][r] * SC;
          if (diag && (k0 + kg * 16 + l15 > rowt)) vk[kg] = -1e30f;
        }
        float cm = fmaxf(fmaxf(vk[0], vk[1]), fmaxf(vk[2], vk[3]));
        #pragma unroll
        for (int off = 1; off < 16; off <<= 1) cm = fmaxf(cm, __shfl_xor(cm, off));
        if (__ballot(cm > mreg[r] + 8.0f)) {  // defer-max: rescale only on real growth
          float mn = fmaxf(mreg[r], cm);
          float al = __expf(mreg[r] - mn);
          ls[r] *= al;
          #pragma unroll
          for (int f = 0; f < 8; ++f) o[f][r] *= al;
          mreg[r] = mn;
        }
        float pk[4], ps = 0.f;
        #pragma unroll
        for (int kg = 0; kg < 4; ++kg) { pk[kg] = __expf(vk[kg] - mreg[r]); ps += pk[kg]; }
        #pragma unroll
        for (int off = 1; off < 16; off <<= 1) ps += __shfl_xor(ps, off);
        ls[r] += ps;
        #pragma unroll
        for (int kg = 0; kg < 4; ++kg) {
          int key = kg * 16 + l15;
          int sl = (key >> 3) ^ (qrow & 7);
          Ps[w][qrow * 64 + sl * 8 + (key & 7)] = f2bs(pk[kg]);
        }
      }
      __syncthreads();  // mid-barrier: V(c) landed; all Ks reads done

      if (c + 1 < nch) {  // issue K(c+1) stage — drains at end-barrier, under PV
        const char* ksrc = (const char*)(Kf + ((long)bh * 2048 + k0 + 64) * 192);
        #pragma unroll
        for (int j = 0; j < 6; ++j)
          gload16(ksrc + (j * 256 + tid) * 16, (char*)Ks + j * 4096 + lbase);
      }

      asm volatile("s_waitcnt lgkmcnt(0)" ::: "memory");
      __builtin_amdgcn_sched_barrier(0);
      __builtin_amdgcn_s_setprio(1);
      #pragma unroll
      for (int ks = 0; ks < 2; ++ks) {
        int psl = (ks * 4 + l4) ^ (l15 & 7);
        bf16x8 pa = *(const bf16x8*)&Ps[w][l15 * 64 + psl * 8];
        #pragma unroll
        for (int f = 0; f < 8; ++f) {
          int vrow = f * 16 + l15;
          int vsl = (ks * 4 + l4) ^ (l15 & 7);
          bf16x8 bv = *(const bf16x8*)&Vs[vrow * 64 + vsl * 8];
          o[f] = MFMA16(pa, bv, o[f]);
        }
      }
      __builtin_amdgcn_s_setprio(0);
      __syncthreads();  // end-barrier: K(c+1) landed; Vs reads done
    }

    #pragma unroll
    for (int r = 0; r < 4; ++r) {
      float inv = 1.0f / ls[r];
      long t = qrow0 + w * 16 + l4 * 4 + r;
      bf16* dst = attn + t * 2048 + h * 128;
      #pragma unroll
      for (int f = 0; f < 8; ++f)
        dst[f * 16 + l15] = __float2bfloat16(o[f][r] * inv);
    }
  }
}

// ---------------------------------------------------------------------------
extern "C" void kernel_launch(void* const* d_in, const int* in_sizes, int n_in,
                              void* d_out, int out_size, void* d_ws, size_t ws_size,
                              hipStream_t stream) {
  const int T = 4096;
  const float* hs_f   = (const float*)d_in[1];
  const float* Wqa_f  = (const float*)d_in[2];
  const float* qln_f  = (const float*)d_in[3];
  const float* Wqb_f  = (const float*)d_in[4];
  const float* Wkva_f = (const float*)d_in[5];
  const float* kvln_f = (const float*)d_in[6];
  const float* Wkvb_f = (const float*)d_in[7];
  const float* Wo_f   = (const float*)d_in[8];

  bf16* base = (bf16*)d_ws;
  bf16* hs_c   = base;                      // 8388608   (dead after gemm3)  | Kf overlay
  bf16* Wkva_c = base + 8388608;            // 1179648
  bf16* ckq    = base + 9568256;            // 6291456
  bf16* qln_c  = base + 15859712;           // 1536
  bf16* kvln_c = base + 15861248;           // 512
  bf16* arena  = base + 15861760;           // 4718592 (W^T staging, serially reused)
  bf16* q      = base + 20580352;           // 12582912
  bf16* kvns   = base + 33163264;           // 2359296 (T x 576)
  bf16* kv     = base + 35522560;           // 16777216 | attn out overlay
  bf16* Vt     = base + 52299776;           // 8388608
  bf16* Kf     = base;                      // 12582912, overlays hs_c/Wkva_c/ckq head
  bf16* attnb  = kv;

  cvt_f32_bf16<<<(8388608 / 8 + 255) / 256, 256, 0, stream>>>(hs_f, hs_c, 8388608 / 8);
  cvt_f32_bf16<<<(1179648 / 8 + 255) / 256, 256, 0, stream>>>(Wkva_f, Wkva_c, 1179648 / 8);
  cvt_f32_bf16<<<1, 256, 0, stream>>>(qln_f, qln_c, 1536 / 8);
  cvt_f32_bf16<<<1, 256, 0, stream>>>(kvln_f, kvln_c, 512 / 8);

  // 1) ckq = hs @ Wqa
  t_cvt<<<dim3(24, 32), 256, 0, stream>>>(Wqa_f, arena, 2048, 1536);
  gemm_v2<false><<<dim3(12, 32), 256, 0, stream>>>(hs_c, arena, ckq, 1536, 2048, 2048, 2048);
  rmsnorm_ip<1536><<<T, 256, 0, stream>>>(ckq, qln_c, 1536);
  // 2) q = q_c @ Wqb
  t_cvt<<<dim3(48, 24), 256, 0, stream>>>(Wqb_f, arena, 1536, 3072);
  gemm_v2<false><<<dim3(24, 32), 256, 0, stream>>>(ckq, arena, q, 3072, 1536, 1536, 1536);
  // 3) kvns = hs @ Wkva (N=576)
  gemm_bf16<<<dim3(9, 32), 256, 0, stream>>>(hs_c, Wkva_c, kvns, 576, 2048, 2048);
  rmsnorm_ip<512><<<T, 256, 0, stream>>>(kvns, kvln_c, 576);
  // 4) kv = kv_c_normed @ Wkvb
  t_cvt<<<dim3(64, 8), 256, 0, stream>>>(Wkvb_f, arena, 512, 4096);
  gemm_v2<false><<<dim3(32, 32), 256, 0, stream>>>(kvns, arena, kv, 4096, 512, 576, 512);
  // 5) rope + K/V assembly
  rope_q<<<T, 512, 0, stream>>>(q);
  prep_kf<<<T, 256, 0, stream>>>(kv, kvns, Kf);
  prep_vt<<<dim3(32, 32), 256, 0, stream>>>(kv, Vt);
  // 6) attention (pipelined)
  attn_v3<<<dim3(16, 32), 256, 0, stream>>>(q, Kf, Vt, attnb);
  // 7) out = attn @ Wo (f32 output)
  t_cvt<<<dim3(32, 32), 256, 0, stream>>>(Wo_f, arena, 2048, 2048);
  gemm_v2<true><<<dim3(16, 32), 256, 0, stream>>>(attnb, arena, d_out, 2048, 2048, 2048, 2048);
}

// Round 11
// 424.947 us; speedup vs baseline: 1.7845x; 1.1491x over previous
//
#include <hip/hip_runtime.h>
#include <hip/hip_bf16.h>

typedef __hip_bfloat16 bf16;
typedef short bf16x8 __attribute__((ext_vector_type(8)));
typedef float f32x4 __attribute__((ext_vector_type(4)));

#define MFMA16(a, b, c) __builtin_amdgcn_mfma_f32_16x16x32_bf16((a), (b), (c), 0, 0, 0)

__device__ __forceinline__ short f2bs(float f) {
  bf16 h = __float2bfloat16(f);
  return __builtin_bit_cast(short, h);
}

// async global->LDS, 16B per lane; LDS dest = wave-uniform base + lane*16
__device__ __forceinline__ void gload16(const void* g, const void* l) {
  __builtin_amdgcn_global_load_lds(
      (const __attribute__((address_space(1))) unsigned int*)g,
      (__attribute__((address_space(3))) unsigned int*)l, 16, 0, 0);
}

// ---------------------------------------------------------------------------
__global__ __launch_bounds__(256) void cvt_f32_bf16(const float* __restrict__ src,
                                                    bf16* __restrict__ dst, int n8) {
  int i = blockIdx.x * 256 + threadIdx.x;
  if (i >= n8) return;
  const float4* s = (const float4*)src;
  float4 a = s[2 * i], b = s[2 * i + 1];
  union { uint4 v; short sh[8]; } o;
  o.sh[0] = f2bs(a.x); o.sh[1] = f2bs(a.y); o.sh[2] = f2bs(a.z); o.sh[3] = f2bs(a.w);
  o.sh[4] = f2bs(b.x); o.sh[5] = f2bs(b.y); o.sh[6] = f2bs(b.z); o.sh[7] = f2bs(b.w);
  ((uint4*)dst)[i] = o.v;
}

// ---------------------------------------------------------------------------
// Fused f32->bf16 + transpose: dst[N][K](bf16) = src[K][N](f32)^T. 64x64 tiles.
// ---------------------------------------------------------------------------
__global__ __launch_bounds__(256) void t_cvt(const float* __restrict__ src,
                                             bf16* __restrict__ dst, int K, int N) {
  __shared__ __align__(16) short Ts[64][72];
  const long n0 = (long)blockIdx.x * 64, k0 = (long)blockIdx.y * 64;
  const int r = threadIdx.x >> 2, c4 = threadIdx.x & 3;
  const float* s = src + (k0 + r) * (long)N + n0 + c4 * 16;
  #pragma unroll
  for (int j = 0; j < 4; ++j) {
    float4 v = *(const float4*)(s + j * 4);
    Ts[r][c4 * 16 + j * 4 + 0] = f2bs(v.x);
    Ts[r][c4 * 16 + j * 4 + 1] = f2bs(v.y);
    Ts[r][c4 * 16 + j * 4 + 2] = f2bs(v.z);
    Ts[r][c4 * 16 + j * 4 + 3] = f2bs(v.w);
  }
  __syncthreads();
  union { uint4 v; short sh[8]; } o0, o1;
  #pragma unroll
  for (int j = 0; j < 8; ++j) o0.sh[j] = Ts[c4 * 16 + j][r];
  #pragma unroll
  for (int j = 0; j < 8; ++j) o1.sh[j] = Ts[c4 * 16 + 8 + j][r];
  *(uint4*)(dst + (n0 + r) * (long)K + k0 + c4 * 16)     = o0.v;
  *(uint4*)(dst + (n0 + r) * (long)K + k0 + c4 * 16 + 8) = o1.v;
}

// ---------------------------------------------------------------------------
// m97-structure GEMM: C = A[M,K] @ BT[N,K]^T. BM=BN=128, BK=32, 4 waves.
// ---------------------------------------------------------------------------
template<bool F32OUT>
__global__ __launch_bounds__(256) void gemm_v2(
    const bf16* __restrict__ A, const bf16* __restrict__ BT, void* __restrict__ Cv,
    int N, int K, int lda, int ldb)
{
  __shared__ __align__(16) short As[128 * 32];
  __shared__ __align__(16) short Bs[128 * 32];
  const int tid = threadIdx.x, lane = tid & 63, w = tid >> 6;
  const int l15 = lane & 15, l4 = lane >> 4;
  const int wr = w >> 1, wc = w & 1;
  const long bm = (long)blockIdx.y * 128, bn = (long)blockIdx.x * 128;
  f32x4 acc[4][4] = {};
  const int srow = tid >> 2, sslot = tid & 3;
  const unsigned lb0 = __builtin_amdgcn_readfirstlane((w * 64) * 16);
  const unsigned lb1 = __builtin_amdgcn_readfirstlane((256 + w * 64) * 16);

  for (int k0 = 0; k0 < K; k0 += 32) {
    __syncthreads();
    gload16(A + (bm + srow) * (long)lda + k0 + sslot * 8,       (char*)As + lb0);
    gload16(A + (bm + 64 + srow) * (long)lda + k0 + sslot * 8,  (char*)As + lb1);
    gload16(BT + (bn + srow) * (long)ldb + k0 + sslot * 8,      (char*)Bs + lb0);
    gload16(BT + (bn + 64 + srow) * (long)ldb + k0 + sslot * 8, (char*)Bs + lb1);
    __syncthreads();
    bf16x8 a[4], b[4];
    #pragma unroll
    for (int mi = 0; mi < 4; ++mi)
      a[mi] = *(const bf16x8*)&As[(wr * 64 + mi * 16 + l15) * 32 + l4 * 8];
    #pragma unroll
    for (int ni = 0; ni < 4; ++ni)
      b[ni] = *(const bf16x8*)&Bs[(wc * 64 + ni * 16 + l15) * 32 + l4 * 8];
    #pragma unroll
    for (int mi = 0; mi < 4; ++mi)
      #pragma unroll
      for (int ni = 0; ni < 4; ++ni)
        acc[mi][ni] = MFMA16(a[mi], b[ni], acc[mi][ni]);
  }
  #pragma unroll
  for (int mi = 0; mi < 4; ++mi)
    #pragma unroll
    for (int ni = 0; ni < 4; ++ni)
      #pragma unroll
      for (int r = 0; r < 4; ++r) {
        long row = bm + wr * 64 + mi * 16 + l4 * 4 + r;
        long col = bn + wc * 64 + ni * 16 + l15;
        float v = acc[mi][ni][r];
        if (F32OUT) ((float*)Cv)[row * N + col] = v;
        else        ((bf16*)Cv)[row * N + col] = __float2bfloat16(v);
      }
}

// ---------------------------------------------------------------------------
// r2-proven GEMM (BM=128, BN=64, BK=32), direct B[K][N], for N=576.
// ---------------------------------------------------------------------------
__global__ __launch_bounds__(256) void gemm_bf16(
    const bf16* __restrict__ A, const bf16* __restrict__ B, bf16* __restrict__ C,
    int N, int K, int lda)
{
  __shared__ __align__(16) short As[128][40];
  __shared__ __align__(16) short Bt[64][40];
  const int tid = threadIdx.x;
  const int lane = tid & 63, w = tid >> 6;
  const int l15 = lane & 15, l4 = lane >> 4;
  const long bm = (long)blockIdx.y * 128;
  const long bn = (long)blockIdx.x * 64;

  f32x4 acc[2][4] = {};
  const int arow = tid >> 1, ac8 = (tid & 1) * 16;
  const int bkr = tid >> 3, bn8 = (tid & 7) * 8;

  for (int k0 = 0; k0 < K; k0 += 32) {
    __syncthreads();
    {
      const uint4* src = (const uint4*)(A + (bm + arow) * (long)lda + k0 + ac8);
      *(uint4*)&As[arow][ac8]     = src[0];
      *(uint4*)&As[arow][ac8 + 8] = src[1];
    }
    {
      union { uint4 v; short s[8]; } u;
      u.v = *(const uint4*)(B + (long)(k0 + bkr) * N + bn + bn8);
      const int swz = ((bn8 >> 3) & 3) << 3;
      #pragma unroll
      for (int i = 0; i < 8; ++i)
        Bt[bn8 + i][bkr ^ swz] = u.s[i];
    }
    __syncthreads();
    bf16x8 a0 = *(const bf16x8*)&As[w * 32 + l15][l4 * 8];
    bf16x8 a1 = *(const bf16x8*)&As[w * 32 + 16 + l15][l4 * 8];
    #pragma unroll
    for (int ni = 0; ni < 4; ++ni) {
      int n = ni * 16 + l15;
      int kb = (l4 * 8) ^ (((n >> 3) & 3) << 3);
      bf16x8 bb = *(const bf16x8*)&Bt[n][kb];
      acc[0][ni] = MFMA16(a0, bb, acc[0][ni]);
      acc[1][ni] = MFMA16(a1, bb, acc[1][ni]);
    }
  }
  #pragma unroll
  for (int mi = 0; mi < 2; ++mi)
    #pragma unroll
    for (int ni = 0; ni < 4; ++ni)
      #pragma unroll
      for (int r = 0; r < 4; ++r) {
        long row = bm + w * 32 + mi * 16 + l4 * 4 + r;
        long col = bn + ni * 16 + l15;
        C[row * N + col] = __float2bfloat16(acc[mi][ni][r]);
      }
}

// ---------------------------------------------------------------------------
template<int C>
__global__ __launch_bounds__(256) void rmsnorm_ip(bf16* __restrict__ x,
                                                  const bf16* __restrict__ w,
                                                  int stride)
{
  constexpr int PER = C / 256;
  const int row = blockIdx.x, tid = threadIdx.x;
  bf16* xr = x + (long)row * stride;
  float v[PER];
  float ss = 0.f;
  #pragma unroll
  for (int k = 0; k < PER; ++k) {
    float f = __bfloat162float(xr[tid + k * 256]);
    v[k] = f; ss += f * f;
  }
  #pragma unroll
  for (int off = 1; off < 64; off <<= 1) ss += __shfl_xor(ss, off);
  __shared__ float red[4];
  if ((tid & 63) == 0) red[tid >> 6] = ss;
  __syncthreads();
  float tot = red[0] + red[1] + red[2] + red[3];
  float scale = rsqrtf(tot / (float)C + 1e-6f);
  #pragma unroll
  for (int k = 0; k < PER; ++k)
    xr[tid + k * 256] =
        __float2bfloat16(v[k] * scale * __bfloat162float(w[tid + k * 256]));
}

// ---------------------------------------------------------------------------
__global__ __launch_bounds__(512) void rope_q(bf16* __restrict__ q)
{
  const int t = blockIdx.x;
  const int h = threadIdx.x >> 5, i = threadIdx.x & 31;
  float p = (float)(t & 2047);
  float freq = powf(10000.0f, -(float)i / 32.0f);
  float sn, cs;
  sincosf(p * freq, &sn, &cs);
  bf16* b = q + (long)t * 3072 + h * 192 + 128 + 2 * i;
  float x1 = __bfloat162float(b[0]), x2 = __bfloat162float(b[1]);
  b[0] = __float2bfloat16(x1 * cs - x2 * sn);
  b[1] = __float2bfloat16(x2 * cs + x1 * sn);
}

// ---------------------------------------------------------------------------
// Build Kf[bh][t][192], rows pre-swizzled: stored 16B-slot s = content s^(t&7).
// ---------------------------------------------------------------------------
__global__ __launch_bounds__(256) void prep_kf(const bf16* __restrict__ kv,
                                               const bf16* __restrict__ kvns,
                                               bf16* __restrict__ Kf)
{
  __shared__ short pe[64];
  const int t = blockIdx.x, tid = threadIdx.x;
  if (tid < 32) {
    int i = tid;
    float p = (float)(t & 2047);
    float freq = powf(10000.0f, -(float)i / 32.0f);
    float sn, cs;
    sincosf(p * freq, &sn, &cs);
    float y1 = __bfloat162float(kvns[(long)t * 576 + 512 + 2 * i]);
    float y2 = __bfloat162float(kvns[(long)t * 576 + 512 + 2 * i + 1]);
    pe[2 * i]     = f2bs(y1 * cs - y2 * sn);
    pe[2 * i + 1] = f2bs(y2 * cs + y1 * sn);
  }
  __syncthreads();
  const int b = t >> 11, ts = t & 2047;
  const int swz = t & 7;
  #pragma unroll
  for (int uu = 0; uu < 2; ++uu) {
    int u = uu * 256 + tid;
    if (u >= 384) break;
    int h = u / 24, s = u % 24;
    int cs = s ^ swz;
    uint4 val;
    if (cs < 16) val = *(const uint4*)(kv + (long)t * 4096 + h * 256 + cs * 8);
    else         val = *(const uint4*)&pe[(cs - 16) * 8];
    *(uint4*)(Kf + ((long)(b * 16 + h) * 2048 + ts) * 192 + s * 8) = val;
  }
}

// ---------------------------------------------------------------------------
// Build Vt[bh][d][2048] = V^T, 64-key blocks pre-swizzled by (d&7).
// ---------------------------------------------------------------------------
__global__ __launch_bounds__(256) void prep_vt(const bf16* __restrict__ kv,
                                               bf16* __restrict__ Vt)
{
  __shared__ __align__(16) short Ts[64][136];
  const int kb = blockIdx.x, bh = blockIdx.y, b = bh >> 4, h = bh & 15;
  const int k0 = kb * 64, tid = threadIdx.x;
  #pragma unroll
  for (int j = 0; j < 4; ++j) {
    int u = j * 256 + tid;
    int kr = u >> 4, seg = u & 15;
    *(uint4*)&Ts[kr][seg * 8] = *(const uint4*)(kv +
        (long)(b * 2048 + k0 + kr) * 4096 + h * 256 + 128 + seg * 8);
  }
  __syncthreads();
  #pragma unroll
  for (int j = 0; j < 4; ++j) {
    int u = j * 256 + tid;
    int d = u >> 3, s = u & 7;
    int cs = s ^ (d & 7);
    union { uint4 v; short sh[8]; } o;
    #pragma unroll
    for (int jj = 0; jj < 8; ++jj) o.sh[jj] = Ts[cs * 8 + jj][d];
    *(uint4*)(Vt + ((long)bh * 128 + d) * 2048 + k0 + s * 8) = o.v;
  }
}

// ---------------------------------------------------------------------------
// attn_v5: SWAPPED QK (T12) — s = mfma(K, Q): lane holds 16 P-values of ONE
// q-row (qrow=l15, keys kg*16+l4*4+r). Softmax = in-reg tree + 2 shfls.
// Grid 1024 one-tile blocks (3/CU), XCD-preserving decode. Pipelined staging.
// ---------------------------------------------------------------------------
__global__ __launch_bounds__(256) void attn_v5(const bf16* __restrict__ q,
                                               const bf16* __restrict__ Kf,
                                               const bf16* __restrict__ Vt,
                                               bf16* __restrict__ attn)
{
  __shared__ __align__(16) short Ks[64 * 192];
  __shared__ __align__(16) short Vs[128 * 64];
  __shared__ __align__(16) short Ps[4][16 * 64];
  const float SC = 0.07216878364870323f;  // 192^-0.5
  const int tid = threadIdx.x, lane = tid & 63, w = tid >> 6;
  const int l15 = lane & 15, l4 = lane >> 4;
  // decode: XCD x owns bh in [4x, 4x+4): lin = x + 8*j, bh = 4x+(j>>5), qt = j&31
  const int lin = blockIdx.x;
  const int x = lin & 7, j = lin >> 3;
  const int bh = x * 4 + (j >> 5), qt = j & 31;
  const int b = bh >> 4, h = bh & 15;
  const unsigned lbase = __builtin_amdgcn_readfirstlane(w * 64 * 16);
  const long qrow0 = (long)b * 2048 + qt * 64;

  bf16x8 qf[6];
  {
    const short* qrow = (const short*)q + (qrow0 + w * 16 + l15) * 3072 + h * 192;
    #pragma unroll
    for (int kc = 0; kc < 6; ++kc)
      qf[kc] = *(const bf16x8*)(qrow + kc * 32 + l4 * 8);
  }
  f32x4 o[8] = {};
  float mreg = -1e30f, ls = 0.f;           // per-lane: qrow = w*16 + l15
  const int rowt = qt * 64 + w * 16 + l15; // lane's global q-row
  const int nch = qt + 1;

  {  // prologue: stage K chunk 0
    const char* ksrc = (const char*)(Kf + (long)bh * 2048 * 192);
    #pragma unroll
    for (int jj = 0; jj < 6; ++jj)
      gload16(ksrc + (jj * 256 + tid) * 16, (char*)Ks + jj * 4096 + lbase);
  }
  __syncthreads();

  for (int c = 0; c < nch; ++c) {
    const int k0 = c * 64;
    {  // issue V(c) — drains at mid-barrier, hidden under QK+softmax
      #pragma unroll
      for (int jj = 0; jj < 4; ++jj) {
        int seg = jj * 256 + tid;
        const bf16* vsrc = Vt + ((long)bh * 128 + (seg >> 3)) * 2048 + k0 + (seg & 7) * 8;
        gload16(vsrc, (char*)Vs + jj * 4096 + lbase);
      }
    }
    __builtin_amdgcn_s_setprio(1);
    f32x4 s[4] = {};
    #pragma unroll
    for (int kc = 0; kc < 6; ++kc)
      #pragma unroll
      for (int kg = 0; kg < 4; ++kg) {
        int row = kg * 16 + l15;
        int slot = (kc * 4 + l4) ^ (l15 & 7);
        bf16x8 kb = *(const bf16x8*)&Ks[row * 192 + slot * 8];
        s[kg] = MFMA16(kb, qf[kc], s[kg]);   // SWAPPED: D[key][qrow]
      }
    __builtin_amdgcn_s_setprio(0);

    // lane holds s[kg][r] = S[key = k0+kg*16+l4*4+r][qrow = rowt]
    const bool diag = (c == qt);
    float pk[16];
    #pragma unroll
    for (int kg = 0; kg < 4; ++kg)
      #pragma unroll
      for (int r = 0; r < 4; ++r) {
        float v = s[kg][r] * SC;
        if (diag && (k0 + kg * 16 + l4 * 4 + r > rowt)) v = -1e30f;
        pk[kg * 4 + r] = v;
      }
    float cm = pk[0];
    #pragma unroll
    for (int i = 1; i < 16; ++i) cm = fmaxf(cm, pk[i]);
    cm = fmaxf(cm, __shfl_xor(cm, 16));
    cm = fmaxf(cm, __shfl_xor(cm, 32));
    if (__ballot(cm > mreg + 8.0f)) {  // defer-max rescale (wave-uniform)
      float mn = fmaxf(mreg, cm);
      float al = __expf(mreg - mn);
      ls *= al;
      float af[4];
      #pragma unroll
      for (int r = 0; r < 4; ++r) af[r] = __shfl(al, l4 * 4 + r);
      #pragma unroll
      for (int f = 0; f < 8; ++f)
        #pragma unroll
        for (int r = 0; r < 4; ++r) o[f][r] *= af[r];
      mreg = mn;
    }
    float ps = 0.f;
    #pragma unroll
    for (int i = 0; i < 16; ++i) { pk[i] = __expf(pk[i] - mreg); ps += pk[i]; }
    ps += __shfl_xor(ps, 16);
    ps += __shfl_xor(ps, 32);
    ls += ps;
    // P -> LDS: 8 packed b32 writes; Ps[qrow=l15][key], slot swizzled by qrow&7
    #pragma unroll
    for (int kg = 0; kg < 4; ++kg)
      #pragma unroll
      for (int pr = 0; pr < 2; ++pr) {
        int key2 = kg * 16 + l4 * 4 + pr * 2;
        int sl = (key2 >> 3) ^ (l15 & 7);
        unsigned lo = (unsigned short)f2bs(pk[kg * 4 + pr * 2]);
        unsigned hi = (unsigned short)f2bs(pk[kg * 4 + pr * 2 + 1]);
        *(unsigned*)&Ps[w][l15 * 64 + sl * 8 + (key2 & 7)] = lo | (hi << 16);
      }
    __syncthreads();  // mid-barrier: V(c) landed; Ks reads + Ps writes done

    if (c + 1 < nch) {  // issue K(c+1) — drains at end-barrier, under PV
      const char* ksrc = (const char*)(Kf + ((long)bh * 2048 + k0 + 64) * 192);
      #pragma unroll
      for (int jj = 0; jj < 6; ++jj)
        gload16(ksrc + (jj * 256 + tid) * 16, (char*)Ks + jj * 4096 + lbase);
    }

    __builtin_amdgcn_s_setprio(1);
    #pragma unroll
    for (int ks = 0; ks < 2; ++ks) {
      int psl = (ks * 4 + l4) ^ (l15 & 7);
      bf16x8 pa = *(const bf16x8*)&Ps[w][l15 * 64 + psl * 8];
      #pragma unroll
      for (int f = 0; f < 8; ++f) {
        int vrow = f * 16 + l15;
        int vsl = (ks * 4 + l4) ^ (l15 & 7);
        bf16x8 bv = *(const bf16x8*)&Vs[vrow * 64 + vsl * 8];
        o[f] = MFMA16(pa, bv, o[f]);
      }
    }
    __builtin_amdgcn_s_setprio(0);
    __syncthreads();  // end-barrier: K(c+1) landed; Vs reads done
  }

  #pragma unroll
  for (int r = 0; r < 4; ++r) {
    float lsr = __shfl(ls, l4 * 4 + r);   // ls lives at lane = qrow (l15<16)
    float inv = 1.0f / lsr;
    long t = qrow0 + w * 16 + l4 * 4 + r;
    bf16* dst = attn + t * 2048 + h * 128;
    #pragma unroll
    for (int f = 0; f < 8; ++f)
      dst[f * 16 + l15] = __float2bfloat16(o[f][r] * inv);
  }
}

// ---------------------------------------------------------------------------
extern "C" void kernel_launch(void* const* d_in, const int* in_sizes, int n_in,
                              void* d_out, int out_size, void* d_ws, size_t ws_size,
                              hipStream_t stream) {
  const int T = 4096;
  const float* hs_f   = (const float*)d_in[1];
  const float* Wqa_f  = (const float*)d_in[2];
  const float* qln_f  = (const float*)d_in[3];
  const float* Wqb_f  = (const float*)d_in[4];
  const float* Wkva_f = (const float*)d_in[5];
  const float* kvln_f = (const float*)d_in[6];
  const float* Wkvb_f = (const float*)d_in[7];
  const float* Wo_f   = (const float*)d_in[8];

  bf16* base = (bf16*)d_ws;
  bf16* hs_c   = base;                      // 8388608   (dead after gemm3)  | Kf overlay
  bf16* Wkva_c = base + 8388608;            // 1179648
  bf16* ckq    = base + 9568256;            // 6291456
  bf16* qln_c  = base + 15859712;           // 1536
  bf16* kvln_c = base + 15861248;           // 512
  bf16* arena  = base + 15861760;           // 4718592 (W^T staging, serially reused)
  bf16* q      = base + 20580352;           // 12582912
  bf16* kvns   = base + 33163264;           // 2359296 (T x 576)
  bf16* kv     = base + 35522560;           // 16777216 | attn out overlay
  bf16* Vt     = base + 52299776;           // 8388608
  bf16* Kf     = base;                      // 12582912, overlays hs_c/Wkva_c/ckq head
  bf16* attnb  = kv;

  cvt_f32_bf16<<<(8388608 / 8 + 255) / 256, 256, 0, stream>>>(hs_f, hs_c, 8388608 / 8);
  cvt_f32_bf16<<<(1179648 / 8 + 255) / 256, 256, 0, stream>>>(Wkva_f, Wkva_c, 1179648 / 8);
  cvt_f32_bf16<<<1, 256, 0, stream>>>(qln_f, qln_c, 1536 / 8);
  cvt_f32_bf16<<<1, 256, 0, stream>>>(kvln_f, kvln_c, 512 / 8);

  // 1) ckq = hs @ Wqa
  t_cvt<<<dim3(24, 32), 256, 0, stream>>>(Wqa_f, arena, 2048, 1536);
  gemm_v2<false><<<dim3(12, 32), 256, 0, stream>>>(hs_c, arena, ckq, 1536, 2048, 2048, 2048);
  rmsnorm_ip<1536><<<T, 256, 0, stream>>>(ckq, qln_c, 1536);
  // 2) q = q_c @ Wqb
  t_cvt<<<dim3(48, 24), 256, 0, stream>>>(Wqb_f, arena, 1536, 3072);
  gemm_v2<false><<<dim3(24, 32), 256, 0, stream>>>(ckq, arena, q, 3072, 1536, 1536, 1536);
  // 3) kvns = hs @ Wkva (N=576)
  gemm_bf16<<<dim3(9, 32), 256, 0, stream>>>(hs_c, Wkva_c, kvns, 576, 2048, 2048);
  rmsnorm_ip<512><<<T, 256, 0, stream>>>(kvns, kvln_c, 576);
  // 4) kv = kv_c_normed @ Wkvb
  t_cvt<<<dim3(64, 8), 256, 0, stream>>>(Wkvb_f, arena, 512, 4096);
  gemm_v2<false><<<dim3(32, 32), 256, 0, stream>>>(kvns, arena, kv, 4096, 512, 576, 512);
  // 5) rope + K/V assembly
  rope_q<<<T, 512, 0, stream>>>(q);
  prep_kf<<<T, 256, 0, stream>>>(kv, kvns, Kf);
  prep_vt<<<dim3(32, 32), 256, 0, stream>>>(kv, Vt);
  // 6) attention (swapped-QK softmax, 1024 one-tile blocks)
  attn_v5<<<1024, 256, 0, stream>>>(q, Kf, Vt, attnb);
  // 7) out = attn @ Wo (f32 output)
  t_cvt<<<dim3(32, 32), 256, 0, stream>>>(Wo_f, arena, 2048, 2048);
  gemm_v2<true><<<dim3(16, 32), 256, 0, stream>>>(attnb, arena, d_out, 2048, 2048, 2048, 2048);
}

// Round 12
// 370.425 us; speedup vs baseline: 2.0471x; 1.1472x over previous
//
#include <hip/hip_runtime.h>
#include <hip/hip_bf16.h>

typedef __hip_bfloat16 bf16;
typedef short bf16x8 __attribute__((ext_vector_type(8)));
typedef float f32x4 __attribute__((ext_vector_type(4)));

#define MFMA16(a, b, c) __builtin_amdgcn_mfma_f32_16x16x32_bf16((a), (b), (c), 0, 0, 0)

__device__ __forceinline__ short f2bs(float f) {
  bf16 h = __float2bfloat16(f);
  return __builtin_bit_cast(short, h);
}
__device__ __forceinline__ float bs2f(short s) {
  return __bfloat162float(__builtin_bit_cast(bf16, s));
}

// async global->LDS, 16B per lane; LDS dest = wave-uniform base + lane*16
__device__ __forceinline__ void gload16(const void* g, const void* l) {
  __builtin_amdgcn_global_load_lds(
      (const __attribute__((address_space(1))) unsigned int*)g,
      (__attribute__((address_space(3))) unsigned int*)l, 16, 0, 0);
}

// ---------------------------------------------------------------------------
__global__ __launch_bounds__(256) void cvt_f32_bf16(const float* __restrict__ src,
                                                    bf16* __restrict__ dst, int n8) {
  int i = blockIdx.x * 256 + threadIdx.x;
  if (i >= n8) return;
  const float4* s = (const float4*)src;
  float4 a = s[2 * i], b = s[2 * i + 1];
  union { uint4 v; short sh[8]; } o;
  o.sh[0] = f2bs(a.x); o.sh[1] = f2bs(a.y); o.sh[2] = f2bs(a.z); o.sh[3] = f2bs(a.w);
  o.sh[4] = f2bs(b.x); o.sh[5] = f2bs(b.y); o.sh[6] = f2bs(b.z); o.sh[7] = f2bs(b.w);
  ((uint4*)dst)[i] = o.v;
}

// ---------------------------------------------------------------------------
// Fused f32->bf16 + transpose: dst[N][K](bf16) = src[K][N](f32)^T. 64x64 tiles.
// ---------------------------------------------------------------------------
__global__ __launch_bounds__(256) void t_cvt(const float* __restrict__ src,
                                             bf16* __restrict__ dst, int K, int N) {
  __shared__ __align__(16) short Ts[64][72];
  const long n0 = (long)blockIdx.x * 64, k0 = (long)blockIdx.y * 64;
  const int r = threadIdx.x >> 2, c4 = threadIdx.x & 3;
  const float* s = src + (k0 + r) * (long)N + n0 + c4 * 16;
  #pragma unroll
  for (int j = 0; j < 4; ++j) {
    float4 v = *(const float4*)(s + j * 4);
    Ts[r][c4 * 16 + j * 4 + 0] = f2bs(v.x);
    Ts[r][c4 * 16 + j * 4 + 1] = f2bs(v.y);
    Ts[r][c4 * 16 + j * 4 + 2] = f2bs(v.z);
    Ts[r][c4 * 16 + j * 4 + 3] = f2bs(v.w);
  }
  __syncthreads();
  union { uint4 v; short sh[8]; } o0, o1;
  #pragma unroll
  for (int j = 0; j < 8; ++j) o0.sh[j] = Ts[c4 * 16 + j][r];
  #pragma unroll
  for (int j = 0; j < 8; ++j) o1.sh[j] = Ts[c4 * 16 + 8 + j][r];
  *(uint4*)(dst + (n0 + r) * (long)K + k0 + c4 * 16)     = o0.v;
  *(uint4*)(dst + (n0 + r) * (long)K + k0 + c4 * 16 + 8) = o1.v;
}

// ---------------------------------------------------------------------------
// m97-structure GEMM: C = A[M,K] @ BT[N,K]^T. BM=BN=128, BK=32, 4 waves.
// T1 XCD swizzle: each XCD owns a contiguous lin-chunk (A-panel L2 locality).
// ---------------------------------------------------------------------------
template<bool F32OUT>
__global__ __launch_bounds__(256) void gemm_v2(
    const bf16* __restrict__ A, const bf16* __restrict__ BT, void* __restrict__ Cv,
    int N, int K, int lda, int ldb)
{
  __shared__ __align__(16) short As[128 * 32];
  __shared__ __align__(16) short Bs[128 * 32];
  const int tid = threadIdx.x, lane = tid & 63, w = tid >> 6;
  const int l15 = lane & 15, l4 = lane >> 4;
  const int wr = w >> 1, wc = w & 1;
  const int nx = gridDim.x, nwg = nx * gridDim.y;
  const int lin = blockIdx.y * nx + blockIdx.x;
  const int sl = (lin & 7) * (nwg >> 3) + (lin >> 3);   // nwg % 8 == 0
  const long bm = (long)(sl / nx) * 128, bn = (long)(sl % nx) * 128;
  f32x4 acc[4][4] = {};
  const int srow = tid >> 2, sslot = tid & 3;
  const unsigned lb0 = __builtin_amdgcn_readfirstlane((w * 64) * 16);
  const unsigned lb1 = __builtin_amdgcn_readfirstlane((256 + w * 64) * 16);

  for (int k0 = 0; k0 < K; k0 += 32) {
    __syncthreads();
    gload16(A + (bm + srow) * (long)lda + k0 + sslot * 8,       (char*)As + lb0);
    gload16(A + (bm + 64 + srow) * (long)lda + k0 + sslot * 8,  (char*)As + lb1);
    gload16(BT + (bn + srow) * (long)ldb + k0 + sslot * 8,      (char*)Bs + lb0);
    gload16(BT + (bn + 64 + srow) * (long)ldb + k0 + sslot * 8, (char*)Bs + lb1);
    __syncthreads();
    bf16x8 a[4], b[4];
    #pragma unroll
    for (int mi = 0; mi < 4; ++mi)
      a[mi] = *(const bf16x8*)&As[(wr * 64 + mi * 16 + l15) * 32 + l4 * 8];
    #pragma unroll
    for (int ni = 0; ni < 4; ++ni)
      b[ni] = *(const bf16x8*)&Bs[(wc * 64 + ni * 16 + l15) * 32 + l4 * 8];
    #pragma unroll
    for (int mi = 0; mi < 4; ++mi)
      #pragma unroll
      for (int ni = 0; ni < 4; ++ni)
        acc[mi][ni] = MFMA16(a[mi], b[ni], acc[mi][ni]);
  }
  #pragma unroll
  for (int mi = 0; mi < 4; ++mi)
    #pragma unroll
    for (int ni = 0; ni < 4; ++ni)
      #pragma unroll
      for (int r = 0; r < 4; ++r) {
        long row = bm + wr * 64 + mi * 16 + l4 * 4 + r;
        long col = bn + wc * 64 + ni * 16 + l15;
        float v = acc[mi][ni][r];
        if (F32OUT) ((float*)Cv)[row * N + col] = v;
        else        ((bf16*)Cv)[row * N + col] = __float2bfloat16(v);
      }
}

// ---------------------------------------------------------------------------
// r2-proven GEMM (BM=128, BN=64, BK=32), direct B[K][N], for N=576. +T1 swizzle.
// ---------------------------------------------------------------------------
__global__ __launch_bounds__(256) void gemm_bf16(
    const bf16* __restrict__ A, const bf16* __restrict__ B, bf16* __restrict__ C,
    int N, int K, int lda)
{
  __shared__ __align__(16) short As[128][40];
  __shared__ __align__(16) short Bt[64][40];
  const int tid = threadIdx.x;
  const int lane = tid & 63, w = tid >> 6;
  const int l15 = lane & 15, l4 = lane >> 4;
  const int nx = gridDim.x, nwg = nx * gridDim.y;
  const int lin = blockIdx.y * nx + blockIdx.x;
  const int sl = (lin & 7) * (nwg >> 3) + (lin >> 3);
  const long bm = (long)(sl / nx) * 128;
  const long bn = (long)(sl % nx) * 64;

  f32x4 acc[2][4] = {};
  const int arow = tid >> 1, ac8 = (tid & 1) * 16;
  const int bkr = tid >> 3, bn8 = (tid & 7) * 8;

  for (int k0 = 0; k0 < K; k0 += 32) {
    __syncthreads();
    {
      const uint4* src = (const uint4*)(A + (bm + arow) * (long)lda + k0 + ac8);
      *(uint4*)&As[arow][ac8]     = src[0];
      *(uint4*)&As[arow][ac8 + 8] = src[1];
    }
    {
      union { uint4 v; short s[8]; } u;
      u.v = *(const uint4*)(B + (long)(k0 + bkr) * N + bn + bn8);
      const int swz = ((bn8 >> 3) & 3) << 3;
      #pragma unroll
      for (int i = 0; i < 8; ++i)
        Bt[bn8 + i][bkr ^ swz] = u.s[i];
    }
    __syncthreads();
    bf16x8 a0 = *(const bf16x8*)&As[w * 32 + l15][l4 * 8];
    bf16x8 a1 = *(const bf16x8*)&As[w * 32 + 16 + l15][l4 * 8];
    #pragma unroll
    for (int ni = 0; ni < 4; ++ni) {
      int n = ni * 16 + l15;
      int kb = (l4 * 8) ^ (((n >> 3) & 3) << 3);
      bf16x8 bb = *(const bf16x8*)&Bt[n][kb];
      acc[0][ni] = MFMA16(a0, bb, acc[0][ni]);
      acc[1][ni] = MFMA16(a1, bb, acc[1][ni]);
    }
  }
  #pragma unroll
  for (int mi = 0; mi < 2; ++mi)
    #pragma unroll
    for (int ni = 0; ni < 4; ++ni)
      #pragma unroll
      for (int r = 0; r < 4; ++r) {
        long row = bm + w * 32 + mi * 16 + l4 * 4 + r;
        long col = bn + ni * 16 + l15;
        C[row * N + col] = __float2bfloat16(acc[mi][ni][r]);
      }
}

// ---------------------------------------------------------------------------
template<int C>
__global__ __launch_bounds__(256) void rmsnorm_ip(bf16* __restrict__ x,
                                                  const bf16* __restrict__ w,
                                                  int stride)
{
  constexpr int PER = C / 256;
  const int row = blockIdx.x, tid = threadIdx.x;
  bf16* xr = x + (long)row * stride;
  float v[PER];
  float ss = 0.f;
  #pragma unroll
  for (int k = 0; k < PER; ++k) {
    float f = __bfloat162float(xr[tid + k * 256]);
    v[k] = f; ss += f * f;
  }
  #pragma unroll
  for (int off = 1; off < 64; off <<= 1) ss += __shfl_xor(ss, off);
  __shared__ float red[4];
  if ((tid & 63) == 0) red[tid >> 6] = ss;
  __syncthreads();
  float tot = red[0] + red[1] + red[2] + red[3];
  float scale = rsqrtf(tot / (float)C + 1e-6f);
  #pragma unroll
  for (int k = 0; k < PER; ++k)
    xr[tid + k * 256] =
        __float2bfloat16(v[k] * scale * __bfloat162float(w[tid + k * 256]));
}

// ---------------------------------------------------------------------------
// Build Kf[bh][t][192], rows pre-swizzled: stored 16B-slot s = content s^(t&7).
// ---------------------------------------------------------------------------
__global__ __launch_bounds__(256) void prep_kf(const bf16* __restrict__ kv,
                                               const bf16* __restrict__ kvns,
                                               bf16* __restrict__ Kf)
{
  __shared__ short pe[64];
  const int t = blockIdx.x, tid = threadIdx.x;
  if (tid < 32) {
    int i = tid;
    float p = (float)(t & 2047);
    float freq = powf(10000.0f, -(float)i / 32.0f);
    float sn, cs;
    sincosf(p * freq, &sn, &cs);
    float y1 = __bfloat162float(kvns[(long)t * 576 + 512 + 2 * i]);
    float y2 = __bfloat162float(kvns[(long)t * 576 + 512 + 2 * i + 1]);
    pe[2 * i]     = f2bs(y1 * cs - y2 * sn);
    pe[2 * i + 1] = f2bs(y2 * cs + y1 * sn);
  }
  __syncthreads();
  const int b = t >> 11, ts = t & 2047;
  const int swz = t & 7;
  #pragma unroll
  for (int uu = 0; uu < 2; ++uu) {
    int u = uu * 256 + tid;
    if (u >= 384) break;
    int h = u / 24, s = u % 24;
    int cs = s ^ swz;
    uint4 val;
    if (cs < 16) val = *(const uint4*)(kv + (long)t * 4096 + h * 256 + cs * 8);
    else         val = *(const uint4*)&pe[(cs - 16) * 8];
    *(uint4*)(Kf + ((long)(b * 16 + h) * 2048 + ts) * 192 + s * 8) = val;
  }
}

// ---------------------------------------------------------------------------
// Build Vt[bh][d][2048] = V^T, 64-key blocks pre-swizzled by (d&7).
// ---------------------------------------------------------------------------
__global__ __launch_bounds__(256) void prep_vt(const bf16* __restrict__ kv,
                                               bf16* __restrict__ Vt)
{
  __shared__ __align__(16) short Ts[64][136];
  const int kb = blockIdx.x, bh = blockIdx.y, b = bh >> 4, h = bh & 15;
  const int k0 = kb * 64, tid = threadIdx.x;
  #pragma unroll
  for (int j = 0; j < 4; ++j) {
    int u = j * 256 + tid;
    int kr = u >> 4, seg = u & 15;
    *(uint4*)&Ts[kr][seg * 8] = *(const uint4*)(kv +
        (long)(b * 2048 + k0 + kr) * 4096 + h * 256 + 128 + seg * 8);
  }
  __syncthreads();
  #pragma unroll
  for (int j = 0; j < 4; ++j) {
    int u = j * 256 + tid;
    int d = u >> 3, s = u & 7;
    int cs = s ^ (d & 7);
    union { uint4 v; short sh[8]; } o;
    #pragma unroll
    for (int jj = 0; jj < 8; ++jj) o.sh[jj] = Ts[cs * 8 + jj][d];
    *(uint4*)(Vt + ((long)bh * 128 + d) * 2048 + k0 + s * 8) = o.v;
  }
}

// ---------------------------------------------------------------------------
// attn_v6: swapped-QK softmax (v5) + q-tile PAIRING (uniform 33 chunks) +
// fused in-register RoPE on Q's pe fragments. Grid 512, XCD-preserving decode.
// ---------------------------------------------------------------------------
__global__ __launch_bounds__(256) void attn_v6(const bf16* __restrict__ q,
                                               const bf16* __restrict__ Kf,
                                               const bf16* __restrict__ Vt,
                                               bf16* __restrict__ attn)
{
  __shared__ __align__(16) short Ks[64 * 192];
  __shared__ __align__(16) short Vs[128 * 64];
  __shared__ __align__(16) short Ps[4][16 * 64];
  const float SC = 0.07216878364870323f;  // 192^-0.5
  const int tid = threadIdx.x, lane = tid & 63, w = tid >> 6;
  const int l15 = lane & 15, l4 = lane >> 4;
  // decode: XCD x owns bh in [4x,4x+4): lin = x + 8*j; bh = 4x+(j>>4); p = j&15
  const int lin = blockIdx.x;
  const int x = lin & 7, j = lin >> 3;
  const int bh = x * 4 + (j >> 4), p = j & 15;
  const int b = bh >> 4, h = bh & 15;
  const unsigned lbase = __builtin_amdgcn_readfirstlane(w * 64 * 16);

  #pragma unroll
  for (int half = 0; half < 2; ++half) {
    const int qt = half ? (31 - p) : p;
    const long qrow0 = (long)b * 2048 + qt * 64;
    const int rowt = qt * 64 + w * 16 + l15;  // lane's global q-row (== pos)

    bf16x8 qf[6];
    {
      const short* qrow = (const short*)q + (qrow0 + w * 16 + l15) * 3072 + h * 192;
      #pragma unroll
      for (int kc = 0; kc < 6; ++kc)
        qf[kc] = *(const bf16x8*)(qrow + kc * 32 + l4 * 8);
    }
    {  // fused GPT-J RoPE on pe fragments (cols 128..191 = kc 4,5)
      float pos = (float)rowt;
      #pragma unroll
      for (int kc = 4; kc < 6; ++kc)
        #pragma unroll
        for (int pr = 0; pr < 4; ++pr) {
          int i = (kc - 4) * 16 + l4 * 4 + pr;
          float freq = __expf((float)i * -0.28782313662425572f);  // 10000^(-i/32)
          float sn, cs;
          sincosf(pos * freq, &sn, &cs);
          float x1 = bs2f(qf[kc][2 * pr]), x2 = bs2f(qf[kc][2 * pr + 1]);
          qf[kc][2 * pr]     = f2bs(x1 * cs - x2 * sn);
          qf[kc][2 * pr + 1] = f2bs(x2 * cs + x1 * sn);
        }
    }
    f32x4 o[8] = {};
    float mreg = -1e30f, ls = 0.f;
    const int nch = qt + 1;

    {  // prologue: stage K chunk 0
      const char* ksrc = (const char*)(Kf + (long)bh * 2048 * 192);
      #pragma unroll
      for (int jj = 0; jj < 6; ++jj)
        gload16(ksrc + (jj * 256 + tid) * 16, (char*)Ks + jj * 4096 + lbase);
    }
    __syncthreads();

    for (int c = 0; c < nch; ++c) {
      const int k0 = c * 64;
      {  // issue V(c) — drains at mid-barrier, hidden under QK+softmax
        #pragma unroll
        for (int jj = 0; jj < 4; ++jj) {
          int seg = jj * 256 + tid;
          const bf16* vsrc = Vt + ((long)bh * 128 + (seg >> 3)) * 2048 + k0 + (seg & 7) * 8;
          gload16(vsrc, (char*)Vs + jj * 4096 + lbase);
        }
      }
      __builtin_amdgcn_s_setprio(1);
      f32x4 s[4] = {};
      #pragma unroll
      for (int kc = 0; kc < 6; ++kc)
        #pragma unroll
        for (int kg = 0; kg < 4; ++kg) {
          int row = kg * 16 + l15;
          int slot = (kc * 4 + l4) ^ (l15 & 7);
          bf16x8 kb = *(const bf16x8*)&Ks[row * 192 + slot * 8];
          s[kg] = MFMA16(kb, qf[kc], s[kg]);   // SWAPPED: D[key][qrow]
        }
      __builtin_amdgcn_s_setprio(0);

      const bool diag = (c == qt);
      float pk[16];
      #pragma unroll
      for (int kg = 0; kg < 4; ++kg)
        #pragma unroll
        for (int r = 0; r < 4; ++r) {
          float v = s[kg][r] * SC;
          if (diag && (k0 + kg * 16 + l4 * 4 + r > rowt)) v = -1e30f;
          pk[kg * 4 + r] = v;
        }
      float cm = pk[0];
      #pragma unroll
      for (int i = 1; i < 16; ++i) cm = fmaxf(cm, pk[i]);
      cm = fmaxf(cm, __shfl_xor(cm, 16));
      cm = fmaxf(cm, __shfl_xor(cm, 32));
      if (__ballot(cm > mreg + 8.0f)) {  // defer-max rescale (wave-uniform)
        float mn = fmaxf(mreg, cm);
        float al = __expf(mreg - mn);
        ls *= al;
        float af[4];
        #pragma unroll
        for (int r = 0; r < 4; ++r) af[r] = __shfl(al, l4 * 4 + r);
        #pragma unroll
        for (int f = 0; f < 8; ++f)
          #pragma unroll
          for (int r = 0; r < 4; ++r) o[f][r] *= af[r];
        mreg = mn;
      }
      float ps = 0.f;
      #pragma unroll
      for (int i = 0; i < 16; ++i) { pk[i] = __expf(pk[i] - mreg); ps += pk[i]; }
      ps += __shfl_xor(ps, 16);
      ps += __shfl_xor(ps, 32);
      ls += ps;
      #pragma unroll
      for (int kg = 0; kg < 4; ++kg)
        #pragma unroll
        for (int pr = 0; pr < 2; ++pr) {
          int key2 = kg * 16 + l4 * 4 + pr * 2;
          int sl = (key2 >> 3) ^ (l15 & 7);
          unsigned lo = (unsigned short)f2bs(pk[kg * 4 + pr * 2]);
          unsigned hi = (unsigned short)f2bs(pk[kg * 4 + pr * 2 + 1]);
          *(unsigned*)&Ps[w][l15 * 64 + sl * 8 + (key2 & 7)] = lo | (hi << 16);
        }
      __syncthreads();  // mid-barrier: V(c) landed; Ks reads + Ps writes done

      if (c + 1 < nch) {  // issue K(c+1) — drains at end-barrier, under PV
        const char* ksrc = (const char*)(Kf + ((long)bh * 2048 + k0 + 64) * 192);
        #pragma unroll
        for (int jj = 0; jj < 6; ++jj)
          gload16(ksrc + (jj * 256 + tid) * 16, (char*)Ks + jj * 4096 + lbase);
      }

      __builtin_amdgcn_s_setprio(1);
      #pragma unroll
      for (int ks = 0; ks < 2; ++ks) {
        int psl = (ks * 4 + l4) ^ (l15 & 7);
        bf16x8 pa = *(const bf16x8*)&Ps[w][l15 * 64 + psl * 8];
        #pragma unroll
        for (int f = 0; f < 8; ++f) {
          int vrow = f * 16 + l15;
          int vsl = (ks * 4 + l4) ^ (l15 & 7);
          bf16x8 bv = *(const bf16x8*)&Vs[vrow * 64 + vsl * 8];
          o[f] = MFMA16(pa, bv, o[f]);
        }
      }
      __builtin_amdgcn_s_setprio(0);
      __syncthreads();  // end-barrier: K(c+1) landed; Vs reads done
    }

    #pragma unroll
    for (int r = 0; r < 4; ++r) {
      float lsr = __shfl(ls, l4 * 4 + r);
      float inv = 1.0f / lsr;
      long t = qrow0 + w * 16 + l4 * 4 + r;
      bf16* dst = attn + t * 2048 + h * 128;
      #pragma unroll
      for (int f = 0; f < 8; ++f)
        dst[f * 16 + l15] = __float2bfloat16(o[f][r] * inv);
    }
  }
}

// ---------------------------------------------------------------------------
extern "C" void kernel_launch(void* const* d_in, const int* in_sizes, int n_in,
                              void* d_out, int out_size, void* d_ws, size_t ws_size,
                              hipStream_t stream) {
  const int T = 4096;
  const float* hs_f   = (const float*)d_in[1];
  const float* Wqa_f  = (const float*)d_in[2];
  const float* qln_f  = (const float*)d_in[3];
  const float* Wqb_f  = (const float*)d_in[4];
  const float* Wkva_f = (const float*)d_in[5];
  const float* kvln_f = (const float*)d_in[6];
  const float* Wkvb_f = (const float*)d_in[7];
  const float* Wo_f   = (const float*)d_in[8];

  bf16* base = (bf16*)d_ws;
  bf16* hs_c   = base;                      // 8388608   (dead after gemm3)  | Kf overlay
  bf16* Wkva_c = base + 8388608;            // 1179648
  bf16* ckq    = base + 9568256;            // 6291456
  bf16* qln_c  = base + 15859712;           // 1536
  bf16* kvln_c = base + 15861248;           // 512
  bf16* arena  = base + 15861760;           // 4718592 (W^T staging, serially reused)
  bf16* q      = base + 20580352;           // 12582912
  bf16* kvns   = base + 33163264;           // 2359296 (T x 576)
  bf16* kv     = base + 35522560;           // 16777216 | attn out overlay
  bf16* Vt     = base + 52299776;           // 8388608
  bf16* Kf     = base;                      // 12582912, overlays hs_c/Wkva_c/ckq head
  bf16* attnb  = kv;

  cvt_f32_bf16<<<(8388608 / 8 + 255) / 256, 256, 0, stream>>>(hs_f, hs_c, 8388608 / 8);
  cvt_f32_bf16<<<(1179648 / 8 + 255) / 256, 256, 0, stream>>>(Wkva_f, Wkva_c, 1179648 / 8);
  cvt_f32_bf16<<<1, 256, 0, stream>>>(qln_f, qln_c, 1536 / 8);
  cvt_f32_bf16<<<1, 256, 0, stream>>>(kvln_f, kvln_c, 512 / 8);

  // 1) ckq = hs @ Wqa
  t_cvt<<<dim3(24, 32), 256, 0, stream>>>(Wqa_f, arena, 2048, 1536);
  gemm_v2<false><<<dim3(12, 32), 256, 0, stream>>>(hs_c, arena, ckq, 1536, 2048, 2048, 2048);
  rmsnorm_ip<1536><<<T, 256, 0, stream>>>(ckq, qln_c, 1536);
  // 2) q = q_c @ Wqb (q_pe raw; roped in-register inside attn)
  t_cvt<<<dim3(48, 24), 256, 0, stream>>>(Wqb_f, arena, 1536, 3072);
  gemm_v2<false><<<dim3(24, 32), 256, 0, stream>>>(ckq, arena, q, 3072, 1536, 1536, 1536);
  // 3) kvns = hs @ Wkva (N=576)
  gemm_bf16<<<dim3(9, 32), 256, 0, stream>>>(hs_c, Wkva_c, kvns, 576, 2048, 2048);
  rmsnorm_ip<512><<<T, 256, 0, stream>>>(kvns, kvln_c, 576);
  // 4) kv = kv_c_normed @ Wkvb
  t_cvt<<<dim3(64, 8), 256, 0, stream>>>(Wkvb_f, arena, 512, 4096);
  gemm_v2<false><<<dim3(32, 32), 256, 0, stream>>>(kvns, arena, kv, 4096, 512, 576, 512);
  // 5) K/V assembly (K rope fused in prep_kf)
  prep_kf<<<T, 256, 0, stream>>>(kv, kvns, Kf);
  prep_vt<<<dim3(32, 32), 256, 0, stream>>>(kv, Vt);
  // 6) attention (paired q-tiles, swapped-QK softmax, fused Q rope)
  attn_v6<<<512, 256, 0, stream>>>(q, Kf, Vt, attnb);
  // 7) out = attn @ Wo (f32 output)
  t_cvt<<<dim3(32, 32), 256, 0, stream>>>(Wo_f, arena, 2048, 2048);
  gemm_v2<true><<<dim3(16, 32), 256, 0, stream>>>(attnb, arena, d_out, 2048, 2048, 2048, 2048);
}

// Round 13
// 351.287 us; speedup vs baseline: 2.1587x; 1.0545x over previous
//
#include <hip/hip_runtime.h>
#include <hip/hip_bf16.h>

typedef __hip_bfloat16 bf16;
typedef short bf16x8 __attribute__((ext_vector_type(8)));
typedef float f32x4 __attribute__((ext_vector_type(4)));

#define MFMA16(a, b, c) __builtin_amdgcn_mfma_f32_16x16x32_bf16((a), (b), (c), 0, 0, 0)

__device__ __forceinline__ short f2bs(float f) {
  bf16 h = __float2bfloat16(f);
  return __builtin_bit_cast(short, h);
}
__device__ __forceinline__ float bs2f(short s) {
  return __bfloat162float(__builtin_bit_cast(bf16, s));
}

// async global->LDS, 16B per lane; LDS dest = wave-uniform base + lane*16
__device__ __forceinline__ void gload16(const void* g, const void* l) {
  __builtin_amdgcn_global_load_lds(
      (const __attribute__((address_space(1))) unsigned int*)g,
      (__attribute__((address_space(3))) unsigned int*)l, 16, 0, 0);
}

// ---------------------------------------------------------------------------
__global__ __launch_bounds__(256) void cvt_f32_bf16(const float* __restrict__ src,
                                                    bf16* __restrict__ dst, int n8) {
  int i = blockIdx.x * 256 + threadIdx.x;
  if (i >= n8) return;
  const float4* s = (const float4*)src;
  float4 a = s[2 * i], b = s[2 * i + 1];
  union { uint4 v; short sh[8]; } o;
  o.sh[0] = f2bs(a.x); o.sh[1] = f2bs(a.y); o.sh[2] = f2bs(a.z); o.sh[3] = f2bs(a.w);
  o.sh[4] = f2bs(b.x); o.sh[5] = f2bs(b.y); o.sh[6] = f2bs(b.z); o.sh[7] = f2bs(b.w);
  ((uint4*)dst)[i] = o.v;
}

// ---------------------------------------------------------------------------
// Fused f32->bf16 + transpose: dst[N][K](bf16) = src[K][N](f32)^T. 64x64 tiles.
// ---------------------------------------------------------------------------
__global__ __launch_bounds__(256) void t_cvt(const float* __restrict__ src,
                                             bf16* __restrict__ dst, int K, int N) {
  __shared__ __align__(16) short Ts[64][72];
  const long n0 = (long)blockIdx.x * 64, k0 = (long)blockIdx.y * 64;
  const int r = threadIdx.x >> 2, c4 = threadIdx.x & 3;
  const float* s = src + (k0 + r) * (long)N + n0 + c4 * 16;
  #pragma unroll
  for (int j = 0; j < 4; ++j) {
    float4 v = *(const float4*)(s + j * 4);
    Ts[r][c4 * 16 + j * 4 + 0] = f2bs(v.x);
    Ts[r][c4 * 16 + j * 4 + 1] = f2bs(v.y);
    Ts[r][c4 * 16 + j * 4 + 2] = f2bs(v.z);
    Ts[r][c4 * 16 + j * 4 + 3] = f2bs(v.w);
  }
  __syncthreads();
  union { uint4 v; short sh[8]; } o0, o1;
  #pragma unroll
  for (int j = 0; j < 8; ++j) o0.sh[j] = Ts[c4 * 16 + j][r];
  #pragma unroll
  for (int j = 0; j < 8; ++j) o1.sh[j] = Ts[c4 * 16 + 8 + j][r];
  *(uint4*)(dst + (n0 + r) * (long)K + k0 + c4 * 16)     = o0.v;
  *(uint4*)(dst + (n0 + r) * (long)K + k0 + c4 * 16 + 8) = o1.v;
}

// ---------------------------------------------------------------------------
// gemm_v4: C = A[M,K] @ BT[N,K]^T. BM=BN=128, BK=64, 4 waves, quadrants.
// LDS rows 128B with XOR(row&7) 16B-slot swizzle (conflict-free ds_read_b128),
// applied via pre-swizzled per-lane global source; linear global_load_lds dest.
// T1 XCD block swizzle. F32OUT selects C dtype.
// ---------------------------------------------------------------------------
template<bool F32OUT>
__global__ __launch_bounds__(256) void gemm_v4(
    const bf16* __restrict__ A, const bf16* __restrict__ BT, void* __restrict__ Cv,
    int N, int K, int lda, int ldb)
{
  __shared__ __align__(16) short As[128 * 64];
  __shared__ __align__(16) short Bs[128 * 64];
  const int tid = threadIdx.x, lane = tid & 63, w = tid >> 6;
  const int l15 = lane & 15, l4 = lane >> 4;
  const int wr = w >> 1, wc = w & 1;
  const int nx = gridDim.x, nwg = nx * gridDim.y;
  const int lin = blockIdx.y * nx + blockIdx.x;
  const int sl = (lin & 7) * (nwg >> 3) + (lin >> 3);   // nwg % 8 == 0
  const long bm = (long)(sl / nx) * 128, bn = (long)(sl % nx) * 128;
  f32x4 acc[4][4] = {};

  // staging decomposition: chunk c = j*256+tid -> row = j*32 + (tid>>3),
  // stored slot = tid&7, content slot cs = (tid&7) ^ ((tid>>3)&7)
  const int srow = tid >> 3;
  const int scs = (tid & 7) ^ (srow & 7);
  const int rsw = l15 & 7;  // fragment-read swizzle (row&7 == l15&7)

  for (int k0 = 0; k0 < K; k0 += 64) {
    __syncthreads();
    #pragma unroll
    for (int j = 0; j < 4; ++j) {
      const unsigned lb = __builtin_amdgcn_readfirstlane((j * 256 + w * 64) * 16);
      gload16(A + (bm + j * 32 + srow) * (long)lda + k0 + scs * 8, (char*)As + lb);
      gload16(BT + (bn + j * 32 + srow) * (long)ldb + k0 + scs * 8, (char*)Bs + lb);
    }
    __syncthreads();
    #pragma unroll
    for (int kk = 0; kk < 2; ++kk) {
      bf16x8 a[4], b[4];
      const int slot = (kk * 4 + l4) ^ rsw;
      #pragma unroll
      for (int mi = 0; mi < 4; ++mi)
        a[mi] = *(const bf16x8*)&As[(wr * 64 + mi * 16 + l15) * 64 + slot * 8];
      #pragma unroll
      for (int ni = 0; ni < 4; ++ni)
        b[ni] = *(const bf16x8*)&Bs[(wc * 64 + ni * 16 + l15) * 64 + slot * 8];
      #pragma unroll
      for (int mi = 0; mi < 4; ++mi)
        #pragma unroll
        for (int ni = 0; ni < 4; ++ni)
          acc[mi][ni] = MFMA16(a[mi], b[ni], acc[mi][ni]);
    }
  }
  #pragma unroll
  for (int mi = 0; mi < 4; ++mi)
    #pragma unroll
    for (int ni = 0; ni < 4; ++ni)
      #pragma unroll
      for (int r = 0; r < 4; ++r) {
        long row = bm + wr * 64 + mi * 16 + l4 * 4 + r;
        long col = bn + wc * 64 + ni * 16 + l15;
        float v = acc[mi][ni][r];
        if (F32OUT) ((float*)Cv)[row * N + col] = v;
        else        ((bf16*)Cv)[row * N + col] = __float2bfloat16(v);
      }
}

// ---------------------------------------------------------------------------
// r2-proven GEMM (BM=128, BN=64, BK=32), direct B[K][N], for N=576. +T1 swizzle.
// ---------------------------------------------------------------------------
__global__ __launch_bounds__(256) void gemm_bf16(
    const bf16* __restrict__ A, const bf16* __restrict__ B, bf16* __restrict__ C,
    int N, int K, int lda)
{
  __shared__ __align__(16) short As[128][40];
  __shared__ __align__(16) short Bt[64][40];
  const int tid = threadIdx.x;
  const int lane = tid & 63, w = tid >> 6;
  const int l15 = lane & 15, l4 = lane >> 4;
  const int nx = gridDim.x, nwg = nx * gridDim.y;
  const int lin = blockIdx.y * nx + blockIdx.x;
  const int sl = (lin & 7) * (nwg >> 3) + (lin >> 3);
  const long bm = (long)(sl / nx) * 128;
  const long bn = (long)(sl % nx) * 64;

  f32x4 acc[2][4] = {};
  const int arow = tid >> 1, ac8 = (tid & 1) * 16;
  const int bkr = tid >> 3, bn8 = (tid & 7) * 8;

  for (int k0 = 0; k0 < K; k0 += 32) {
    __syncthreads();
    {
      const uint4* src = (const uint4*)(A + (bm + arow) * (long)lda + k0 + ac8);
      *(uint4*)&As[arow][ac8]     = src[0];
      *(uint4*)&As[arow][ac8 + 8] = src[1];
    }
    {
      union { uint4 v; short s[8]; } u;
      u.v = *(const uint4*)(B + (long)(k0 + bkr) * N + bn + bn8);
      const int swz = ((bn8 >> 3) & 3) << 3;
      #pragma unroll
      for (int i = 0; i < 8; ++i)
        Bt[bn8 + i][bkr ^ swz] = u.s[i];
    }
    __syncthreads();
    bf16x8 a0 = *(const bf16x8*)&As[w * 32 + l15][l4 * 8];
    bf16x8 a1 = *(const bf16x8*)&As[w * 32 + 16 + l15][l4 * 8];
    #pragma unroll
    for (int ni = 0; ni < 4; ++ni) {
      int n = ni * 16 + l15;
      int kb = (l4 * 8) ^ (((n >> 3) & 3) << 3);
      bf16x8 bb = *(const bf16x8*)&Bt[n][kb];
      acc[0][ni] = MFMA16(a0, bb, acc[0][ni]);
      acc[1][ni] = MFMA16(a1, bb, acc[1][ni]);
    }
  }
  #pragma unroll
  for (int mi = 0; mi < 2; ++mi)
    #pragma unroll
    for (int ni = 0; ni < 4; ++ni)
      #pragma unroll
      for (int r = 0; r < 4; ++r) {
        long row = bm + w * 32 + mi * 16 + l4 * 4 + r;
        long col = bn + ni * 16 + l15;
        C[row * N + col] = __float2bfloat16(acc[mi][ni][r]);
      }
}

// ---------------------------------------------------------------------------
template<int C>
__global__ __launch_bounds__(256) void rmsnorm_ip(bf16* __restrict__ x,
                                                  const bf16* __restrict__ w,
                                                  int stride)
{
  constexpr int PER = C / 256;
  const int row = blockIdx.x, tid = threadIdx.x;
  bf16* xr = x + (long)row * stride;
  float v[PER];
  float ss = 0.f;
  #pragma unroll
  for (int k = 0; k < PER; ++k) {
    float f = __bfloat162float(xr[tid + k * 256]);
    v[k] = f; ss += f * f;
  }
  #pragma unroll
  for (int off = 1; off < 64; off <<= 1) ss += __shfl_xor(ss, off);
  __shared__ float red[4];
  if ((tid & 63) == 0) red[tid >> 6] = ss;
  __syncthreads();
  float tot = red[0] + red[1] + red[2] + red[3];
  float scale = rsqrtf(tot / (float)C + 1e-6f);
  #pragma unroll
  for (int k = 0; k < PER; ++k)
    xr[tid + k * 256] =
        __float2bfloat16(v[k] * scale * __bfloat162float(w[tid + k * 256]));
}

// ---------------------------------------------------------------------------
// Build Kf[bh][t][192], rows pre-swizzled: stored 16B-slot s = content s^(t&7).
// ---------------------------------------------------------------------------
__global__ __launch_bounds__(256) void prep_kf(const bf16* __restrict__ kv,
                                               const bf16* __restrict__ kvns,
                                               bf16* __restrict__ Kf)
{
  __shared__ short pe[64];
  const int t = blockIdx.x, tid = threadIdx.x;
  if (tid < 32) {
    int i = tid;
    float p = (float)(t & 2047);
    float freq = powf(10000.0f, -(float)i / 32.0f);
    float sn, cs;
    sincosf(p * freq, &sn, &cs);
    float y1 = __bfloat162float(kvns[(long)t * 576 + 512 + 2 * i]);
    float y2 = __bfloat162float(kvns[(long)t * 576 + 512 + 2 * i + 1]);
    pe[2 * i]     = f2bs(y1 * cs - y2 * sn);
    pe[2 * i + 1] = f2bs(y2 * cs + y1 * sn);
  }
  __syncthreads();
  const int b = t >> 11, ts = t & 2047;
  const int swz = t & 7;
  #pragma unroll
  for (int uu = 0; uu < 2; ++uu) {
    int u = uu * 256 + tid;
    if (u >= 384) break;
    int h = u / 24, s = u % 24;
    int cs = s ^ swz;
    uint4 val;
    if (cs < 16) val = *(const uint4*)(kv + (long)t * 4096 + h * 256 + cs * 8);
    else         val = *(const uint4*)&pe[(cs - 16) * 8];
    *(uint4*)(Kf + ((long)(b * 16 + h) * 2048 + ts) * 192 + s * 8) = val;
  }
}

// ---------------------------------------------------------------------------
// Build Vt[bh][d][2048] = V^T, 64-key blocks pre-swizzled by (d&7).
// ---------------------------------------------------------------------------
__global__ __launch_bounds__(256) void prep_vt(const bf16* __restrict__ kv,
                                               bf16* __restrict__ Vt)
{
  __shared__ __align__(16) short Ts[64][136];
  const int kb = blockIdx.x, bh = blockIdx.y, b = bh >> 4, h = bh & 15;
  const int k0 = kb * 64, tid = threadIdx.x;
  #pragma unroll
  for (int j = 0; j < 4; ++j) {
    int u = j * 256 + tid;
    int kr = u >> 4, seg = u & 15;
    *(uint4*)&Ts[kr][seg * 8] = *(const uint4*)(kv +
        (long)(b * 2048 + k0 + kr) * 4096 + h * 256 + 128 + seg * 8);
  }
  __syncthreads();
  #pragma unroll
  for (int j = 0; j < 4; ++j) {
    int u = j * 256 + tid;
    int d = u >> 3, s = u & 7;
    int cs = s ^ (d & 7);
    union { uint4 v; short sh[8]; } o;
    #pragma unroll
    for (int jj = 0; jj < 8; ++jj) o.sh[jj] = Ts[cs * 8 + jj][d];
    *(uint4*)(Vt + ((long)bh * 128 + d) * 2048 + k0 + s * 8) = o.v;
  }
}

// ---------------------------------------------------------------------------
// attn_v6 (r12-proven): swapped-QK softmax + q-tile pairing + fused Q-RoPE.
// ---------------------------------------------------------------------------
__global__ __launch_bounds__(256) void attn_v6(const bf16* __restrict__ q,
                                               const bf16* __restrict__ Kf,
                                               const bf16* __restrict__ Vt,
                                               bf16* __restrict__ attn)
{
  __shared__ __align__(16) short Ks[64 * 192];
  __shared__ __align__(16) short Vs[128 * 64];
  __shared__ __align__(16) short Ps[4][16 * 64];
  const float SC = 0.07216878364870323f;  // 192^-0.5
  const int tid = threadIdx.x, lane = tid & 63, w = tid >> 6;
  const int l15 = lane & 15, l4 = lane >> 4;
  const int lin = blockIdx.x;
  const int x = lin & 7, j = lin >> 3;
  const int bh = x * 4 + (j >> 4), p = j & 15;
  const int b = bh >> 4, h = bh & 15;
  const unsigned lbase = __builtin_amdgcn_readfirstlane(w * 64 * 16);

  #pragma unroll
  for (int half = 0; half < 2; ++half) {
    const int qt = half ? (31 - p) : p;
    const long qrow0 = (long)b * 2048 + qt * 64;
    const int rowt = qt * 64 + w * 16 + l15;

    bf16x8 qf[6];
    {
      const short* qrow = (const short*)q + (qrow0 + w * 16 + l15) * 3072 + h * 192;
      #pragma unroll
      for (int kc = 0; kc < 6; ++kc)
        qf[kc] = *(const bf16x8*)(qrow + kc * 32 + l4 * 8);
    }
    {  // fused GPT-J RoPE on pe fragments (cols 128..191 = kc 4,5)
      float pos = (float)rowt;
      #pragma unroll
      for (int kc = 4; kc < 6; ++kc)
        #pragma unroll
        for (int pr = 0; pr < 4; ++pr) {
          int i = (kc - 4) * 16 + l4 * 4 + pr;
          float freq = __expf((float)i * -0.28782313662425572f);  // 10000^(-i/32)
          float sn, cs;
          sincosf(pos * freq, &sn, &cs);
          float x1 = bs2f(qf[kc][2 * pr]), x2 = bs2f(qf[kc][2 * pr + 1]);
          qf[kc][2 * pr]     = f2bs(x1 * cs - x2 * sn);
          qf[kc][2 * pr + 1] = f2bs(x2 * cs + x1 * sn);
        }
    }
    f32x4 o[8] = {};
    float mreg = -1e30f, ls = 0.f;
    const int nch = qt + 1;

    {  // prologue: stage K chunk 0
      const char* ksrc = (const char*)(Kf + (long)bh * 2048 * 192);
      #pragma unroll
      for (int jj = 0; jj < 6; ++jj)
        gload16(ksrc + (jj * 256 + tid) * 16, (char*)Ks + jj * 4096 + lbase);
    }
    __syncthreads();

    for (int c = 0; c < nch; ++c) {
      const int k0 = c * 64;
      {  // issue V(c) — drains at mid-barrier, hidden under QK+softmax
        #pragma unroll
        for (int jj = 0; jj < 4; ++jj) {
          int seg = jj * 256 + tid;
          const bf16* vsrc = Vt + ((long)bh * 128 + (seg >> 3)) * 2048 + k0 + (seg & 7) * 8;
          gload16(vsrc, (char*)Vs + jj * 4096 + lbase);
        }
      }
      __builtin_amdgcn_s_setprio(1);
      f32x4 s[4] = {};
      #pragma unroll
      for (int kc = 0; kc < 6; ++kc)
        #pragma unroll
        for (int kg = 0; kg < 4; ++kg) {
          int row = kg * 16 + l15;
          int slot = (kc * 4 + l4) ^ (l15 & 7);
          bf16x8 kb = *(const bf16x8*)&Ks[row * 192 + slot * 8];
          s[kg] = MFMA16(kb, qf[kc], s[kg]);   // SWAPPED: D[key][qrow]
        }
      __builtin_amdgcn_s_setprio(0);

      const bool diag = (c == qt);
      float pk[16];
      #pragma unroll
      for (int kg = 0; kg < 4; ++kg)
        #pragma unroll
        for (int r = 0; r < 4; ++r) {
          float v = s[kg][r] * SC;
          if (diag && (k0 + kg * 16 + l4 * 4 + r > rowt)) v = -1e30f;
          pk[kg * 4 + r] = v;
        }
      float cm = pk[0];
      #pragma unroll
      for (int i = 1; i < 16; ++i) cm = fmaxf(cm, pk[i]);
      cm = fmaxf(cm, __shfl_xor(cm, 16));
      cm = fmaxf(cm, __shfl_xor(cm, 32));
      if (__ballot(cm > mreg + 8.0f)) {  // defer-max rescale (wave-uniform)
        float mn = fmaxf(mreg, cm);
        float al = __expf(mreg - mn);
        ls *= al;
        float af[4];
        #pragma unroll
        for (int r = 0; r < 4; ++r) af[r] = __shfl(al, l4 * 4 + r);
        #pragma unroll
        for (int f = 0; f < 8; ++f)
          #pragma unroll
          for (int r = 0; r < 4; ++r) o[f][r] *= af[r];
        mreg = mn;
      }
      float ps = 0.f;
      #pragma unroll
      for (int i = 0; i < 16; ++i) { pk[i] = __expf(pk[i] - mreg); ps += pk[i]; }
      ps += __shfl_xor(ps, 16);
      ps += __shfl_xor(ps, 32);
      ls += ps;
      #pragma unroll
      for (int kg = 0; kg < 4; ++kg)
        #pragma unroll
        for (int pr = 0; pr < 2; ++pr) {
          int key2 = kg * 16 + l4 * 4 + pr * 2;
          int sl = (key2 >> 3) ^ (l15 & 7);
          unsigned lo = (unsigned short)f2bs(pk[kg * 4 + pr * 2]);
          unsigned hi = (unsigned short)f2bs(pk[kg * 4 + pr * 2 + 1]);
          *(unsigned*)&Ps[w][l15 * 64 + sl * 8 + (key2 & 7)] = lo | (hi << 16);
        }
      __syncthreads();  // mid-barrier: V(c) landed; Ks reads + Ps writes done

      if (c + 1 < nch) {  // issue K(c+1) — drains at end-barrier, under PV
        const char* ksrc = (const char*)(Kf + ((long)bh * 2048 + k0 + 64) * 192);
        #pragma unroll
        for (int jj = 0; jj < 6; ++jj)
          gload16(ksrc + (jj * 256 + tid) * 16, (char*)Ks + jj * 4096 + lbase);
      }

      __builtin_amdgcn_s_setprio(1);
      #pragma unroll
      for (int ks = 0; ks < 2; ++ks) {
        int psl = (ks * 4 + l4) ^ (l15 & 7);
        bf16x8 pa = *(const bf16x8*)&Ps[w][l15 * 64 + psl * 8];
        #pragma unroll
        for (int f = 0; f < 8; ++f) {
          int vrow = f * 16 + l15;
          int vsl = (ks * 4 + l4) ^ (l15 & 7);
          bf16x8 bv = *(const bf16x8*)&Vs[vrow * 64 + vsl * 8];
          o[f] = MFMA16(pa, bv, o[f]);
        }
      }
      __builtin_amdgcn_s_setprio(0);
      __syncthreads();  // end-barrier: K(c+1) landed; Vs reads done
    }

    #pragma unroll
    for (int r = 0; r < 4; ++r) {
      float lsr = __shfl(ls, l4 * 4 + r);
      float inv = 1.0f / lsr;
      long t = qrow0 + w * 16 + l4 * 4 + r;
      bf16* dst = attn + t * 2048 + h * 128;
      #pragma unroll
      for (int f = 0; f < 8; ++f)
        dst[f * 16 + l15] = __float2bfloat16(o[f][r] * inv);
    }
  }
}

// ---------------------------------------------------------------------------
extern "C" void kernel_launch(void* const* d_in, const int* in_sizes, int n_in,
                              void* d_out, int out_size, void* d_ws, size_t ws_size,
                              hipStream_t stream) {
  const int T = 4096;
  const float* hs_f   = (const float*)d_in[1];
  const float* Wqa_f  = (const float*)d_in[2];
  const float* qln_f  = (const float*)d_in[3];
  const float* Wqb_f  = (const float*)d_in[4];
  const float* Wkva_f = (const float*)d_in[5];
  const float* kvln_f = (const float*)d_in[6];
  const float* Wkvb_f = (const float*)d_in[7];
  const float* Wo_f   = (const float*)d_in[8];

  bf16* base = (bf16*)d_ws;
  bf16* hs_c   = base;                      // 8388608   (dead after gemm3)  | Kf overlay
  bf16* Wkva_c = base + 8388608;            // 1179648
  bf16* ckq    = base + 9568256;            // 6291456
  bf16* qln_c  = base + 15859712;           // 1536
  bf16* kvln_c = base + 15861248;           // 512
  bf16* arena  = base + 15861760;           // 4718592 (W^T staging, serially reused)
  bf16* q      = base + 20580352;           // 12582912
  bf16* kvns   = base + 33163264;           // 2359296 (T x 576)
  bf16* kv     = base + 35522560;           // 16777216 | attn out overlay
  bf16* Vt     = base + 52299776;           // 8388608
  bf16* Kf     = base;                      // 12582912, overlays hs_c/Wkva_c/ckq head
  bf16* attnb  = kv;

  cvt_f32_bf16<<<(8388608 / 8 + 255) / 256, 256, 0, stream>>>(hs_f, hs_c, 8388608 / 8);
  cvt_f32_bf16<<<(1179648 / 8 + 255) / 256, 256, 0, stream>>>(Wkva_f, Wkva_c, 1179648 / 8);
  cvt_f32_bf16<<<1, 256, 0, stream>>>(qln_f, qln_c, 1536 / 8);
  cvt_f32_bf16<<<1, 256, 0, stream>>>(kvln_f, kvln_c, 512 / 8);

  // 1) ckq = hs @ Wqa
  t_cvt<<<dim3(24, 32), 256, 0, stream>>>(Wqa_f, arena, 2048, 1536);
  gemm_v4<false><<<dim3(12, 32), 256, 0, stream>>>(hs_c, arena, ckq, 1536, 2048, 2048, 2048);
  rmsnorm_ip<1536><<<T, 256, 0, stream>>>(ckq, qln_c, 1536);
  // 2) q = q_c @ Wqb (q_pe raw; roped in-register inside attn)
  t_cvt<<<dim3(48, 24), 256, 0, stream>>>(Wqb_f, arena, 1536, 3072);
  gemm_v4<false><<<dim3(24, 32), 256, 0, stream>>>(ckq, arena, q, 3072, 1536, 1536, 1536);
  // 3) kvns = hs @ Wkva (N=576)
  gemm_bf16<<<dim3(9, 32), 256, 0, stream>>>(hs_c, Wkva_c, kvns, 576, 2048, 2048);
  rmsnorm_ip<512><<<T, 256, 0, stream>>>(kvns, kvln_c, 576);
  // 4) kv = kv_c_normed @ Wkvb
  t_cvt<<<dim3(64, 8), 256, 0, stream>>>(Wkvb_f, arena, 512, 4096);
  gemm_v4<false><<<dim3(32, 32), 256, 0, stream>>>(kvns, arena, kv, 4096, 512, 576, 512);
  // 5) K/V assembly (K rope fused in prep_kf)
  prep_kf<<<T, 256, 0, stream>>>(kv, kvns, Kf);
  prep_vt<<<dim3(32, 32), 256, 0, stream>>>(kv, Vt);
  // 6) attention (r12-proven attn_v6)
  attn_v6<<<512, 256, 0, stream>>>(q, Kf, Vt, attnb);
  // 7) out = attn @ Wo (f32 output)
  t_cvt<<<dim3(32, 32), 256, 0, stream>>>(Wo_f, arena, 2048, 2048);
  gemm_v4<true><<<dim3(16, 32), 256, 0, stream>>>(attnb, arena, d_out, 2048, 2048, 2048, 2048);
}

// Round 14
// 323.029 us; speedup vs baseline: 2.3475x; 1.0875x over previous
//
#include <hip/hip_runtime.h>
#include <hip/hip_bf16.h>

typedef __hip_bfloat16 bf16;
typedef short bf16x8 __attribute__((ext_vector_type(8)));
typedef float f32x4 __attribute__((ext_vector_type(4)));

#define MFMA16(a, b, c) __builtin_amdgcn_mfma_f32_16x16x32_bf16((a), (b), (c), 0, 0, 0)

__device__ __forceinline__ short f2bs(float f) {
  bf16 h = __float2bfloat16(f);
  return __builtin_bit_cast(short, h);
}
__device__ __forceinline__ float bs2f(short s) {
  return __bfloat162float(__builtin_bit_cast(bf16, s));
}

// async global->LDS, 16B per lane; LDS dest = wave-uniform base + lane*16
__device__ __forceinline__ void gload16(const void* g, const void* l) {
  __builtin_amdgcn_global_load_lds(
      (const __attribute__((address_space(1))) unsigned int*)g,
      (__attribute__((address_space(3))) unsigned int*)l, 16, 0, 0);
}

// ---------------------------------------------------------------------------
// Batched f32->bf16 conversion: 3 segments (hs, q_ln_w, kv_ln_w).
// ---------------------------------------------------------------------------
__global__ __launch_bounds__(256) void cvt3(
    const float* __restrict__ s0, bf16* __restrict__ d0, int n0,
    const float* __restrict__ s1, bf16* __restrict__ d1, int n1,
    const float* __restrict__ s2, bf16* __restrict__ d2)
{
  int i = blockIdx.x * 256 + threadIdx.x;
  const float* s; bf16* d; int idx;
  if (i < n0)            { s = s0; d = d0; idx = i; }
  else if (i < n0 + n1)  { s = s1; d = d1; idx = i - n0; }
  else                   { s = s2; d = d2; idx = i - n0 - n1; }
  const float4* sp = (const float4*)s;
  float4 a = sp[2 * idx], b = sp[2 * idx + 1];
  union { uint4 v; short sh[8]; } o;
  o.sh[0] = f2bs(a.x); o.sh[1] = f2bs(a.y); o.sh[2] = f2bs(a.z); o.sh[3] = f2bs(a.w);
  o.sh[4] = f2bs(b.x); o.sh[5] = f2bs(b.y); o.sh[6] = f2bs(b.z); o.sh[7] = f2bs(b.w);
  ((uint4*)d)[idx] = o.v;
}

// ---------------------------------------------------------------------------
// Fused f32->bf16 + transpose: dst[N][K](bf16) = src[K][N](f32)^T. 64x64 tiles.
// ---------------------------------------------------------------------------
__global__ __launch_bounds__(256) void t_cvt(const float* __restrict__ src,
                                             bf16* __restrict__ dst, int K, int N) {
  __shared__ __align__(16) short Ts[64][72];
  const long n0 = (long)blockIdx.x * 64, k0 = (long)blockIdx.y * 64;
  const int r = threadIdx.x >> 2, c4 = threadIdx.x & 3;
  const float* s = src + (k0 + r) * (long)N + n0 + c4 * 16;
  #pragma unroll
  for (int j = 0; j < 4; ++j) {
    float4 v = *(const float4*)(s + j * 4);
    Ts[r][c4 * 16 + j * 4 + 0] = f2bs(v.x);
    Ts[r][c4 * 16 + j * 4 + 1] = f2bs(v.y);
    Ts[r][c4 * 16 + j * 4 + 2] = f2bs(v.z);
    Ts[r][c4 * 16 + j * 4 + 3] = f2bs(v.w);
  }
  __syncthreads();
  union { uint4 v; short sh[8]; } o0, o1;
  #pragma unroll
  for (int j = 0; j < 8; ++j) o0.sh[j] = Ts[c4 * 16 + j][r];
  #pragma unroll
  for (int j = 0; j < 8; ++j) o1.sh[j] = Ts[c4 * 16 + 8 + j][r];
  *(uint4*)(dst + (n0 + r) * (long)K + k0 + c4 * 16)     = o0.v;
  *(uint4*)(dst + (n0 + r) * (long)K + k0 + c4 * 16 + 8) = o1.v;
}

// ---------------------------------------------------------------------------
// gemm_v4: C = A[M,K] @ BT[N,K]^T. BM=BN=128, BK=64, 4 waves, quadrants.
// XOR(row&7)-swizzled LDS (conflict-free), T1 XCD swizzle. ldc = primary C
// stride. Optional split epilogue: cols >= ncut -> C2[row*640 + col-ncut].
// ---------------------------------------------------------------------------
template<bool F32OUT>
__global__ __launch_bounds__(256) void gemm_v4(
    const bf16* __restrict__ A, const bf16* __restrict__ BT, void* __restrict__ Cv,
    int N, int K, int lda, int ldb, int ldc, bf16* __restrict__ C2, int ncut)
{
  __shared__ __align__(16) short As[128 * 64];
  __shared__ __align__(16) short Bs[128 * 64];
  const int tid = threadIdx.x, lane = tid & 63, w = tid >> 6;
  const int l15 = lane & 15, l4 = lane >> 4;
  const int wr = w >> 1, wc = w & 1;
  const int nx = gridDim.x, nwg = nx * gridDim.y;
  const int lin = blockIdx.y * nx + blockIdx.x;
  const int sl = (lin & 7) * (nwg >> 3) + (lin >> 3);   // nwg % 8 == 0
  const long bm = (long)(sl / nx) * 128, bn = (long)(sl % nx) * 128;
  f32x4 acc[4][4] = {};

  const int srow = tid >> 3;
  const int scs = (tid & 7) ^ (srow & 7);
  const int rsw = l15 & 7;

  for (int k0 = 0; k0 < K; k0 += 64) {
    __syncthreads();
    #pragma unroll
    for (int j = 0; j < 4; ++j) {
      const unsigned lb = __builtin_amdgcn_readfirstlane((j * 256 + w * 64) * 16);
      gload16(A + (bm + j * 32 + srow) * (long)lda + k0 + scs * 8, (char*)As + lb);
      gload16(BT + (bn + j * 32 + srow) * (long)ldb + k0 + scs * 8, (char*)Bs + lb);
    }
    __syncthreads();
    #pragma unroll
    for (int kk = 0; kk < 2; ++kk) {
      bf16x8 a[4], b[4];
      const int slot = (kk * 4 + l4) ^ rsw;
      #pragma unroll
      for (int mi = 0; mi < 4; ++mi)
        a[mi] = *(const bf16x8*)&As[(wr * 64 + mi * 16 + l15) * 64 + slot * 8];
      #pragma unroll
      for (int ni = 0; ni < 4; ++ni)
        b[ni] = *(const bf16x8*)&Bs[(wc * 64 + ni * 16 + l15) * 64 + slot * 8];
      #pragma unroll
      for (int mi = 0; mi < 4; ++mi)
        #pragma unroll
        for (int ni = 0; ni < 4; ++ni)
          acc[mi][ni] = MFMA16(a[mi], b[ni], acc[mi][ni]);
    }
  }
  #pragma unroll
  for (int mi = 0; mi < 4; ++mi)
    #pragma unroll
    for (int ni = 0; ni < 4; ++ni)
      #pragma unroll
      for (int r = 0; r < 4; ++r) {
        long row = bm + wr * 64 + mi * 16 + l4 * 4 + r;
        long col = bn + wc * 64 + ni * 16 + l15;
        float v = acc[mi][ni][r];
        if (F32OUT) {
          ((float*)Cv)[row * ldc + col] = v;
        } else if (C2 && col >= ncut) {
          C2[row * 640 + (col - ncut)] = __float2bfloat16(v);
        } else {
          ((bf16*)Cv)[row * (long)ldc + col] = __float2bfloat16(v);
        }
      }
}

// ---------------------------------------------------------------------------
template<int C>
__global__ __launch_bounds__(256) void rmsnorm_ip(bf16* __restrict__ x,
                                                  const bf16* __restrict__ w,
                                                  int stride)
{
  constexpr int PER = C / 256;
  const int row = blockIdx.x, tid = threadIdx.x;
  bf16* xr = x + (long)row * stride;
  float v[PER];
  float ss = 0.f;
  #pragma unroll
  for (int k = 0; k < PER; ++k) {
    float f = __bfloat162float(xr[tid + k * 256]);
    v[k] = f; ss += f * f;
  }
  #pragma unroll
  for (int off = 1; off < 64; off <<= 1) ss += __shfl_xor(ss, off);
  __shared__ float red[4];
  if ((tid & 63) == 0) red[tid >> 6] = ss;
  __syncthreads();
  float tot = red[0] + red[1] + red[2] + red[3];
  float scale = rsqrtf(tot / (float)C + 1e-6f);
  #pragma unroll
  for (int k = 0; k < PER; ++k)
    xr[tid + k * 256] =
        __float2bfloat16(v[k] * scale * __bfloat162float(w[tid + k * 256]));
}

// ---------------------------------------------------------------------------
// Build Kf[bh][t][192], rows pre-swizzled: stored 16B-slot s = content s^(t&7).
// kvns row stride 640.
// ---------------------------------------------------------------------------
__global__ __launch_bounds__(256) void prep_kf(const bf16* __restrict__ kv,
                                               const bf16* __restrict__ kvns,
                                               bf16* __restrict__ Kf)
{
  __shared__ short pe[64];
  const int t = blockIdx.x, tid = threadIdx.x;
  if (tid < 32) {
    int i = tid;
    float p = (float)(t & 2047);
    float freq = powf(10000.0f, -(float)i / 32.0f);
    float sn, cs;
    sincosf(p * freq, &sn, &cs);
    float y1 = __bfloat162float(kvns[(long)t * 640 + 512 + 2 * i]);
    float y2 = __bfloat162float(kvns[(long)t * 640 + 512 + 2 * i + 1]);
    pe[2 * i]     = f2bs(y1 * cs - y2 * sn);
    pe[2 * i + 1] = f2bs(y2 * cs + y1 * sn);
  }
  __syncthreads();
  const int b = t >> 11, ts = t & 2047;
  const int swz = t & 7;
  #pragma unroll
  for (int uu = 0; uu < 2; ++uu) {
    int u = uu * 256 + tid;
    if (u >= 384) break;
    int h = u / 24, s = u % 24;
    int cs = s ^ swz;
    uint4 val;
    if (cs < 16) val = *(const uint4*)(kv + (long)t * 4096 + h * 256 + cs * 8);
    else         val = *(const uint4*)&pe[(cs - 16) * 8];
    *(uint4*)(Kf + ((long)(b * 16 + h) * 2048 + ts) * 192 + s * 8) = val;
  }
}

// ---------------------------------------------------------------------------
// Build Vt[bh][d][2048] = V^T, 64-key blocks pre-swizzled by (d&7).
// ---------------------------------------------------------------------------
__global__ __launch_bounds__(256) void prep_vt(const bf16* __restrict__ kv,
                                               bf16* __restrict__ Vt)
{
  __shared__ __align__(16) short Ts[64][136];
  const int kb = blockIdx.x, bh = blockIdx.y, b = bh >> 4, h = bh & 15;
  const int k0 = kb * 64, tid = threadIdx.x;
  #pragma unroll
  for (int j = 0; j < 4; ++j) {
    int u = j * 256 + tid;
    int kr = u >> 4, seg = u & 15;
    *(uint4*)&Ts[kr][seg * 8] = *(const uint4*)(kv +
        (long)(b * 2048 + k0 + kr) * 4096 + h * 256 + 128 + seg * 8);
  }
  __syncthreads();
  #pragma unroll
  for (int j = 0; j < 4; ++j) {
    int u = j * 256 + tid;
    int d = u >> 3, s = u & 7;
    int cs = s ^ (d & 7);
    union { uint4 v; short sh[8]; } o;
    #pragma unroll
    for (int jj = 0; jj < 8; ++jj) o.sh[jj] = Ts[cs * 8 + jj][d];
    *(uint4*)(Vt + ((long)bh * 128 + d) * 2048 + k0 + s * 8) = o.v;
  }
}

// ---------------------------------------------------------------------------
// attn_v6 (r12-proven) + exp2 scale-fold: scores scaled by 192^-0.5*log2(e).
// ---------------------------------------------------------------------------
__global__ __launch_bounds__(256) void attn_v6(const bf16* __restrict__ q,
                                               const bf16* __restrict__ Kf,
                                               const bf16* __restrict__ Vt,
                                               bf16* __restrict__ attn)
{
  __shared__ __align__(16) short Ks[64 * 192];
  __shared__ __align__(16) short Vs[128 * 64];
  __shared__ __align__(16) short Ps[4][16 * 64];
  const float SC2 = 0.10411442245076847f;  // 192^-0.5 * log2(e)
  const int tid = threadIdx.x, lane = tid & 63, w = tid >> 6;
  const int l15 = lane & 15, l4 = lane >> 4;
  const int lin = blockIdx.x;
  const int x = lin & 7, j = lin >> 3;
  const int bh = x * 4 + (j >> 4), p = j & 15;
  const int b = bh >> 4, h = bh & 15;
  const unsigned lbase = __builtin_amdgcn_readfirstlane(w * 64 * 16);

  #pragma unroll
  for (int half = 0; half < 2; ++half) {
    const int qt = half ? (31 - p) : p;
    const long qrow0 = (long)b * 2048 + qt * 64;
    const int rowt = qt * 64 + w * 16 + l15;

    bf16x8 qf[6];
    {
      const short* qrow = (const short*)q + (qrow0 + w * 16 + l15) * 3072 + h * 192;
      #pragma unroll
      for (int kc = 0; kc < 6; ++kc)
        qf[kc] = *(const bf16x8*)(qrow + kc * 32 + l4 * 8);
    }
    {  // fused GPT-J RoPE on pe fragments (cols 128..191 = kc 4,5)
      float pos = (float)rowt;
      #pragma unroll
      for (int kc = 4; kc < 6; ++kc)
        #pragma unroll
        for (int pr = 0; pr < 4; ++pr) {
          int i = (kc - 4) * 16 + l4 * 4 + pr;
          float freq = __expf((float)i * -0.28782313662425572f);  // 10000^(-i/32)
          float sn, cs;
          sincosf(pos * freq, &sn, &cs);
          float x1 = bs2f(qf[kc][2 * pr]), x2 = bs2f(qf[kc][2 * pr + 1]);
          qf[kc][2 * pr]     = f2bs(x1 * cs - x2 * sn);
          qf[kc][2 * pr + 1] = f2bs(x2 * cs + x1 * sn);
        }
    }
    f32x4 o[8] = {};
    float mreg = -1e30f, ls = 0.f;
    const int nch = qt + 1;

    {  // prologue: stage K chunk 0
      const char* ksrc = (const char*)(Kf + (long)bh * 2048 * 192);
      #pragma unroll
      for (int jj = 0; jj < 6; ++jj)
        gload16(ksrc + (jj * 256 + tid) * 16, (char*)Ks + jj * 4096 + lbase);
    }
    __syncthreads();

    for (int c = 0; c < nch; ++c) {
      const int k0 = c * 64;
      {  // issue V(c) — drains at mid-barrier, hidden under QK+softmax
        #pragma unroll
        for (int jj = 0; jj < 4; ++jj) {
          int seg = jj * 256 + tid;
          const bf16* vsrc = Vt + ((long)bh * 128 + (seg >> 3)) * 2048 + k0 + (seg & 7) * 8;
          gload16(vsrc, (char*)Vs + jj * 4096 + lbase);
        }
      }
      __builtin_amdgcn_s_setprio(1);
      f32x4 s[4] = {};
      #pragma unroll
      for (int kc = 0; kc < 6; ++kc)
        #pragma unroll
        for (int kg = 0; kg < 4; ++kg) {
          int row = kg * 16 + l15;
          int slot = (kc * 4 + l4) ^ (l15 & 7);
          bf16x8 kb = *(const bf16x8*)&Ks[row * 192 + slot * 8];
          s[kg] = MFMA16(kb, qf[kc], s[kg]);   // SWAPPED: D[key][qrow]
        }
      __builtin_amdgcn_s_setprio(0);

      const bool diag = (c == qt);
      float pk[16];
      #pragma unroll
      for (int kg = 0; kg < 4; ++kg)
        #pragma unroll
        for (int r = 0; r < 4; ++r) {
          float v = s[kg][r] * SC2;
          if (diag && (k0 + kg * 16 + l4 * 4 + r > rowt)) v = -1e30f;
          pk[kg * 4 + r] = v;
        }
      float cm = pk[0];
      #pragma unroll
      for (int i = 1; i < 16; ++i) cm = fmaxf(cm, pk[i]);
      cm = fmaxf(cm, __shfl_xor(cm, 16));
      cm = fmaxf(cm, __shfl_xor(cm, 32));
      if (__ballot(cm > mreg + 8.0f)) {  // defer-max rescale (wave-uniform)
        float mn = fmaxf(mreg, cm);
        float al = exp2f(mreg - mn);
        ls *= al;
        float af[4];
        #pragma unroll
        for (int r = 0; r < 4; ++r) af[r] = __shfl(al, l4 * 4 + r);
        #pragma unroll
        for (int f = 0; f < 8; ++f)
          #pragma unroll
          for (int r = 0; r < 4; ++r) o[f][r] *= af[r];
        mreg = mn;
      }
      float ps = 0.f;
      #pragma unroll
      for (int i = 0; i < 16; ++i) { pk[i] = exp2f(pk[i] - mreg); ps += pk[i]; }
      ps += __shfl_xor(ps, 16);
      ps += __shfl_xor(ps, 32);
      ls += ps;
      #pragma unroll
      for (int kg = 0; kg < 4; ++kg)
        #pragma unroll
        for (int pr = 0; pr < 2; ++pr) {
          int key2 = kg * 16 + l4 * 4 + pr * 2;
          int sl = (key2 >> 3) ^ (l15 & 7);
          unsigned lo = (unsigned short)f2bs(pk[kg * 4 + pr * 2]);
          unsigned hi = (unsigned short)f2bs(pk[kg * 4 + pr * 2 + 1]);
          *(unsigned*)&Ps[w][l15 * 64 + sl * 8 + (key2 & 7)] = lo | (hi << 16);
        }
      __syncthreads();  // mid-barrier: V(c) landed; Ks reads + Ps writes done

      if (c + 1 < nch) {  // issue K(c+1) — drains at end-barrier, under PV
        const char* ksrc = (const char*)(Kf + ((long)bh * 2048 + k0 + 64) * 192);
        #pragma unroll
        for (int jj = 0; jj < 6; ++jj)
          gload16(ksrc + (jj * 256 + tid) * 16, (char*)Ks + jj * 4096 + lbase);
      }

      __builtin_amdgcn_s_setprio(1);
      #pragma unroll
      for (int ks = 0; ks < 2; ++ks) {
        int psl = (ks * 4 + l4) ^ (l15 & 7);
        bf16x8 pa = *(const bf16x8*)&Ps[w][l15 * 64 + psl * 8];
        #pragma unroll
        for (int f = 0; f < 8; ++f) {
          int vrow = f * 16 + l15;
          int vsl = (ks * 4 + l4) ^ (l15 & 7);
          bf16x8 bv = *(const bf16x8*)&Vs[vrow * 64 + vsl * 8];
          o[f] = MFMA16(pa, bv, o[f]);
        }
      }
      __builtin_amdgcn_s_setprio(0);
      __syncthreads();  // end-barrier: K(c+1) landed; Vs reads done
    }

    #pragma unroll
    for (int r = 0; r < 4; ++r) {
      float lsr = __shfl(ls, l4 * 4 + r);
      float inv = 1.0f / lsr;
      long t = qrow0 + w * 16 + l4 * 4 + r;
      bf16* dst = attn + t * 2048 + h * 128;
      #pragma unroll
      for (int f = 0; f < 8; ++f)
        dst[f * 16 + l15] = __float2bfloat16(o[f][r] * inv);
    }
  }
}

// ---------------------------------------------------------------------------
extern "C" void kernel_launch(void* const* d_in, const int* in_sizes, int n_in,
                              void* d_out, int out_size, void* d_ws, size_t ws_size,
                              hipStream_t stream) {
  const int T = 4096;
  const float* hs_f   = (const float*)d_in[1];
  const float* Wqa_f  = (const float*)d_in[2];
  const float* qln_f  = (const float*)d_in[3];
  const float* Wqb_f  = (const float*)d_in[4];
  const float* Wkva_f = (const float*)d_in[5];
  const float* kvln_f = (const float*)d_in[6];
  const float* Wkvb_f = (const float*)d_in[7];
  const float* Wo_f   = (const float*)d_in[8];

  bf16* base = (bf16*)d_ws;
  bf16* hs_c  = base;                       // 8,388,608  (dead after gemmA) | Kf overlay
  bf16* ckq   = base + 8388608;             // 6,291,456  (dead after gemm2) |
  bf16* qln_c = base + 14680064;            // 1536
  bf16* kvln_c= base + 14681600;            // 512
  bf16* arena = base + 14682112;            // 4,718,592 (BT staging, serially reused)
  bf16* q     = base + 19400704;            // 12,582,912
  bf16* kvns  = base + 31983616;            // 2,621,440 (T x 640)
  bf16* kv    = base + 34605056;            // 16,777,216 | attn out overlay
  bf16* Vt    = base + 51382272;            // 8,388,608  (ends 59,770,880 ≈ 119.5 MB)
  bf16* Kf    = base;                       // 12,582,912, overlays hs_c+ckq (both dead)
  bf16* attnb = kv;

  // 1) batched conversions (hs, q_ln, kv_ln): 1048576+192+64 = 4097*256 lanes
  cvt3<<<4097, 256, 0, stream>>>(hs_f, hs_c, 1048576, qln_f, qln_c, 192, kvln_f, kvln_c);

  // 2) BT for fused QKV-A GEMM: rows 0..1535 = Wqa^T, rows 1536..2111 = Wkva^T
  t_cvt<<<dim3(24, 32), 256, 0, stream>>>(Wqa_f, arena, 2048, 1536);
  t_cvt<<<dim3(9, 32), 256, 0, stream>>>(Wkva_f, arena + (size_t)1536 * 2048, 2048, 576);
  // 3) fused: [ckq | kvns] = hs @ [Wqa | Wkva]  (N=2176, split epilogue at 1536)
  gemm_v4<false><<<dim3(17, 32), 256, 0, stream>>>(hs_c, arena, ckq, 2176, 2048,
                                                   2048, 2048, 1536, kvns, 1536);
  rmsnorm_ip<1536><<<T, 256, 0, stream>>>(ckq, qln_c, 1536);
  rmsnorm_ip<512><<<T, 256, 0, stream>>>(kvns, kvln_c, 640);
  // 4) q = q_c @ Wqb (q_pe roped in-register inside attn)
  t_cvt<<<dim3(48, 24), 256, 0, stream>>>(Wqb_f, arena, 1536, 3072);
  gemm_v4<false><<<dim3(24, 32), 256, 0, stream>>>(ckq, arena, q, 3072, 1536,
                                                   1536, 1536, 3072, nullptr, 0);
  // 5) kv = kv_c_normed @ Wkvb
  t_cvt<<<dim3(64, 8), 256, 0, stream>>>(Wkvb_f, arena, 512, 4096);
  gemm_v4<false><<<dim3(32, 32), 256, 0, stream>>>(kvns, arena, kv, 4096, 512,
                                                   640, 512, 4096, nullptr, 0);
  // 6) K/V assembly (K rope fused in prep_kf)
  prep_kf<<<T, 256, 0, stream>>>(kv, kvns, Kf);
  prep_vt<<<dim3(32, 32), 256, 0, stream>>>(kv, Vt);
  // 7) attention
  attn_v6<<<512, 256, 0, stream>>>(q, Kf, Vt, attnb);
  // 8) out = attn @ Wo (f32 output)
  t_cvt<<<dim3(32, 32), 256, 0, stream>>>(Wo_f, arena, 2048, 2048);
  gemm_v4<true><<<dim3(16, 32), 256, 0, stream>>>(attnb, arena, d_out, 2048, 2048,
                                                  2048, 2048, 2048, nullptr, 0);
}

// Round 16
// 302.229 us; speedup vs baseline: 2.5091x; 1.0688x over previous
//
#include <hip/hip_runtime.h>
#include <hip/hip_bf16.h>

typedef __hip_bfloat16 bf16;
typedef short bf16x8 __attribute__((ext_vector_type(8)));
typedef float f32x4 __attribute__((ext_vector_type(4)));

#define MFMA16(a, b, c) __builtin_amdgcn_mfma_f32_16x16x32_bf16((a), (b), (c), 0, 0, 0)

__device__ __forceinline__ short f2bs(float f) {
  bf16 h = __float2bfloat16(f);
  return __builtin_bit_cast(short, h);
}
__device__ __forceinline__ float bs2f(short s) {
  return __bfloat162float(__builtin_bit_cast(bf16, s));
}

// async global->LDS, 16B per lane; LDS dest = wave-uniform base + lane*16
__device__ __forceinline__ void gload16(const void* g, const void* l) {
  __builtin_amdgcn_global_load_lds(
      (const __attribute__((address_space(1))) unsigned int*)g,
      (__attribute__((address_space(3))) unsigned int*)l, 16, 0, 0);
}

// ---------------------------------------------------------------------------
// Batched f32->bf16 conversion: 3 segments (hs, q_ln_w, kv_ln_w).
// ---------------------------------------------------------------------------
__global__ __launch_bounds__(256) void cvt3(
    const float* __restrict__ s0, bf16* __restrict__ d0, int n0,
    const float* __restrict__ s1, bf16* __restrict__ d1, int n1,
    const float* __restrict__ s2, bf16* __restrict__ d2)
{
  int i = blockIdx.x * 256 + threadIdx.x;
  const float* s; bf16* d; int idx;
  if (i < n0)            { s = s0; d = d0; idx = i; }
  else if (i < n0 + n1)  { s = s1; d = d1; idx = i - n0; }
  else                   { s = s2; d = d2; idx = i - n0 - n1; }
  const float4* sp = (const float4*)s;
  float4 a = sp[2 * idx], b = sp[2 * idx + 1];
  union { uint4 v; short sh[8]; } o;
  o.sh[0] = f2bs(a.x); o.sh[1] = f2bs(a.y); o.sh[2] = f2bs(a.z); o.sh[3] = f2bs(a.w);
  o.sh[4] = f2bs(b.x); o.sh[5] = f2bs(b.y); o.sh[6] = f2bs(b.z); o.sh[7] = f2bs(b.w);
  ((uint4*)d)[idx] = o.v;
}

// ---------------------------------------------------------------------------
// Fused f32->bf16 + transpose: dst[N][K](bf16) = src[K][N](f32)^T. 64x64 tiles.
// ---------------------------------------------------------------------------
__global__ __launch_bounds__(256) void t_cvt(const float* __restrict__ src,
                                             bf16* __restrict__ dst, int K, int N) {
  __shared__ __align__(16) short Ts[64][72];
  const long n0 = (long)blockIdx.x * 64, k0 = (long)blockIdx.y * 64;
  const int r = threadIdx.x >> 2, c4 = threadIdx.x & 3;
  const float* s = src + (k0 + r) * (long)N + n0 + c4 * 16;
  #pragma unroll
  for (int j = 0; j < 4; ++j) {
    float4 v = *(const float4*)(s + j * 4);
    Ts[r][c4 * 16 + j * 4 + 0] = f2bs(v.x);
    Ts[r][c4 * 16 + j * 4 + 1] = f2bs(v.y);
    Ts[r][c4 * 16 + j * 4 + 2] = f2bs(v.z);
    Ts[r][c4 * 16 + j * 4 + 3] = f2bs(v.w);
  }
  __syncthreads();
  union { uint4 v; short sh[8]; } o0, o1;
  #pragma unroll
  for (int j = 0; j < 8; ++j) o0.sh[j] = Ts[c4 * 16 + j][r];
  #pragma unroll
  for (int j = 0; j < 8; ++j) o1.sh[j] = Ts[c4 * 16 + 8 + j][r];
  *(uint4*)(dst + (n0 + r) * (long)K + k0 + c4 * 16)     = o0.v;
  *(uint4*)(dst + (n0 + r) * (long)K + k0 + c4 * 16 + 8) = o1.v;
}

// ---------------------------------------------------------------------------
// gemm core: C = A[M,K] @ BT[N,K]^T. BM=BN=128, BK=64, 4 waves, quadrants.
// XOR(row&7)-swizzled LDS (conflict-free), T1 XCD swizzle on (lin, nwg).
// Split epilogue: cols >= ncut -> C2[row*640 + col-ncut].
// ---------------------------------------------------------------------------
template<bool F32OUT>
__device__ __forceinline__ void gemm_core(
    short* As, short* Bs,
    const bf16* __restrict__ A, const bf16* __restrict__ BT, void* __restrict__ Cv,
    int N, int K, int lda, int ldb, int ldc, bf16* __restrict__ C2, int ncut,
    int nx, int nwg, int lin)
{
  const int tid = threadIdx.x, lane = tid & 63, w = tid >> 6;
  const int l15 = lane & 15, l4 = lane >> 4;
  const int wr = w >> 1, wc = w & 1;
  const int sl = (lin & 7) * (nwg >> 3) + (lin >> 3);   // nwg % 8 == 0
  const long bm = (long)(sl / nx) * 128, bn = (long)(sl % nx) * 128;
  f32x4 acc[4][4] = {};

  const int srow = tid >> 3;
  const int scs = (tid & 7) ^ (srow & 7);
  const int rsw = l15 & 7;

  for (int k0 = 0; k0 < K; k0 += 64) {
    __syncthreads();
    #pragma unroll
    for (int j = 0; j < 4; ++j) {
      const unsigned lb = __builtin_amdgcn_readfirstlane((j * 256 + w * 64) * 16);
      gload16(A + (bm + j * 32 + srow) * (long)lda + k0 + scs * 8, (char*)As + lb);
      gload16(BT + (bn + j * 32 + srow) * (long)ldb + k0 + scs * 8, (char*)Bs + lb);
    }
    __syncthreads();
    #pragma unroll
    for (int kk = 0; kk < 2; ++kk) {
      bf16x8 a[4], b[4];
      const int slot = (kk * 4 + l4) ^ rsw;
      #pragma unroll
      for (int mi = 0; mi < 4; ++mi)
        a[mi] = *(const bf16x8*)&As[(wr * 64 + mi * 16 + l15) * 64 + slot * 8];
      #pragma unroll
      for (int ni = 0; ni < 4; ++ni)
        b[ni] = *(const bf16x8*)&Bs[(wc * 64 + ni * 16 + l15) * 64 + slot * 8];
      #pragma unroll
      for (int mi = 0; mi < 4; ++mi)
        #pragma unroll
        for (int ni = 0; ni < 4; ++ni)
          acc[mi][ni] = MFMA16(a[mi], b[ni], acc[mi][ni]);
    }
  }
  #pragma unroll
  for (int mi = 0; mi < 4; ++mi)
    #pragma unroll
    for (int ni = 0; ni < 4; ++ni)
      #pragma unroll
      for (int r = 0; r < 4; ++r) {
        long row = bm + wr * 64 + mi * 16 + l4 * 4 + r;
        long col = bn + wc * 64 + ni * 16 + l15;
        float v = acc[mi][ni][r];
        if (F32OUT) {
          ((float*)Cv)[row * ldc + col] = v;
        } else if (C2 && col >= ncut) {
          C2[row * 640 + (col - ncut)] = __float2bfloat16(v);
        } else {
          ((bf16*)Cv)[row * (long)ldc + col] = __float2bfloat16(v);
        }
      }
}

template<bool F32OUT>
__global__ __launch_bounds__(256) void gemm_v4(
    const bf16* __restrict__ A, const bf16* __restrict__ BT, void* __restrict__ Cv,
    int N, int K, int lda, int ldb, int ldc, bf16* __restrict__ C2, int ncut)
{
  __shared__ __align__(16) short As[128 * 64];
  __shared__ __align__(16) short Bs[128 * 64];
  const int nx = gridDim.x, nwg = nx * gridDim.y;
  const int lin = blockIdx.y * nx + blockIdx.x;
  gemm_core<F32OUT>(As, Bs, A, BT, Cv, N, K, lda, ldb, ldc, C2, ncut, nx, nwg, lin);
}

// Merged gemm2 (q = ckq@WqbT, 768 blocks) + gemm4 (kv = kvns@WkvbT, 1024 blocks).
__global__ __launch_bounds__(256) void gemm_dual(
    const bf16* __restrict__ A0, const bf16* __restrict__ B0, bf16* __restrict__ C0,
    const bf16* __restrict__ A1, const bf16* __restrict__ B1, bf16* __restrict__ C1)
{
  __shared__ __align__(16) short As[128 * 64];
  __shared__ __align__(16) short Bs[128 * 64];
  const int bid = blockIdx.x;
  if (bid < 768)
    gemm_core<false>(As, Bs, A0, B0, C0, 3072, 1536, 1536, 1536, 3072, nullptr, 0,
                     24, 768, bid);
  else
    gemm_core<false>(As, Bs, A1, B1, C1, 4096, 512, 640, 512, 4096, nullptr, 0,
                     32, 1024, bid - 768);
}

// ---------------------------------------------------------------------------
// Merged RMSNorm: blocks 0..4095 -> ckq (C=1536, stride 1536);
//                 blocks 4096..8191 -> kvns (C=512, stride 640).
// ---------------------------------------------------------------------------
template<int C>
__device__ __forceinline__ void rms_core(bf16* __restrict__ xr,
                                         const bf16* __restrict__ w, float* red)
{
  constexpr int PER = C / 256;
  const int tid = threadIdx.x;
  float v[PER];
  float ss = 0.f;
  #pragma unroll
  for (int k = 0; k < PER; ++k) {
    float f = __bfloat162float(xr[tid + k * 256]);
    v[k] = f; ss += f * f;
  }
  #pragma unroll
  for (int off = 1; off < 64; off <<= 1) ss += __shfl_xor(ss, off);
  if ((tid & 63) == 0) red[tid >> 6] = ss;
  __syncthreads();
  float tot = red[0] + red[1] + red[2] + red[3];
  float scale = rsqrtf(tot / (float)C + 1e-6f);
  #pragma unroll
  for (int k = 0; k < PER; ++k)
    xr[tid + k * 256] =
        __float2bfloat16(v[k] * scale * __bfloat162float(w[tid + k * 256]));
}

__global__ __launch_bounds__(256) void rms_dual(bf16* __restrict__ ckq,
                                                const bf16* __restrict__ qw,
                                                bf16* __restrict__ kvns,
                                                const bf16* __restrict__ kvw)
{
  __shared__ float red[4];
  const int bid = blockIdx.x;
  if (bid < 4096) rms_core<1536>(ckq + (long)bid * 1536, qw, red);
  else            rms_core<512>(kvns + (long)(bid - 4096) * 640, kvw, red);
}

// ---------------------------------------------------------------------------
// Build Kf[bh][t][192], rows pre-swizzled: stored 16B-slot s = content s^(t&7).
// kvns row stride 640.
// ---------------------------------------------------------------------------
__global__ __launch_bounds__(256) void prep_kf(const bf16* __restrict__ kv,
                                               const bf16* __restrict__ kvns,
                                               bf16* __restrict__ Kf)
{
  __shared__ short pe[64];
  const int t = blockIdx.x, tid = threadIdx.x;
  if (tid < 32) {
    int i = tid;
    float p = (float)(t & 2047);
    float freq = powf(10000.0f, -(float)i / 32.0f);
    float sn, cs;
    sincosf(p * freq, &sn, &cs);
    float y1 = __bfloat162float(kvns[(long)t * 640 + 512 + 2 * i]);
    float y2 = __bfloat162float(kvns[(long)t * 640 + 512 + 2 * i + 1]);
    pe[2 * i]     = f2bs(y1 * cs - y2 * sn);
    pe[2 * i + 1] = f2bs(y2 * cs + y1 * sn);
  }
  __syncthreads();
  const int b = t >> 11, ts = t & 2047;
  const int swz = t & 7;
  #pragma unroll
  for (int uu = 0; uu < 2; ++uu) {
    int u = uu * 256 + tid;
    if (u >= 384) break;
    int h = u / 24, s = u % 24;
    int cs = s ^ swz;
    uint4 val;
    if (cs < 16) val = *(const uint4*)(kv + (long)t * 4096 + h * 256 + cs * 8);
    else         val = *(const uint4*)&pe[(cs - 16) * 8];
    *(uint4*)(Kf + ((long)(b * 16 + h) * 2048 + ts) * 192 + s * 8) = val;
  }
}

// ---------------------------------------------------------------------------
// Build Vt[bh][d][2048] = V^T, 64-key blocks pre-swizzled by (d&7).
// ---------------------------------------------------------------------------
__global__ __launch_bounds__(256) void prep_vt(const bf16* __restrict__ kv,
                                               bf16* __restrict__ Vt)
{
  __shared__ __align__(16) short Ts[64][136];
  const int kb = blockIdx.x, bh = blockIdx.y, b = bh >> 4, h = bh & 15;
  const int k0 = kb * 64, tid = threadIdx.x;
  #pragma unroll
  for (int j = 0; j < 4; ++j) {
    int u = j * 256 + tid;
    int kr = u >> 4, seg = u & 15;
    *(uint4*)&Ts[kr][seg * 8] = *(const uint4*)(kv +
        (long)(b * 2048 + k0 + kr) * 4096 + h * 256 + 128 + seg * 8);
  }
  __syncthreads();
  #pragma unroll
  for (int j = 0; j < 4; ++j) {
    int u = j * 256 + tid;
    int d = u >> 3, s = u & 7;
    int cs = s ^ (d & 7);
    union { uint4 v; short sh[8]; } o;
    #pragma unroll
    for (int jj = 0; jj < 8; ++jj) o.sh[jj] = Ts[cs * 8 + jj][d];
    *(uint4*)(Vt + ((long)bh * 128 + d) * 2048 + k0 + s * 8) = o.v;
  }
}

// ---------------------------------------------------------------------------
// attn_v6: swapped-QK softmax + pairing + fused Q-RoPE. exp2 domain with
// max-before-scale (fma fold) and defer-max threshold 12 (log2 units ~ 8.3 nats).
// ---------------------------------------------------------------------------
__global__ __launch_bounds__(256) void attn_v6(const bf16* __restrict__ q,
                                               const bf16* __restrict__ Kf,
                                               const bf16* __restrict__ Vt,
                                               bf16* __restrict__ attn)
{
  __shared__ __align__(16) short Ks[64 * 192];
  __shared__ __align__(16) short Vs[128 * 64];
  __shared__ __align__(16) short Ps[4][16 * 64];
  const float SC2 = 0.10411442245076847f;  // 192^-0.5 * log2(e)
  const int tid = threadIdx.x, lane = tid & 63, w = tid >> 6;
  const int l15 = lane & 15, l4 = lane >> 4;
  const int lin = blockIdx.x;
  const int x = lin & 7, j = lin >> 3;
  const int bh = x * 4 + (j >> 4), p = j & 15;
  const int b = bh >> 4, h = bh & 15;
  const unsigned lbase = __builtin_amdgcn_readfirstlane(w * 64 * 16);

  #pragma unroll
  for (int half = 0; half < 2; ++half) {
    const int qt = half ? (31 - p) : p;
    const long qrow0 = (long)b * 2048 + qt * 64;
    const int rowt = qt * 64 + w * 16 + l15;

    bf16x8 qf[6];
    {
      const short* qrow = (const short*)q + (qrow0 + w * 16 + l15) * 3072 + h * 192;
      #pragma unroll
      for (int kc = 0; kc < 6; ++kc)
        qf[kc] = *(const bf16x8*)(qrow + kc * 32 + l4 * 8);
    }
    {  // fused GPT-J RoPE on pe fragments (cols 128..191 = kc 4,5)
      float pos = (float)rowt;
      #pragma unroll
      for (int kc = 4; kc < 6; ++kc)
        #pragma unroll
        for (int pr = 0; pr < 4; ++pr) {
          int i = (kc - 4) * 16 + l4 * 4 + pr;
          float freq = __expf((float)i * -0.28782313662425572f);  // 10000^(-i/32)
          float sn, cs;
          sincosf(pos * freq, &sn, &cs);
          float x1 = bs2f(qf[kc][2 * pr]), x2 = bs2f(qf[kc][2 * pr + 1]);
          qf[kc][2 * pr]     = f2bs(x1 * cs - x2 * sn);
          qf[kc][2 * pr + 1] = f2bs(x2 * cs + x1 * sn);
        }
    }
    f32x4 o[8] = {};
    float mreg = -1e30f, ls = 0.f;
    const int nch = qt + 1;

    {  // prologue: stage K chunk 0
      const char* ksrc = (const char*)(Kf + (long)bh * 2048 * 192);
      #pragma unroll
      for (int jj = 0; jj < 6; ++jj)
        gload16(ksrc + (jj * 256 + tid) * 16, (char*)Ks + jj * 4096 + lbase);
    }
    __syncthreads();

    for (int c = 0; c < nch; ++c) {
      const int k0 = c * 64;
      {  // issue V(c) — drains at mid-barrier, hidden under QK+softmax
        #pragma unroll
        for (int jj = 0; jj < 4; ++jj) {
          int seg = jj * 256 + tid;
          const bf16* vsrc = Vt + ((long)bh * 128 + (seg >> 3)) * 2048 + k0 + (seg & 7) * 8;
          gload16(vsrc, (char*)Vs + jj * 4096 + lbase);
        }
      }
      __builtin_amdgcn_s_setprio(1);
      f32x4 s[4] = {};
      #pragma unroll
      for (int kc = 0; kc < 6; ++kc)
        #pragma unroll
        for (int kg = 0; kg < 4; ++kg) {
          int row = kg * 16 + l15;
          int slot = (kc * 4 + l4) ^ (l15 & 7);
          bf16x8 kb = *(const bf16x8*)&Ks[row * 192 + slot * 8];
          s[kg] = MFMA16(kb, qf[kc], s[kg]);   // SWAPPED: D[key][qrow]
        }
      __builtin_amdgcn_s_setprio(0);

      const bool diag = (c == qt);
      float pk[16];
      #pragma unroll
      for (int kg = 0; kg < 4; ++kg)
        #pragma unroll
        for (int r = 0; r < 4; ++r) {
          float v = s[kg][r];
          if (diag && (k0 + kg * 16 + l4 * 4 + r > rowt)) v = -1e30f;
          pk[kg * 4 + r] = v;
        }
      float cm = pk[0];
      #pragma unroll
      for (int i = 1; i < 16; ++i) cm = fmaxf(cm, pk[i]);
      cm = fmaxf(cm, __shfl_xor(cm, 16));
      cm = fmaxf(cm, __shfl_xor(cm, 32));
      cm *= SC2;  // scale once (monotone)
      if (__ballot(cm > mreg + 12.0f)) {  // defer-max rescale (wave-uniform)
        float mn = fmaxf(mreg, cm);
        float al = exp2f(mreg - mn);
        ls *= al;
        float af[4];
        #pragma unroll
        for (int r = 0; r < 4; ++r) af[r] = __shfl(al, l4 * 4 + r);
        #pragma unroll
        for (int f = 0; f < 8; ++f)
          #pragma unroll
          for (int r = 0; r < 4; ++r) o[f][r] *= af[r];
        mreg = mn;
      }
      float ps = 0.f;
      #pragma unroll
      for (int i = 0; i < 16; ++i) {
        pk[i] = exp2f(fmaf(pk[i], SC2, -mreg));
        ps += pk[i];
      }
      ps += __shfl_xor(ps, 16);
      ps += __shfl_xor(ps, 32);
      ls += ps;
      #pragma unroll
      for (int kg = 0; kg < 4; ++kg)
        #pragma unroll
        for (int pr = 0; pr < 2; ++pr) {
          int key2 = kg * 16 + l4 * 4 + pr * 2;
          int sl = (key2 >> 3) ^ (l15 & 7);
          unsigned lo = (unsigned short)f2bs(pk[kg * 4 + pr * 2]);
          unsigned hi = (unsigned short)f2bs(pk[kg * 4 + pr * 2 + 1]);
          *(unsigned*)&Ps[w][l15 * 64 + sl * 8 + (key2 & 7)] = lo | (hi << 16);
        }
      __syncthreads();  // mid-barrier: V(c) landed; Ks reads + Ps writes done

      if (c + 1 < nch) {  // issue K(c+1) — drains at end-barrier, under PV
        const char* ksrc = (const char*)(Kf + ((long)bh * 2048 + k0 + 64) * 192);
        #pragma unroll
        for (int jj = 0; jj < 6; ++jj)
          gload16(ksrc + (jj * 256 + tid) * 16, (char*)Ks + jj * 4096 + lbase);
      }

      __builtin_amdgcn_s_setprio(1);
      #pragma unroll
      for (int ks = 0; ks < 2; ++ks) {
        int psl = (ks * 4 + l4) ^ (l15 & 7);
        bf16x8 pa = *(const bf16x8*)&Ps[w][l15 * 64 + psl * 8];
        #pragma unroll
        for (int f = 0; f < 8; ++f) {
          int vrow = f * 16 + l15;
          int vsl = (ks * 4 + l4) ^ (l15 & 7);
          bf16x8 bv = *(const bf16x8*)&Vs[vrow * 64 + vsl * 8];
          o[f] = MFMA16(pa, bv, o[f]);
        }
      }
      __builtin_amdgcn_s_setprio(0);
      __syncthreads();  // end-barrier: K(c+1) landed; Vs reads done
    }

    #pragma unroll
    for (int r = 0; r < 4; ++r) {
      float lsr = __shfl(ls, l4 * 4 + r);
      float inv = 1.0f / lsr;
      long t = qrow0 + w * 16 + l4 * 4 + r;
      bf16* dst = attn + t * 2048 + h * 128;
      #pragma unroll
      for (int f = 0; f < 8; ++f)
        dst[f * 16 + l15] = __float2bfloat16(o[f][r] * inv);
    }
  }
}

// ---------------------------------------------------------------------------
extern "C" void kernel_launch(void* const* d_in, const int* in_sizes, int n_in,
                              void* d_out, int out_size, void* d_ws, size_t ws_size,
                              hipStream_t stream) {
  const int T = 4096;
  const float* hs_f   = (const float*)d_in[1];
  const float* Wqa_f  = (const float*)d_in[2];
  const float* qln_f  = (const float*)d_in[3];
  const float* Wqb_f  = (const float*)d_in[4];
  const float* Wkva_f = (const float*)d_in[5];
  const float* kvln_f = (const float*)d_in[6];
  const float* Wkvb_f = (const float*)d_in[7];
  const float* Wo_f   = (const float*)d_in[8];

  bf16* base = (bf16*)d_ws;
  bf16* hs_c  = base;                       // 8,388,608  (dead after gemmA) | Kf overlay
  bf16* ckq   = base + 8388608;             // 6,291,456  (dead after gemm_dual)
  bf16* qln_c = base + 14680064;            // 1536
  bf16* kvln_c= base + 14681600;            // 512
  bf16* arena = base + 14682112;            // 6,815,744 (BT staging, serially reused)
  bf16* q     = base + 21497856;            // 12,582,912
  bf16* kvns  = base + 34080768;            // 2,621,440 (T x 640)
  bf16* kv    = base + 36702208;            // 16,777,216 | attn out overlay
  bf16* Vt    = base + 53479424;            // 8,388,608  (ends 61,868,032 ≈ 123.7 MB)
  bf16* Kf    = base;                       // 12,582,912, overlays hs_c+ckq head
  bf16* attnb = kv;

  // 1) batched conversions (hs, q_ln, kv_ln)
  cvt3<<<4097, 256, 0, stream>>>(hs_f, hs_c, 1048576, qln_f, qln_c, 192, kvln_f, kvln_c);

  // 2) BT for fused QKV-A GEMM: rows 0..1535 = Wqa^T, rows 1536..2111 = Wkva^T
  t_cvt<<<dim3(24, 32), 256, 0, stream>>>(Wqa_f, arena, 2048, 1536);
  t_cvt<<<dim3(9, 32), 256, 0, stream>>>(Wkva_f, arena + (size_t)1536 * 2048, 2048, 576);
  // 3) fused: [ckq | kvns] = hs @ [Wqa | Wkva]  (N=2176, split epilogue at 1536)
  gemm_v4<false><<<dim3(17, 32), 256, 0, stream>>>(hs_c, arena, ckq, 2176, 2048,
                                                   2048, 2048, 1536, kvns, 1536);
  // 4) both rmsnorms in one dispatch
  rms_dual<<<8192, 256, 0, stream>>>(ckq, qln_c, kvns, kvln_c);
  // 5) BT for both second-stage GEMMs
  t_cvt<<<dim3(48, 24), 256, 0, stream>>>(Wqb_f, arena, 1536, 3072);
  t_cvt<<<dim3(64, 8), 256, 0, stream>>>(Wkvb_f, arena + 4718592, 512, 4096);
  // 6) merged: q = ckq@WqbT  |  kv = kvns@WkvbT
  gemm_dual<<<1792, 256, 0, stream>>>(ckq, arena, q, kvns, arena + 4718592, kv);
  // 7) K/V assembly (K rope fused in prep_kf)
  prep_kf<<<T, 256, 0, stream>>>(kv, kvns, Kf);
  prep_vt<<<dim3(32, 32), 256, 0, stream>>>(kv, Vt);
  // 8) attention
  attn_v6<<<512, 256, 0, stream>>>(q, Kf, Vt, attnb);
  // 9) out = attn @ Wo (f32 output)
  t_cvt<<<dim3(32, 32), 256, 0, stream>>>(Wo_f, arena, 2048, 2048);
  gemm_v4<true><<<dim3(16, 32), 256, 0, stream>>>(attnb, arena, d_out, 2048, 2048,
                                                  2048, 2048, 2048, nullptr, 0);
}

// Round 17
// 293.609 us; speedup vs baseline: 2.5827x; 1.0294x over previous
//
#include <hip/hip_runtime.h>
#include <hip/hip_bf16.h>

typedef __hip_bfloat16 bf16;
typedef short bf16x8 __attribute__((ext_vector_type(8)));
typedef float f32x4 __attribute__((ext_vector_type(4)));

#define MFMA16(a, b, c) __builtin_amdgcn_mfma_f32_16x16x32_bf16((a), (b), (c), 0, 0, 0)

__device__ __forceinline__ short f2bs(float f) {
  bf16 h = __float2bfloat16(f);
  return __builtin_bit_cast(short, h);
}
__device__ __forceinline__ float bs2f(short s) {
  return __bfloat162float(__builtin_bit_cast(bf16, s));
}

// async global->LDS, 16B per lane; LDS dest = wave-uniform base + lane*16
__device__ __forceinline__ void gload16(const void* g, const void* l) {
  __builtin_amdgcn_global_load_lds(
      (const __attribute__((address_space(1))) unsigned int*)g,
      (__attribute__((address_space(3))) unsigned int*)l, 16, 0, 0);
}

// ---------------------------------------------------------------------------
// f32->bf16 transpose core: dst[N][K](bf16) = src[K][N](f32)^T, 64x64 tile.
// ---------------------------------------------------------------------------
__device__ __forceinline__ void t_cvt_core(const float* __restrict__ src,
                                           bf16* __restrict__ dst, int K, int N,
                                           int bx, int by, short Ts[64][72]) {
  const long n0 = (long)bx * 64, k0 = (long)by * 64;
  const int r = threadIdx.x >> 2, c4 = threadIdx.x & 3;
  const float* s = src + (k0 + r) * (long)N + n0 + c4 * 16;
  #pragma unroll
  for (int j = 0; j < 4; ++j) {
    float4 v = *(const float4*)(s + j * 4);
    Ts[r][c4 * 16 + j * 4 + 0] = f2bs(v.x);
    Ts[r][c4 * 16 + j * 4 + 1] = f2bs(v.y);
    Ts[r][c4 * 16 + j * 4 + 2] = f2bs(v.z);
    Ts[r][c4 * 16 + j * 4 + 3] = f2bs(v.w);
  }
  __syncthreads();
  union { uint4 v; short sh[8]; } o0, o1;
  #pragma unroll
  for (int j = 0; j < 8; ++j) o0.sh[j] = Ts[c4 * 16 + j][r];
  #pragma unroll
  for (int j = 0; j < 8; ++j) o1.sh[j] = Ts[c4 * 16 + 8 + j][r];
  *(uint4*)(dst + (n0 + r) * (long)K + k0 + c4 * 16)     = o0.v;
  *(uint4*)(dst + (n0 + r) * (long)K + k0 + c4 * 16 + 8) = o1.v;
}

// ---------------------------------------------------------------------------
// prep1: flat cvt (hs, q_ln, kv_ln) + WqaT + WkvaT. 5153 blocks.
// ---------------------------------------------------------------------------
__global__ __launch_bounds__(256) void prep1(
    const float* __restrict__ hs_f, bf16* __restrict__ hs_c,
    const float* __restrict__ qln_f, bf16* __restrict__ qln_c,
    const float* __restrict__ kvln_f, bf16* __restrict__ kvln_c,
    const float* __restrict__ Wqa_f, const float* __restrict__ Wkva_f,
    bf16* __restrict__ arena)
{
  __shared__ __align__(16) short Ts[64][72];
  const int bid = blockIdx.x;
  if (bid < 4097) {
    int i = bid * 256 + threadIdx.x;
    const float* s; bf16* d; int idx;
    if (i < 1048576)            { s = hs_f;   d = hs_c;   idx = i; }
    else if (i < 1048576 + 192) { s = qln_f;  d = qln_c;  idx = i - 1048576; }
    else                        { s = kvln_f; d = kvln_c; idx = i - 1048768; }
    const float4* sp = (const float4*)s;
    float4 a = sp[2 * idx], b = sp[2 * idx + 1];
    union { uint4 v; short sh[8]; } o;
    o.sh[0] = f2bs(a.x); o.sh[1] = f2bs(a.y); o.sh[2] = f2bs(a.z); o.sh[3] = f2bs(a.w);
    o.sh[4] = f2bs(b.x); o.sh[5] = f2bs(b.y); o.sh[6] = f2bs(b.z); o.sh[7] = f2bs(b.w);
    ((uint4*)d)[idx] = o.v;
  } else if (bid < 4097 + 768) {
    int l = bid - 4097;
    t_cvt_core(Wqa_f, arena, 2048, 1536, l % 24, l / 24, Ts);
  } else {
    int l = bid - 4865;
    t_cvt_core(Wkva_f, arena + (size_t)1536 * 2048, 2048, 576, l % 9, l / 9, Ts);
  }
}

// ---------------------------------------------------------------------------
// prep2: WqbT + WkvbT + WoT. 2688 blocks.
// ---------------------------------------------------------------------------
__global__ __launch_bounds__(256) void prep2(
    const float* __restrict__ Wqb_f, bf16* __restrict__ wqbT,
    const float* __restrict__ Wkvb_f, bf16* __restrict__ wkvbT,
    const float* __restrict__ Wo_f, bf16* __restrict__ woT)
{
  __shared__ __align__(16) short Ts[64][72];
  const int bid = blockIdx.x;
  if (bid < 1152)      t_cvt_core(Wqb_f, wqbT, 1536, 3072, bid % 48, bid / 48, Ts);
  else if (bid < 1664) { int l = bid - 1152; t_cvt_core(Wkvb_f, wkvbT, 512, 4096, l % 64, l / 64, Ts); }
  else                 { int l = bid - 1664; t_cvt_core(Wo_f, woT, 2048, 2048, l % 32, l / 32, Ts); }
}

// ---------------------------------------------------------------------------
// gemm core: C = A[M,K] @ BT[N,K]^T. BM=BN=128, BK=64, 4 waves, quadrants.
// XOR(row&7)-swizzled LDS (throughput-optimal reads), T1 XCD swizzle.
// Split epilogue: cols >= ncut -> C2[row*640 + col-ncut].
// ---------------------------------------------------------------------------
template<bool F32OUT>
__device__ __forceinline__ void gemm_core(
    short* As, short* Bs,
    const bf16* __restrict__ A, const bf16* __restrict__ BT, void* __restrict__ Cv,
    int N, int K, int lda, int ldb, int ldc, bf16* __restrict__ C2, int ncut,
    int nx, int nwg, int lin)
{
  const int tid = threadIdx.x, lane = tid & 63, w = tid >> 6;
  const int l15 = lane & 15, l4 = lane >> 4;
  const int wr = w >> 1, wc = w & 1;
  const int sl = (lin & 7) * (nwg >> 3) + (lin >> 3);   // nwg % 8 == 0
  const long bm = (long)(sl / nx) * 128, bn = (long)(sl % nx) * 128;
  f32x4 acc[4][4] = {};

  const int srow = tid >> 3;
  const int scs = (tid & 7) ^ (srow & 7);
  const int rsw = l15 & 7;

  for (int k0 = 0; k0 < K; k0 += 64) {
    __syncthreads();
    #pragma unroll
    for (int j = 0; j < 4; ++j) {
      const unsigned lb = __builtin_amdgcn_readfirstlane((j * 256 + w * 64) * 16);
      gload16(A + (bm + j * 32 + srow) * (long)lda + k0 + scs * 8, (char*)As + lb);
      gload16(BT + (bn + j * 32 + srow) * (long)ldb + k0 + scs * 8, (char*)Bs + lb);
    }
    __syncthreads();
    #pragma unroll
    for (int kk = 0; kk < 2; ++kk) {
      bf16x8 a[4], b[4];
      const int slot = (kk * 4 + l4) ^ rsw;
      #pragma unroll
      for (int mi = 0; mi < 4; ++mi)
        a[mi] = *(const bf16x8*)&As[(wr * 64 + mi * 16 + l15) * 64 + slot * 8];
      #pragma unroll
      for (int ni = 0; ni < 4; ++ni)
        b[ni] = *(const bf16x8*)&Bs[(wc * 64 + ni * 16 + l15) * 64 + slot * 8];
      #pragma unroll
      for (int mi = 0; mi < 4; ++mi)
        #pragma unroll
        for (int ni = 0; ni < 4; ++ni)
          acc[mi][ni] = MFMA16(a[mi], b[ni], acc[mi][ni]);
    }
  }
  #pragma unroll
  for (int mi = 0; mi < 4; ++mi)
    #pragma unroll
    for (int ni = 0; ni < 4; ++ni)
      #pragma unroll
      for (int r = 0; r < 4; ++r) {
        long row = bm + wr * 64 + mi * 16 + l4 * 4 + r;
        long col = bn + wc * 64 + ni * 16 + l15;
        float v = acc[mi][ni][r];
        if (F32OUT) {
          ((float*)Cv)[row * ldc + col] = v;
        } else if (C2 && col >= ncut) {
          C2[row * 640 + (col - ncut)] = __float2bfloat16(v);
        } else {
          ((bf16*)Cv)[row * (long)ldc + col] = __float2bfloat16(v);
        }
      }
}

template<bool F32OUT>
__global__ __launch_bounds__(256) void gemm_v4(
    const bf16* __restrict__ A, const bf16* __restrict__ BT, void* __restrict__ Cv,
    int N, int K, int lda, int ldb, int ldc, bf16* __restrict__ C2, int ncut)
{
  __shared__ __align__(16) short As[128 * 64];
  __shared__ __align__(16) short Bs[128 * 64];
  const int nx = gridDim.x, nwg = nx * gridDim.y;
  const int lin = blockIdx.y * nx + blockIdx.x;
  gemm_core<F32OUT>(As, Bs, A, BT, Cv, N, K, lda, ldb, ldc, C2, ncut, nx, nwg, lin);
}

// ---------------------------------------------------------------------------
// gemm_dual: blocks 0..767 -> q = ckq@WqbT (plain epilogue);
// blocks 768..1791 -> kv GEMM with FUSED K/V assembly epilogue:
//   k_nope tiles (bn%256==0)  -> Kf[bh][t][slot (cs^(t&7))] scatter
//   v tiles     (bn%256==128) -> LDS transpose -> Vt[bh][d][...] (d&7 swizzle)
// ---------------------------------------------------------------------------
__global__ __launch_bounds__(256) void gemm_dual(
    const bf16* __restrict__ ckq, const bf16* __restrict__ wqbT, bf16* __restrict__ q,
    const bf16* __restrict__ kvns, const bf16* __restrict__ wkvbT,
    bf16* __restrict__ Kf, bf16* __restrict__ Vt)
{
  __shared__ __align__(16) short LDSU[17408];   // 34.8 KB (128x136 transpose max)
  short* As = LDSU;
  short* Bs = LDSU + 8192;
  const int bid = blockIdx.x;
  if (bid < 768) {
    gemm_core<false>(As, Bs, ckq, wqbT, q, 3072, 1536, 1536, 1536, 3072, nullptr, 0,
                     24, 768, bid);
    return;
  }
  // ---- kv segment ----
  const int lin = bid - 768;
  const int tid = threadIdx.x, lane = tid & 63, w = tid >> 6;
  const int l15 = lane & 15, l4 = lane >> 4;
  const int wr = w >> 1, wc = w & 1;
  const int sl = (lin & 7) * 128 + (lin >> 3);   // nwg=1024
  const long bm = (long)(sl / 32) * 128, bn = (long)(sl % 32) * 128;
  f32x4 acc[4][4] = {};
  const int srow = tid >> 3;
  const int scs = (tid & 7) ^ (srow & 7);
  const int rsw = l15 & 7;

  for (int k0 = 0; k0 < 512; k0 += 64) {
    __syncthreads();
    #pragma unroll
    for (int j = 0; j < 4; ++j) {
      const unsigned lb = __builtin_amdgcn_readfirstlane((j * 256 + w * 64) * 16);
      gload16(kvns + (bm + j * 32 + srow) * 640L + k0 + scs * 8, (char*)As + lb);
      gload16(wkvbT + (bn + j * 32 + srow) * 512L + k0 + scs * 8, (char*)Bs + lb);
    }
    __syncthreads();
    #pragma unroll
    for (int kk = 0; kk < 2; ++kk) {
      bf16x8 a[4], b[4];
      const int slot = (kk * 4 + l4) ^ rsw;
      #pragma unroll
      for (int mi = 0; mi < 4; ++mi)
        a[mi] = *(const bf16x8*)&As[(wr * 64 + mi * 16 + l15) * 64 + slot * 8];
      #pragma unroll
      for (int ni = 0; ni < 4; ++ni)
        b[ni] = *(const bf16x8*)&Bs[(wc * 64 + ni * 16 + l15) * 64 + slot * 8];
      #pragma unroll
      for (int mi = 0; mi < 4; ++mi)
        #pragma unroll
        for (int ni = 0; ni < 4; ++ni)
          acc[mi][ni] = MFMA16(a[mi], b[ni], acc[mi][ni]);
    }
  }

  const int h = (int)(bn >> 8);
  const int lc = (int)(bn & 255);                // 0 = k_nope, 128 = v
  const int bh = (int)(bm >> 11) * 16 + h;

  if (lc == 0) {
    // k_nope -> Kf scatter (stored slot = cs ^ (t&7); pe slots 16..23 untouched)
    #pragma unroll
    for (int mi = 0; mi < 4; ++mi)
      #pragma unroll
      for (int ni = 0; ni < 4; ++ni) {
        const int col = wc * 64 + ni * 16 + l15;
        const int cs = col >> 3, e = col & 7;
        #pragma unroll
        for (int r = 0; r < 4; ++r) {
          int t = (int)bm + wr * 64 + mi * 16 + l4 * 4 + r;
          Kf[((size_t)bh * 2048 + (t & 2047)) * 192 + ((cs ^ (t & 7)) << 3) + e] =
              __float2bfloat16(acc[mi][ni][r]);
        }
      }
  } else {
    // v -> LDS transpose -> Vt coalesced (64-key blocks, (d&7) slot swizzle)
    __syncthreads();
    #pragma unroll
    for (int mi = 0; mi < 4; ++mi)
      #pragma unroll
      for (int ni = 0; ni < 4; ++ni)
        #pragma unroll
        for (int r = 0; r < 4; ++r)
          LDSU[(wr * 64 + mi * 16 + l4 * 4 + r) * 136 + wc * 64 + ni * 16 + l15] =
              f2bs(acc[mi][ni][r]);
    __syncthreads();
    #pragma unroll
    for (int j = 0; j < 8; ++j) {
      int u = j * 256 + tid;
      int d = u >> 4, slo = u & 15;
      int k0l = (slo >> 3) << 6;     // 0 or 64
      int cs = slo & 7;
      int tb = k0l + cs * 8;
      union { uint4 v; short sh[8]; } o;
      #pragma unroll
      for (int i = 0; i < 8; ++i) o.sh[i] = LDSU[(tb + i) * 136 + d];
      *(uint4*)(Vt + ((size_t)(bh * 128 + d)) * 2048 + (int)(bm & 2047) + k0l +
                ((cs ^ (d & 7)) << 3)) = o.v;
    }
  }
}

// ---------------------------------------------------------------------------
// Merged RMSNorm: blocks 0..4095 -> ckq (C=1536); 4096..8191 -> kvns (C=512).
// ---------------------------------------------------------------------------
template<int C>
__device__ __forceinline__ void rms_core(bf16* __restrict__ xr,
                                         const bf16* __restrict__ w, float* red)
{
  constexpr int PER = C / 256;
  const int tid = threadIdx.x;
  float v[PER];
  float ss = 0.f;
  #pragma unroll
  for (int k = 0; k < PER; ++k) {
    float f = __bfloat162float(xr[tid + k * 256]);
    v[k] = f; ss += f * f;
  }
  #pragma unroll
  for (int off = 1; off < 64; off <<= 1) ss += __shfl_xor(ss, off);
  if ((tid & 63) == 0) red[tid >> 6] = ss;
  __syncthreads();
  float tot = red[0] + red[1] + red[2] + red[3];
  float scale = rsqrtf(tot / (float)C + 1e-6f);
  #pragma unroll
  for (int k = 0; k < PER; ++k)
    xr[tid + k * 256] =
        __float2bfloat16(v[k] * scale * __bfloat162float(w[tid + k * 256]));
}

__global__ __launch_bounds__(256) void rms_dual(bf16* __restrict__ ckq,
                                                const bf16* __restrict__ qw,
                                                bf16* __restrict__ kvns,
                                                const bf16* __restrict__ kvw)
{
  __shared__ float red[4];
  const int bid = blockIdx.x;
  if (bid < 4096) rms_core<1536>(ckq + (long)bid * 1536, qw, red);
  else            rms_core<512>(kvns + (long)(bid - 4096) * 640, kvw, red);
}

// ---------------------------------------------------------------------------
// prep_pe: rope k_pe from kvns[t][512..575] -> Kf pe slots (stored 16..23).
// ---------------------------------------------------------------------------
__global__ __launch_bounds__(256) void prep_pe(const bf16* __restrict__ kvns,
                                               bf16* __restrict__ Kf)
{
  __shared__ short pe[64];
  const int t = blockIdx.x, tid = threadIdx.x;
  if (tid < 32) {
    int i = tid;
    float p = (float)(t & 2047);
    float freq = powf(10000.0f, -(float)i / 32.0f);
    float sn, cs;
    sincosf(p * freq, &sn, &cs);
    float y1 = __bfloat162float(kvns[(long)t * 640 + 512 + 2 * i]);
    float y2 = __bfloat162float(kvns[(long)t * 640 + 512 + 2 * i + 1]);
    pe[2 * i]     = f2bs(y1 * cs - y2 * sn);
    pe[2 * i + 1] = f2bs(y2 * cs + y1 * sn);
  }
  __syncthreads();
  if (tid < 128) {
    const int hh = tid >> 3, j = tid & 7;
    const int swz = t & 7;
    const int b = t >> 11, ts = t & 2047;
    uint4 val = *(const uint4*)&pe[(j ^ swz) * 8];
    *(uint4*)(Kf + ((size_t)(b * 16 + hh) * 2048 + ts) * 192 + (16 + j) * 8) = val;
  }
}

// ---------------------------------------------------------------------------
// attn_v6 (r16-proven): swapped-QK softmax + pairing + fused Q-RoPE, exp2.
// ---------------------------------------------------------------------------
__global__ __launch_bounds__(256) void attn_v6(const bf16* __restrict__ q,
                                               const bf16* __restrict__ Kf,
                                               const bf16* __restrict__ Vt,
                                               bf16* __restrict__ attn)
{
  __shared__ __align__(16) short Ks[64 * 192];
  __shared__ __align__(16) short Vs[128 * 64];
  __shared__ __align__(16) short Ps[4][16 * 64];
  const float SC2 = 0.10411442245076847f;  // 192^-0.5 * log2(e)
  const int tid = threadIdx.x, lane = tid & 63, w = tid >> 6;
  const int l15 = lane & 15, l4 = lane >> 4;
  const int lin = blockIdx.x;
  const int x = lin & 7, j = lin >> 3;
  const int bh = x * 4 + (j >> 4), p = j & 15;
  const int b = bh >> 4, h = bh & 15;
  const unsigned lbase = __builtin_amdgcn_readfirstlane(w * 64 * 16);

  #pragma unroll
  for (int half = 0; half < 2; ++half) {
    const int qt = half ? (31 - p) : p;
    const long qrow0 = (long)b * 2048 + qt * 64;
    const int rowt = qt * 64 + w * 16 + l15;

    bf16x8 qf[6];
    {
      const short* qrow = (const short*)q + (qrow0 + w * 16 + l15) * 3072 + h * 192;
      #pragma unroll
      for (int kc = 0; kc < 6; ++kc)
        qf[kc] = *(const bf16x8*)(qrow + kc * 32 + l4 * 8);
    }
    {  // fused GPT-J RoPE on pe fragments (cols 128..191 = kc 4,5)
      float pos = (float)rowt;
      #pragma unroll
      for (int kc = 4; kc < 6; ++kc)
        #pragma unroll
        for (int pr = 0; pr < 4; ++pr) {
          int i = (kc - 4) * 16 + l4 * 4 + pr;
          float freq = __expf((float)i * -0.28782313662425572f);  // 10000^(-i/32)
          float sn, cs;
          sincosf(pos * freq, &sn, &cs);
          float x1 = bs2f(qf[kc][2 * pr]), x2 = bs2f(qf[kc][2 * pr + 1]);
          qf[kc][2 * pr]     = f2bs(x1 * cs - x2 * sn);
          qf[kc][2 * pr + 1] = f2bs(x2 * cs + x1 * sn);
        }
    }
    f32x4 o[8] = {};
    float mreg = -1e30f, ls = 0.f;
    const int nch = qt + 1;

    {  // prologue: stage K chunk 0
      const char* ksrc = (const char*)(Kf + (long)bh * 2048 * 192);
      #pragma unroll
      for (int jj = 0; jj < 6; ++jj)
        gload16(ksrc + (jj * 256 + tid) * 16, (char*)Ks + jj * 4096 + lbase);
    }
    __syncthreads();

    for (int c = 0; c < nch; ++c) {
      const int k0 = c * 64;
      {  // issue V(c) — drains at mid-barrier, hidden under QK+softmax
        #pragma unroll
        for (int jj = 0; jj < 4; ++jj) {
          int seg = jj * 256 + tid;
          const bf16* vsrc = Vt + ((long)bh * 128 + (seg >> 3)) * 2048 + k0 + (seg & 7) * 8;
          gload16(vsrc, (char*)Vs + jj * 4096 + lbase);
        }
      }
      __builtin_amdgcn_s_setprio(1);
      f32x4 s[4] = {};
      #pragma unroll
      for (int kc = 0; kc < 6; ++kc)
        #pragma unroll
        for (int kg = 0; kg < 4; ++kg) {
          int row = kg * 16 + l15;
          int slot = (kc * 4 + l4) ^ (l15 & 7);
          bf16x8 kb = *(const bf16x8*)&Ks[row * 192 + slot * 8];
          s[kg] = MFMA16(kb, qf[kc], s[kg]);   // SWAPPED: D[key][qrow]
        }
      __builtin_amdgcn_s_setprio(0);

      const bool diag = (c == qt);
      float pk[16];
      #pragma unroll
      for (int kg = 0; kg < 4; ++kg)
        #pragma unroll
        for (int r = 0; r < 4; ++r) {
          float v = s[kg][r];
          if (diag && (k0 + kg * 16 + l4 * 4 + r > rowt)) v = -1e30f;
          pk[kg * 4 + r] = v;
        }
      float cm = pk[0];
      #pragma unroll
      for (int i = 1; i < 16; ++i) cm = fmaxf(cm, pk[i]);
      cm = fmaxf(cm, __shfl_xor(cm, 16));
      cm = fmaxf(cm, __shfl_xor(cm, 32));
      cm *= SC2;  // scale once (monotone)
      if (__ballot(cm > mreg + 12.0f)) {  // defer-max rescale (wave-uniform)
        float mn = fmaxf(mreg, cm);
        float al = exp2f(mreg - mn);
        ls *= al;
        float af[4];
        #pragma unroll
        for (int r = 0; r < 4; ++r) af[r] = __shfl(al, l4 * 4 + r);
        #pragma unroll
        for (int f = 0; f < 8; ++f)
          #pragma unroll
          for (int r = 0; r < 4; ++r) o[f][r] *= af[r];
        mreg = mn;
      }
      float ps = 0.f;
      #pragma unroll
      for (int i = 0; i < 16; ++i) {
        pk[i] = exp2f(fmaf(pk[i], SC2, -mreg));
        ps += pk[i];
      }
      ps += __shfl_xor(ps, 16);
      ps += __shfl_xor(ps, 32);
      ls += ps;
      #pragma unroll
      for (int kg = 0; kg < 4; ++kg)
        #pragma unroll
        for (int pr = 0; pr < 2; ++pr) {
          int key2 = kg * 16 + l4 * 4 + pr * 2;
          int sl = (key2 >> 3) ^ (l15 & 7);
          unsigned lo = (unsigned short)f2bs(pk[kg * 4 + pr * 2]);
          unsigned hi = (unsigned short)f2bs(pk[kg * 4 + pr * 2 + 1]);
          *(unsigned*)&Ps[w][l15 * 64 + sl * 8 + (key2 & 7)] = lo | (hi << 16);
        }
      __syncthreads();  // mid-barrier: V(c) landed; Ks reads + Ps writes done

      if (c + 1 < nch) {  // issue K(c+1) — drains at end-barrier, under PV
        const char* ksrc = (const char*)(Kf + ((long)bh * 2048 + k0 + 64) * 192);
        #pragma unroll
        for (int jj = 0; jj < 6; ++jj)
          gload16(ksrc + (jj * 256 + tid) * 16, (char*)Ks + jj * 4096 + lbase);
      }

      __builtin_amdgcn_s_setprio(1);
      #pragma unroll
      for (int ks = 0; ks < 2; ++ks) {
        int psl = (ks * 4 + l4) ^ (l15 & 7);
        bf16x8 pa = *(const bf16x8*)&Ps[w][l15 * 64 + psl * 8];
        #pragma unroll
        for (int f = 0; f < 8; ++f) {
          int vrow = f * 16 + l15;
          int vsl = (ks * 4 + l4) ^ (l15 & 7);
          bf16x8 bv = *(const bf16x8*)&Vs[vrow * 64 + vsl * 8];
          o[f] = MFMA16(pa, bv, o[f]);
        }
      }
      __builtin_amdgcn_s_setprio(0);
      __syncthreads();  // end-barrier: K(c+1) landed; Vs reads done
    }

    #pragma unroll
    for (int r = 0; r < 4; ++r) {
      float lsr = __shfl(ls, l4 * 4 + r);
      float inv = 1.0f / lsr;
      long t = qrow0 + w * 16 + l4 * 4 + r;
      bf16* dst = attn + t * 2048 + h * 128;
      #pragma unroll
      for (int f = 0; f < 8; ++f)
        dst[f * 16 + l15] = __float2bfloat16(o[f][r] * inv);
    }
  }
}

// ---------------------------------------------------------------------------
extern "C" void kernel_launch(void* const* d_in, const int* in_sizes, int n_in,
                              void* d_out, int out_size, void* d_ws, size_t ws_size,
                              hipStream_t stream) {
  const int T = 4096;
  const float* hs_f   = (const float*)d_in[1];
  const float* Wqa_f  = (const float*)d_in[2];
  const float* qln_f  = (const float*)d_in[3];
  const float* Wqb_f  = (const float*)d_in[4];
  const float* Wkva_f = (const float*)d_in[5];
  const float* kvln_f = (const float*)d_in[6];
  const float* Wkvb_f = (const float*)d_in[7];
  const float* Wo_f   = (const float*)d_in[8];

  bf16* base = (bf16*)d_ws;
  bf16* hs_c  = base;                       // 8,388,608 (dead after gemmA) | WoT overlay
  bf16* woT   = base;                       // 4,194,304 (written by prep2, after gemmA)
  bf16* ckq   = base + 8388608;             // 6,291,456 (dead after gemm_dual) | attnb
  bf16* qln_c = base + 14680064;            // 1536  (dead after rms_dual)
  bf16* kvln_c= base + 14681600;            // 512
  bf16* arena = base + 14682112;            // 6,815,744 (WqaT+WkvaT, then WqbT+WkvbT)
  bf16* q     = base + 21497856;            // 12,582,912
  bf16* kvns  = base + 34080768;            // 2,621,440 (T x 640)
  bf16* Kf    = base + 36702208;            // 12,582,912
  bf16* Vt    = base + 49285120;            // 8,388,608  (ends 57,673,728 ≈ 115.3 MB)
  bf16* attnb = ckq;                        // 8,388,608 over dead ckq/qln/arena-head

  // 1) prep1: cvt(hs, q_ln, kv_ln) + WqaT + WkvaT
  prep1<<<5153, 256, 0, stream>>>(hs_f, hs_c, qln_f, qln_c, kvln_f, kvln_c,
                                  Wqa_f, Wkva_f, arena);
  // 2) fused: [ckq | kvns] = hs @ [Wqa | Wkva]  (N=2176, split at 1536)
  gemm_v4<false><<<dim3(17, 32), 256, 0, stream>>>(hs_c, arena, ckq, 2176, 2048,
                                                   2048, 2048, 1536, kvns, 1536);
  // 3) both rmsnorms
  rms_dual<<<8192, 256, 0, stream>>>(ckq, qln_c, kvns, kvln_c);
  // 4) pe rope -> Kf slots 16..23 (raw k_pe; untouched by rms)
  prep_pe<<<T, 256, 0, stream>>>(kvns, Kf);
  // 5) prep2: WqbT + WkvbT + WoT (hs_c dead)
  prep2<<<2688, 256, 0, stream>>>(Wqb_f, arena, Wkvb_f, arena + 4718592, Wo_f, woT);
  // 6) merged: q = ckq@WqbT  |  {Kf k_nope, Vt} = kvns@WkvbT (fused assembly)
  gemm_dual<<<1792, 256, 0, stream>>>(ckq, arena, q, kvns, arena + 4718592, Kf, Vt);
  // 7) attention
  attn_v6<<<512, 256, 0, stream>>>(q, Kf, Vt, attnb);
  // 8) out = attn @ Wo (f32 output)
  gemm_v4<true><<<dim3(16, 32), 256, 0, stream>>>(attnb, woT, d_out, 2048, 2048,
                                                  2048, 2048, 2048, nullptr, 0);
}

// Round 18
// 289.251 us; speedup vs baseline: 2.6216x; 1.0151x over previous
//
#include <hip/hip_runtime.h>
#include <hip/hip_bf16.h>

typedef __hip_bfloat16 bf16;
typedef short bf16x8 __attribute__((ext_vector_type(8)));
typedef float f32x4 __attribute__((ext_vector_type(4)));

#define MFMA16(a, b, c) __builtin_amdgcn_mfma_f32_16x16x32_bf16((a), (b), (c), 0, 0, 0)

__device__ __forceinline__ short f2bs(float f) {
  bf16 h = __float2bfloat16(f);
  return __builtin_bit_cast(short, h);
}
__device__ __forceinline__ float bs2f(short s) {
  return __bfloat162float(__builtin_bit_cast(bf16, s));
}

// async global->LDS, 16B per lane; LDS dest = wave-uniform base + lane*16
__device__ __forceinline__ void gload16(const void* g, const void* l) {
  __builtin_amdgcn_global_load_lds(
      (const __attribute__((address_space(1))) unsigned int*)g,
      (__attribute__((address_space(3))) unsigned int*)l, 16, 0, 0);
}

// ---------------------------------------------------------------------------
// f32->bf16 transpose core: dst[N][K](bf16) = src[K][N](f32)^T, 64x64 tile.
// ---------------------------------------------------------------------------
__device__ __forceinline__ void t_cvt_core(const float* __restrict__ src,
                                           bf16* __restrict__ dst, int K, int N,
                                           int bx, int by, short Ts[64][72]) {
  const long n0 = (long)bx * 64, k0 = (long)by * 64;
  const int r = threadIdx.x >> 2, c4 = threadIdx.x & 3;
  const float* s = src + (k0 + r) * (long)N + n0 + c4 * 16;
  #pragma unroll
  for (int j = 0; j < 4; ++j) {
    float4 v = *(const float4*)(s + j * 4);
    Ts[r][c4 * 16 + j * 4 + 0] = f2bs(v.x);
    Ts[r][c4 * 16 + j * 4 + 1] = f2bs(v.y);
    Ts[r][c4 * 16 + j * 4 + 2] = f2bs(v.z);
    Ts[r][c4 * 16 + j * 4 + 3] = f2bs(v.w);
  }
  __syncthreads();
  union { uint4 v; short sh[8]; } o0, o1;
  #pragma unroll
  for (int j = 0; j < 8; ++j) o0.sh[j] = Ts[c4 * 16 + j][r];
  #pragma unroll
  for (int j = 0; j < 8; ++j) o1.sh[j] = Ts[c4 * 16 + 8 + j][r];
  *(uint4*)(dst + (n0 + r) * (long)K + k0 + c4 * 16)     = o0.v;
  *(uint4*)(dst + (n0 + r) * (long)K + k0 + c4 * 16 + 8) = o1.v;
}

// ---------------------------------------------------------------------------
// prep1: flat cvt (hs, q_ln, kv_ln) + WqaT + WkvaT. 5153 blocks.
// ---------------------------------------------------------------------------
__global__ __launch_bounds__(256) void prep1(
    const float* __restrict__ hs_f, bf16* __restrict__ hs_c,
    const float* __restrict__ qln_f, bf16* __restrict__ qln_c,
    const float* __restrict__ kvln_f, bf16* __restrict__ kvln_c,
    const float* __restrict__ Wqa_f, const float* __restrict__ Wkva_f,
    bf16* __restrict__ arena)
{
  __shared__ __align__(16) short Ts[64][72];
  const int bid = blockIdx.x;
  if (bid < 4097) {
    int i = bid * 256 + threadIdx.x;
    const float* s; bf16* d; int idx;
    if (i < 1048576)            { s = hs_f;   d = hs_c;   idx = i; }
    else if (i < 1048576 + 192) { s = qln_f;  d = qln_c;  idx = i - 1048576; }
    else                        { s = kvln_f; d = kvln_c; idx = i - 1048768; }
    const float4* sp = (const float4*)s;
    float4 a = sp[2 * idx], b = sp[2 * idx + 1];
    union { uint4 v; short sh[8]; } o;
    o.sh[0] = f2bs(a.x); o.sh[1] = f2bs(a.y); o.sh[2] = f2bs(a.z); o.sh[3] = f2bs(a.w);
    o.sh[4] = f2bs(b.x); o.sh[5] = f2bs(b.y); o.sh[6] = f2bs(b.z); o.sh[7] = f2bs(b.w);
    ((uint4*)d)[idx] = o.v;
  } else if (bid < 4097 + 768) {
    int l = bid - 4097;
    t_cvt_core(Wqa_f, arena, 2048, 1536, l % 24, l / 24, Ts);
  } else {
    int l = bid - 4865;
    t_cvt_core(Wkva_f, arena + (size_t)1536 * 2048, 2048, 576, l % 9, l / 9, Ts);
  }
}

// ---------------------------------------------------------------------------
// prep2: WqbT + WkvbT + WoT. 2688 blocks.
// ---------------------------------------------------------------------------
__global__ __launch_bounds__(256) void prep2(
    const float* __restrict__ Wqb_f, bf16* __restrict__ wqbT,
    const float* __restrict__ Wkvb_f, bf16* __restrict__ wkvbT,
    const float* __restrict__ Wo_f, bf16* __restrict__ woT)
{
  __shared__ __align__(16) short Ts[64][72];
  const int bid = blockIdx.x;
  if (bid < 1152)      t_cvt_core(Wqb_f, wqbT, 1536, 3072, bid % 48, bid / 48, Ts);
  else if (bid < 1664) { int l = bid - 1152; t_cvt_core(Wkvb_f, wkvbT, 512, 4096, l % 64, l / 64, Ts); }
  else                 { int l = bid - 1664; t_cvt_core(Wo_f, woT, 2048, 2048, l % 32, l / 32, Ts); }
}

// ---------------------------------------------------------------------------
// gemm core: C = A[M,K] @ BT[N,K]^T. BM=BN=128, BK=64, 4 waves, quadrants.
// XOR(row&7)-swizzled LDS, T1 XCD swizzle. Split epilogue via C2/ncut.
// ---------------------------------------------------------------------------
template<bool F32OUT>
__device__ __forceinline__ void gemm_core(
    short* As, short* Bs,
    const bf16* __restrict__ A, const bf16* __restrict__ BT, void* __restrict__ Cv,
    int N, int K, int lda, int ldb, int ldc, bf16* __restrict__ C2, int ncut,
    int nx, int nwg, int lin)
{
  const int tid = threadIdx.x, lane = tid & 63, w = tid >> 6;
  const int l15 = lane & 15, l4 = lane >> 4;
  const int wr = w >> 1, wc = w & 1;
  const int sl = (lin & 7) * (nwg >> 3) + (lin >> 3);   // nwg % 8 == 0
  const long bm = (long)(sl / nx) * 128, bn = (long)(sl % nx) * 128;
  f32x4 acc[4][4] = {};

  const int srow = tid >> 3;
  const int scs = (tid & 7) ^ (srow & 7);
  const int rsw = l15 & 7;

  for (int k0 = 0; k0 < K; k0 += 64) {
    __syncthreads();
    #pragma unroll
    for (int j = 0; j < 4; ++j) {
      const unsigned lb = __builtin_amdgcn_readfirstlane((j * 256 + w * 64) * 16);
      gload16(A + (bm + j * 32 + srow) * (long)lda + k0 + scs * 8, (char*)As + lb);
      gload16(BT + (bn + j * 32 + srow) * (long)ldb + k0 + scs * 8, (char*)Bs + lb);
    }
    __syncthreads();
    #pragma unroll
    for (int kk = 0; kk < 2; ++kk) {
      bf16x8 a[4], b[4];
      const int slot = (kk * 4 + l4) ^ rsw;
      #pragma unroll
      for (int mi = 0; mi < 4; ++mi)
        a[mi] = *(const bf16x8*)&As[(wr * 64 + mi * 16 + l15) * 64 + slot * 8];
      #pragma unroll
      for (int ni = 0; ni < 4; ++ni)
        b[ni] = *(const bf16x8*)&Bs[(wc * 64 + ni * 16 + l15) * 64 + slot * 8];
      #pragma unroll
      for (int mi = 0; mi < 4; ++mi)
        #pragma unroll
        for (int ni = 0; ni < 4; ++ni)
          acc[mi][ni] = MFMA16(a[mi], b[ni], acc[mi][ni]);
    }
  }
  #pragma unroll
  for (int mi = 0; mi < 4; ++mi)
    #pragma unroll
    for (int ni = 0; ni < 4; ++ni)
      #pragma unroll
      for (int r = 0; r < 4; ++r) {
        long row = bm + wr * 64 + mi * 16 + l4 * 4 + r;
        long col = bn + wc * 64 + ni * 16 + l15;
        float v = acc[mi][ni][r];
        if (F32OUT) {
          ((float*)Cv)[row * ldc + col] = v;
        } else if (C2 && col >= ncut) {
          C2[row * 640 + (col - ncut)] = __float2bfloat16(v);
        } else {
          ((bf16*)Cv)[row * (long)ldc + col] = __float2bfloat16(v);
        }
      }
}

template<bool F32OUT>
__global__ __launch_bounds__(256) void gemm_v4(
    const bf16* __restrict__ A, const bf16* __restrict__ BT, void* __restrict__ Cv,
    int N, int K, int lda, int ldb, int ldc, bf16* __restrict__ C2, int ncut)
{
  __shared__ __align__(16) short As[128 * 64];
  __shared__ __align__(16) short Bs[128 * 64];
  const int nx = gridDim.x, nwg = nx * gridDim.y;
  const int lin = blockIdx.y * nx + blockIdx.x;
  gemm_core<F32OUT>(As, Bs, A, BT, Cv, N, K, lda, ldb, ldc, C2, ncut, nx, nwg, lin);
}

// ---------------------------------------------------------------------------
// gemm_dual: blocks 0..767 -> q = ckq@WqbT; blocks 768..1791 -> kv GEMM with
// fused K/V assembly. BOTH k_nope and V are LDS-transpose-staged and written
// with coalesced uint4 stores (stride S=139 kills the cs-column bank alias).
// ---------------------------------------------------------------------------
#define TS_S 139
__global__ __launch_bounds__(256) void gemm_dual(
    const bf16* __restrict__ ckq, const bf16* __restrict__ wqbT, bf16* __restrict__ q,
    const bf16* __restrict__ kvns, const bf16* __restrict__ wkvbT,
    bf16* __restrict__ Kf, bf16* __restrict__ Vt)
{
  __shared__ __align__(16) short LDSU[128 * TS_S];   // 35.6 KB
  short* As = LDSU;
  short* Bs = LDSU + 8192;
  const int bid = blockIdx.x;
  if (bid < 768) {
    gemm_core<false>(As, Bs, ckq, wqbT, q, 3072, 1536, 1536, 1536, 3072, nullptr, 0,
                     24, 768, bid);
    return;
  }
  // ---- kv segment ----
  const int lin = bid - 768;
  const int tid = threadIdx.x, lane = tid & 63, w = tid >> 6;
  const int l15 = lane & 15, l4 = lane >> 4;
  const int wr = w >> 1, wc = w & 1;
  const int sl = (lin & 7) * 128 + (lin >> 3);   // nwg=1024
  const long bm = (long)(sl / 32) * 128, bn = (long)(sl % 32) * 128;
  f32x4 acc[4][4] = {};
  const int srow = tid >> 3;
  const int scs = (tid & 7) ^ (srow & 7);
  const int rsw = l15 & 7;

  for (int k0 = 0; k0 < 512; k0 += 64) {
    __syncthreads();
    #pragma unroll
    for (int j = 0; j < 4; ++j) {
      const unsigned lb = __builtin_amdgcn_readfirstlane((j * 256 + w * 64) * 16);
      gload16(kvns + (bm + j * 32 + srow) * 640L + k0 + scs * 8, (char*)As + lb);
      gload16(wkvbT + (bn + j * 32 + srow) * 512L + k0 + scs * 8, (char*)Bs + lb);
    }
    __syncthreads();
    #pragma unroll
    for (int kk = 0; kk < 2; ++kk) {
      bf16x8 a[4], b[4];
      const int slot = (kk * 4 + l4) ^ rsw;
      #pragma unroll
      for (int mi = 0; mi < 4; ++mi)
        a[mi] = *(const bf16x8*)&As[(wr * 64 + mi * 16 + l15) * 64 + slot * 8];
      #pragma unroll
      for (int ni = 0; ni < 4; ++ni)
        b[ni] = *(const bf16x8*)&Bs[(wc * 64 + ni * 16 + l15) * 64 + slot * 8];
      #pragma unroll
      for (int mi = 0; mi < 4; ++mi)
        #pragma unroll
        for (int ni = 0; ni < 4; ++ni)
          acc[mi][ni] = MFMA16(a[mi], b[ni], acc[mi][ni]);
    }
  }

  const int h = (int)(bn >> 8);
  const int lc = (int)(bn & 255);                // 0 = k_nope, 128 = v
  const int bh = (int)(bm >> 11) * 16 + h;
  const int tsb = (int)(bm & 2047);

  // stage tile [t_local][dim] into LDS (stride TS_S)
  __syncthreads();
  #pragma unroll
  for (int mi = 0; mi < 4; ++mi)
    #pragma unroll
    for (int ni = 0; ni < 4; ++ni)
      #pragma unroll
      for (int r = 0; r < 4; ++r)
        LDSU[(wr * 64 + mi * 16 + l4 * 4 + r) * TS_S + wc * 64 + ni * 16 + l15] =
            f2bs(acc[mi][ni][r]);
  __syncthreads();

  if (lc == 0) {
    // k_nope: per (t, slot) coalesced 16B write; stored slot = cs ^ (t&7)
    #pragma unroll
    for (int j = 0; j < 8; ++j) {
      int u = j * 256 + tid;
      int tl = u >> 4, cs = u & 15;
      union { uint4 v; short sh[8]; } o;
      #pragma unroll
      for (int i = 0; i < 8; ++i) o.sh[i] = LDSU[tl * TS_S + cs * 8 + i];
      *(uint4*)(Kf + ((size_t)bh * 2048 + tsb + tl) * 192 +
                ((cs ^ (tl & 7)) << 3)) = o.v;
    }
  } else {
    // v: transpose -> Vt coalesced (64-key blocks, (d&7) slot swizzle)
    #pragma unroll
    for (int j = 0; j < 8; ++j) {
      int u = j * 256 + tid;
      int d = u >> 4, slo = u & 15;
      int k0l = (slo >> 3) << 6;     // 0 or 64
      int cs = slo & 7;
      int tb = k0l + cs * 8;
      union { uint4 v; short sh[8]; } o;
      #pragma unroll
      for (int i = 0; i < 8; ++i) o.sh[i] = LDSU[(tb + i) * TS_S + d];
      *(uint4*)(Vt + ((size_t)(bh * 128 + d)) * 2048 + tsb + k0l +
                ((cs ^ (d & 7)) << 3)) = o.v;
    }
  }
}

// ---------------------------------------------------------------------------
// Merged RMSNorm: blocks 0..4095 -> ckq (C=1536); 4096..8191 -> kvns (C=512).
// ---------------------------------------------------------------------------
template<int C>
__device__ __forceinline__ void rms_core(bf16* __restrict__ xr,
                                         const bf16* __restrict__ w, float* red)
{
  constexpr int PER = C / 256;
  const int tid = threadIdx.x;
  float v[PER];
  float ss = 0.f;
  #pragma unroll
  for (int k = 0; k < PER; ++k) {
    float f = __bfloat162float(xr[tid + k * 256]);
    v[k] = f; ss += f * f;
  }
  #pragma unroll
  for (int off = 1; off < 64; off <<= 1) ss += __shfl_xor(ss, off);
  if ((tid & 63) == 0) red[tid >> 6] = ss;
  __syncthreads();
  float tot = red[0] + red[1] + red[2] + red[3];
  float scale = rsqrtf(tot / (float)C + 1e-6f);
  #pragma unroll
  for (int k = 0; k < PER; ++k)
    xr[tid + k * 256] =
        __float2bfloat16(v[k] * scale * __bfloat162float(w[tid + k * 256]));
}

__global__ __launch_bounds__(256) void rms_dual(bf16* __restrict__ ckq,
                                                const bf16* __restrict__ qw,
                                                bf16* __restrict__ kvns,
                                                const bf16* __restrict__ kvw)
{
  __shared__ float red[4];
  const int bid = blockIdx.x;
  if (bid < 4096) rms_core<1536>(ckq + (long)bid * 1536, qw, red);
  else            rms_core<512>(kvns + (long)(bid - 4096) * 640, kvw, red);
}

// ---------------------------------------------------------------------------
// prep_pe: rope k_pe from kvns[t][512..575] -> Kf pe slots (stored 16..23).
// ---------------------------------------------------------------------------
__global__ __launch_bounds__(256) void prep_pe(const bf16* __restrict__ kvns,
                                               bf16* __restrict__ Kf)
{
  __shared__ short pe[64];
  const int t = blockIdx.x, tid = threadIdx.x;
  if (tid < 32) {
    int i = tid;
    float p = (float)(t & 2047);
    float freq = powf(10000.0f, -(float)i / 32.0f);
    float sn, cs;
    sincosf(p * freq, &sn, &cs);
    float y1 = __bfloat162float(kvns[(long)t * 640 + 512 + 2 * i]);
    float y2 = __bfloat162float(kvns[(long)t * 640 + 512 + 2 * i + 1]);
    pe[2 * i]     = f2bs(y1 * cs - y2 * sn);
    pe[2 * i + 1] = f2bs(y2 * cs + y1 * sn);
  }
  __syncthreads();
  if (tid < 128) {
    const int hh = tid >> 3, j = tid & 7;
    const int swz = t & 7;
    const int b = t >> 11, ts = t & 2047;
    uint4 val = *(const uint4*)&pe[(j ^ swz) * 8];
    *(uint4*)(Kf + ((size_t)(b * 16 + hh) * 2048 + ts) * 192 + (16 + j) * 8) = val;
  }
}

// ---------------------------------------------------------------------------
// attn_v6 (r16-proven): swapped-QK softmax + pairing + fused Q-RoPE, exp2.
// ---------------------------------------------------------------------------
__global__ __launch_bounds__(256) void attn_v6(const bf16* __restrict__ q,
                                               const bf16* __restrict__ Kf,
                                               const bf16* __restrict__ Vt,
                                               bf16* __restrict__ attn)
{
  __shared__ __align__(16) short Ks[64 * 192];
  __shared__ __align__(16) short Vs[128 * 64];
  __shared__ __align__(16) short Ps[4][16 * 64];
  const float SC2 = 0.10411442245076847f;  // 192^-0.5 * log2(e)
  const int tid = threadIdx.x, lane = tid & 63, w = tid >> 6;
  const int l15 = lane & 15, l4 = lane >> 4;
  const int lin = blockIdx.x;
  const int x = lin & 7, j = lin >> 3;
  const int bh = x * 4 + (j >> 4), p = j & 15;
  const int b = bh >> 4, h = bh & 15;
  const unsigned lbase = __builtin_amdgcn_readfirstlane(w * 64 * 16);

  #pragma unroll
  for (int half = 0; half < 2; ++half) {
    const int qt = half ? (31 - p) : p;
    const long qrow0 = (long)b * 2048 + qt * 64;
    const int rowt = qt * 64 + w * 16 + l15;

    bf16x8 qf[6];
    {
      const short* qrow = (const short*)q + (qrow0 + w * 16 + l15) * 3072 + h * 192;
      #pragma unroll
      for (int kc = 0; kc < 6; ++kc)
        qf[kc] = *(const bf16x8*)(qrow + kc * 32 + l4 * 8);
    }
    {  // fused GPT-J RoPE on pe fragments (cols 128..191 = kc 4,5)
      float pos = (float)rowt;
      #pragma unroll
      for (int kc = 4; kc < 6; ++kc)
        #pragma unroll
        for (int pr = 0; pr < 4; ++pr) {
          int i = (kc - 4) * 16 + l4 * 4 + pr;
          float freq = __expf((float)i * -0.28782313662425572f);  // 10000^(-i/32)
          float sn, cs;
          sincosf(pos * freq, &sn, &cs);
          float x1 = bs2f(qf[kc][2 * pr]), x2 = bs2f(qf[kc][2 * pr + 1]);
          qf[kc][2 * pr]     = f2bs(x1 * cs - x2 * sn);
          qf[kc][2 * pr + 1] = f2bs(x2 * cs + x1 * sn);
        }
    }
    f32x4 o[8] = {};
    float mreg = -1e30f, ls = 0.f;
    const int nch = qt + 1;

    {  // prologue: stage K chunk 0
      const char* ksrc = (const char*)(Kf + (long)bh * 2048 * 192);
      #pragma unroll
      for (int jj = 0; jj < 6; ++jj)
        gload16(ksrc + (jj * 256 + tid) * 16, (char*)Ks + jj * 4096 + lbase);
    }
    __syncthreads();

    for (int c = 0; c < nch; ++c) {
      const int k0 = c * 64;
      {  // issue V(c) — drains at mid-barrier, hidden under QK+softmax
        #pragma unroll
        for (int jj = 0; jj < 4; ++jj) {
          int seg = jj * 256 + tid;
          const bf16* vsrc = Vt + ((long)bh * 128 + (seg >> 3)) * 2048 + k0 + (seg & 7) * 8;
          gload16(vsrc, (char*)Vs + jj * 4096 + lbase);
        }
      }
      __builtin_amdgcn_s_setprio(1);
      f32x4 s[4] = {};
      #pragma unroll
      for (int kc = 0; kc < 6; ++kc)
        #pragma unroll
        for (int kg = 0; kg < 4; ++kg) {
          int row = kg * 16 + l15;
          int slot = (kc * 4 + l4) ^ (l15 & 7);
          bf16x8 kb = *(const bf16x8*)&Ks[row * 192 + slot * 8];
          s[kg] = MFMA16(kb, qf[kc], s[kg]);   // SWAPPED: D[key][qrow]
        }
      __builtin_amdgcn_s_setprio(0);

      const bool diag = (c == qt);
      float pk[16];
      #pragma unroll
      for (int kg = 0; kg < 4; ++kg)
        #pragma unroll
        for (int r = 0; r < 4; ++r) {
          float v = s[kg][r];
          if (diag && (k0 + kg * 16 + l4 * 4 + r > rowt)) v = -1e30f;
          pk[kg * 4 + r] = v;
        }
      float cm = pk[0];
      #pragma unroll
      for (int i = 1; i < 16; ++i) cm = fmaxf(cm, pk[i]);
      cm = fmaxf(cm, __shfl_xor(cm, 16));
      cm = fmaxf(cm, __shfl_xor(cm, 32));
      cm *= SC2;  // scale once (monotone)
      if (__ballot(cm > mreg + 12.0f)) {  // defer-max rescale (wave-uniform)
        float mn = fmaxf(mreg, cm);
        float al = exp2f(mreg - mn);
        ls *= al;
        float af[4];
        #pragma unroll
        for (int r = 0; r < 4; ++r) af[r] = __shfl(al, l4 * 4 + r);
        #pragma unroll
        for (int f = 0; f < 8; ++f)
          #pragma unroll
          for (int r = 0; r < 4; ++r) o[f][r] *= af[r];
        mreg = mn;
      }
      float ps = 0.f;
      #pragma unroll
      for (int i = 0; i < 16; ++i) {
        pk[i] = exp2f(fmaf(pk[i], SC2, -mreg));
        ps += pk[i];
      }
      ps += __shfl_xor(ps, 16);
      ps += __shfl_xor(ps, 32);
      ls += ps;
      #pragma unroll
      for (int kg = 0; kg < 4; ++kg)
        #pragma unroll
        for (int pr = 0; pr < 2; ++pr) {
          int key2 = kg * 16 + l4 * 4 + pr * 2;
          int sl = (key2 >> 3) ^ (l15 & 7);
          unsigned lo = (unsigned short)f2bs(pk[kg * 4 + pr * 2]);
          unsigned hi = (unsigned short)f2bs(pk[kg * 4 + pr * 2 + 1]);
          *(unsigned*)&Ps[w][l15 * 64 + sl * 8 + (key2 & 7)] = lo | (hi << 16);
        }
      __syncthreads();  // mid-barrier: V(c) landed; Ks reads + Ps writes done

      if (c + 1 < nch) {  // issue K(c+1) — drains at end-barrier, under PV
        const char* ksrc = (const char*)(Kf + ((long)bh * 2048 + k0 + 64) * 192);
        #pragma unroll
        for (int jj = 0; jj < 6; ++jj)
          gload16(ksrc + (jj * 256 + tid) * 16, (char*)Ks + jj * 4096 + lbase);
      }

      __builtin_amdgcn_s_setprio(1);
      #pragma unroll
      for (int ks = 0; ks < 2; ++ks) {
        int psl = (ks * 4 + l4) ^ (l15 & 7);
        bf16x8 pa = *(const bf16x8*)&Ps[w][l15 * 64 + psl * 8];
        #pragma unroll
        for (int f = 0; f < 8; ++f) {
          int vrow = f * 16 + l15;
          int vsl = (ks * 4 + l4) ^ (l15 & 7);
          bf16x8 bv = *(const bf16x8*)&Vs[vrow * 64 + vsl * 8];
          o[f] = MFMA16(pa, bv, o[f]);
        }
      }
      __builtin_amdgcn_s_setprio(0);
      __syncthreads();  // end-barrier: K(c+1) landed; Vs reads done
    }

    #pragma unroll
    for (int r = 0; r < 4; ++r) {
      float lsr = __shfl(ls, l4 * 4 + r);
      float inv = 1.0f / lsr;
      long t = qrow0 + w * 16 + l4 * 4 + r;
      bf16* dst = attn + t * 2048 + h * 128;
      #pragma unroll
      for (int f = 0; f < 8; ++f)
        dst[f * 16 + l15] = __float2bfloat16(o[f][r] * inv);
    }
  }
}

// ---------------------------------------------------------------------------
extern "C" void kernel_launch(void* const* d_in, const int* in_sizes, int n_in,
                              void* d_out, int out_size, void* d_ws, size_t ws_size,
                              hipStream_t stream) {
  const int T = 4096;
  const float* hs_f   = (const float*)d_in[1];
  const float* Wqa_f  = (const float*)d_in[2];
  const float* qln_f  = (const float*)d_in[3];
  const float* Wqb_f  = (const float*)d_in[4];
  const float* Wkva_f = (const float*)d_in[5];
  const float* kvln_f = (const float*)d_in[6];
  const float* Wkvb_f = (const float*)d_in[7];
  const float* Wo_f   = (const float*)d_in[8];

  bf16* base = (bf16*)d_ws;
  bf16* hs_c  = base;                       // 8,388,608 (dead after gemmA) | WoT overlay
  bf16* woT   = base;                       // 4,194,304 (written by prep2, after gemmA)
  bf16* ckq   = base + 8388608;             // 6,291,456 (dead after gemm_dual) | attnb
  bf16* qln_c = base + 14680064;            // 1536  (dead after rms_dual)
  bf16* kvln_c= base + 14681600;            // 512
  bf16* arena = base + 14682112;            // 6,815,744 (WqaT+WkvaT, then WqbT+WkvbT)
  bf16* q     = base + 21497856;            // 12,582,912
  bf16* kvns  = base + 34080768;            // 2,621,440 (T x 640)
  bf16* Kf    = base + 36702208;            // 12,582,912
  bf16* Vt    = base + 49285120;            // 8,388,608  (ends 57,673,728 ≈ 115.3 MB)
  bf16* attnb = ckq;                        // 8,388,608 over dead ckq/qln/arena-head

  // 1) prep1: cvt(hs, q_ln, kv_ln) + WqaT + WkvaT
  prep1<<<5153, 256, 0, stream>>>(hs_f, hs_c, qln_f, qln_c, kvln_f, kvln_c,
                                  Wqa_f, Wkva_f, arena);
  // 2) fused: [ckq | kvns] = hs @ [Wqa | Wkva]  (N=2176, split at 1536)
  gemm_v4<false><<<dim3(17, 32), 256, 0, stream>>>(hs_c, arena, ckq, 2176, 2048,
                                                   2048, 2048, 1536, kvns, 1536);
  // 3) both rmsnorms
  rms_dual<<<8192, 256, 0, stream>>>(ckq, qln_c, kvns, kvln_c);
  // 4) pe rope -> Kf slots 16..23 (raw k_pe; untouched by rms)
  prep_pe<<<T, 256, 0, stream>>>(kvns, Kf);
  // 5) prep2: WqbT + WkvbT + WoT (hs_c dead)
  prep2<<<2688, 256, 0, stream>>>(Wqb_f, arena, Wkvb_f, arena + 4718592, Wo_f, woT);
  // 6) merged: q = ckq@WqbT  |  {Kf k_nope, Vt} = kvns@WkvbT (fused assembly)
  gemm_dual<<<1792, 256, 0, stream>>>(ckq, arena, q, kvns, arena + 4718592, Kf, Vt);
  // 7) attention
  attn_v6<<<512, 256, 0, stream>>>(q, Kf, Vt, attnb);
  // 8) out = attn @ Wo (f32 output)
  gemm_v4<true><<<dim3(16, 32), 256, 0, stream>>>(attnb, woT, d_out, 2048, 2048,
                                                  2048, 2048, 2048, nullptr, 0);
}

// Round 19
// 282.960 us; speedup vs baseline: 2.6799x; 1.0222x over previous
//
#include <hip/hip_runtime.h>
#include <hip/hip_bf16.h>

typedef __hip_bfloat16 bf16;
typedef short bf16x8 __attribute__((ext_vector_type(8)));
typedef float f32x4 __attribute__((ext_vector_type(4)));

#define MFMA16(a, b, c) __builtin_amdgcn_mfma_f32_16x16x32_bf16((a), (b), (c), 0, 0, 0)

__device__ __forceinline__ short f2bs(float f) {
  bf16 h = __float2bfloat16(f);
  return __builtin_bit_cast(short, h);
}
__device__ __forceinline__ float bs2f(short s) {
  return __bfloat162float(__builtin_bit_cast(bf16, s));
}

// async global->LDS, 16B per lane; LDS dest = wave-uniform base + lane*16
__device__ __forceinline__ void gload16(const void* g, const void* l) {
  __builtin_amdgcn_global_load_lds(
      (const __attribute__((address_space(1))) unsigned int*)g,
      (__attribute__((address_space(3))) unsigned int*)l, 16, 0, 0);
}

// ---------------------------------------------------------------------------
// f32->bf16 transpose core: dst[N][K](bf16) = src[K][N](f32)^T, 64x64 tile.
// ---------------------------------------------------------------------------
__device__ __forceinline__ void t_cvt_core(const float* __restrict__ src,
                                           bf16* __restrict__ dst, int K, int N,
                                           int bx, int by, short Ts[64][72]) {
  const long n0 = (long)bx * 64, k0 = (long)by * 64;
  const int r = threadIdx.x >> 2, c4 = threadIdx.x & 3;
  const float* s = src + (k0 + r) * (long)N + n0 + c4 * 16;
  #pragma unroll
  for (int j = 0; j < 4; ++j) {
    float4 v = *(const float4*)(s + j * 4);
    Ts[r][c4 * 16 + j * 4 + 0] = f2bs(v.x);
    Ts[r][c4 * 16 + j * 4 + 1] = f2bs(v.y);
    Ts[r][c4 * 16 + j * 4 + 2] = f2bs(v.z);
    Ts[r][c4 * 16 + j * 4 + 3] = f2bs(v.w);
  }
  __syncthreads();
  union { uint4 v; short sh[8]; } o0, o1;
  #pragma unroll
  for (int j = 0; j < 8; ++j) o0.sh[j] = Ts[c4 * 16 + j][r];
  #pragma unroll
  for (int j = 0; j < 8; ++j) o1.sh[j] = Ts[c4 * 16 + 8 + j][r];
  *(uint4*)(dst + (n0 + r) * (long)K + k0 + c4 * 16)     = o0.v;
  *(uint4*)(dst + (n0 + r) * (long)K + k0 + c4 * 16 + 8) = o1.v;
}

// ---------------------------------------------------------------------------
// mega-prep: flat cvt (hs, q_ln, kv_ln) + ALL five weight transposes. 7841 blk.
// ---------------------------------------------------------------------------
__global__ __launch_bounds__(256) void prep_all(
    const float* __restrict__ hs_f, bf16* __restrict__ hs_c,
    const float* __restrict__ qln_f, bf16* __restrict__ qln_c,
    const float* __restrict__ kvln_f, bf16* __restrict__ kvln_c,
    const float* __restrict__ Wqa_f, bf16* __restrict__ wqaT,
    const float* __restrict__ Wkva_f, bf16* __restrict__ wkvaT,
    const float* __restrict__ Wqb_f, bf16* __restrict__ wqbT,
    const float* __restrict__ Wkvb_f, bf16* __restrict__ wkvbT,
    const float* __restrict__ Wo_f, bf16* __restrict__ woT)
{
  __shared__ __align__(16) short Ts[64][72];
  const int bid = blockIdx.x;
  if (bid < 4097) {
    int i = bid * 256 + threadIdx.x;
    const float* s; bf16* d; int idx;
    if (i < 1048576)            { s = hs_f;   d = hs_c;   idx = i; }
    else if (i < 1048576 + 192) { s = qln_f;  d = qln_c;  idx = i - 1048576; }
    else                        { s = kvln_f; d = kvln_c; idx = i - 1048768; }
    const float4* sp = (const float4*)s;
    float4 a = sp[2 * idx], b = sp[2 * idx + 1];
    union { uint4 v; short sh[8]; } o;
    o.sh[0] = f2bs(a.x); o.sh[1] = f2bs(a.y); o.sh[2] = f2bs(a.z); o.sh[3] = f2bs(a.w);
    o.sh[4] = f2bs(b.x); o.sh[5] = f2bs(b.y); o.sh[6] = f2bs(b.z); o.sh[7] = f2bs(b.w);
    ((uint4*)d)[idx] = o.v;
  } else if (bid < 4865) {
    int l = bid - 4097;  t_cvt_core(Wqa_f, wqaT, 2048, 1536, l % 24, l / 24, Ts);
  } else if (bid < 5153) {
    int l = bid - 4865;  t_cvt_core(Wkva_f, wkvaT, 2048, 576, l % 9, l / 9, Ts);
  } else if (bid < 6305) {
    int l = bid - 5153;  t_cvt_core(Wqb_f, wqbT, 1536, 3072, l % 48, l / 48, Ts);
  } else if (bid < 6817) {
    int l = bid - 6305;  t_cvt_core(Wkvb_f, wkvbT, 512, 4096, l % 64, l / 64, Ts);
  } else {
    int l = bid - 6817;  t_cvt_core(Wo_f, woT, 2048, 2048, l % 32, l / 32, Ts);
  }
}

// ---------------------------------------------------------------------------
// gemm core: C = A[M,K] @ BT[N,K]^T. BM=BN=128, BK=64, 4 waves, quadrants.
// XOR(row&7)-swizzled LDS, T1 XCD swizzle. Split epilogue via C2/ncut.
// ---------------------------------------------------------------------------
template<bool F32OUT>
__device__ __forceinline__ void gemm_core(
    short* As, short* Bs,
    const bf16* __restrict__ A, const bf16* __restrict__ BT, void* __restrict__ Cv,
    int N, int K, int lda, int ldb, int ldc, bf16* __restrict__ C2, int ncut,
    int nx, int nwg, int lin)
{
  const int tid = threadIdx.x, lane = tid & 63, w = tid >> 6;
  const int l15 = lane & 15, l4 = lane >> 4;
  const int wr = w >> 1, wc = w & 1;
  const int sl = (lin & 7) * (nwg >> 3) + (lin >> 3);   // nwg % 8 == 0
  const long bm = (long)(sl / nx) * 128, bn = (long)(sl % nx) * 128;
  f32x4 acc[4][4] = {};

  const int srow = tid >> 3;
  const int scs = (tid & 7) ^ (srow & 7);
  const int rsw = l15 & 7;

  for (int k0 = 0; k0 < K; k0 += 64) {
    __syncthreads();
    #pragma unroll
    for (int j = 0; j < 4; ++j) {
      const unsigned lb = __builtin_amdgcn_readfirstlane((j * 256 + w * 64) * 16);
      gload16(A + (bm + j * 32 + srow) * (long)lda + k0 + scs * 8, (char*)As + lb);
      gload16(BT + (bn + j * 32 + srow) * (long)ldb + k0 + scs * 8, (char*)Bs + lb);
    }
    __syncthreads();
    #pragma unroll
    for (int kk = 0; kk < 2; ++kk) {
      bf16x8 a[4], b[4];
      const int slot = (kk * 4 + l4) ^ rsw;
      #pragma unroll
      for (int mi = 0; mi < 4; ++mi)
        a[mi] = *(const bf16x8*)&As[(wr * 64 + mi * 16 + l15) * 64 + slot * 8];
      #pragma unroll
      for (int ni = 0; ni < 4; ++ni)
        b[ni] = *(const bf16x8*)&Bs[(wc * 64 + ni * 16 + l15) * 64 + slot * 8];
      #pragma unroll
      for (int mi = 0; mi < 4; ++mi)
        #pragma unroll
        for (int ni = 0; ni < 4; ++ni)
          acc[mi][ni] = MFMA16(a[mi], b[ni], acc[mi][ni]);
    }
  }
  #pragma unroll
  for (int mi = 0; mi < 4; ++mi)
    #pragma unroll
    for (int ni = 0; ni < 4; ++ni)
      #pragma unroll
      for (int r = 0; r < 4; ++r) {
        long row = bm + wr * 64 + mi * 16 + l4 * 4 + r;
        long col = bn + wc * 64 + ni * 16 + l15;
        float v = acc[mi][ni][r];
        if (F32OUT) {
          ((float*)Cv)[row * ldc + col] = v;
        } else if (C2 && col >= ncut) {
          C2[row * 640 + (col - ncut)] = __float2bfloat16(v);
        } else {
          ((bf16*)Cv)[row * (long)ldc + col] = __float2bfloat16(v);
        }
      }
}

template<bool F32OUT>
__global__ __launch_bounds__(256) void gemm_v4(
    const bf16* __restrict__ A, const bf16* __restrict__ BT, void* __restrict__ Cv,
    int N, int K, int lda, int ldb, int ldc, bf16* __restrict__ C2, int ncut)
{
  __shared__ __align__(16) short As[128 * 64];
  __shared__ __align__(16) short Bs[128 * 64];
  const int nx = gridDim.x, nwg = nx * gridDim.y;
  const int lin = blockIdx.y * nx + blockIdx.x;
  gemm_core<F32OUT>(As, Bs, A, BT, Cv, N, K, lda, ldb, ldc, C2, ncut, nx, nwg, lin);
}

// ---------------------------------------------------------------------------
// gemm_dual: blocks 0..767 -> q = ckq@WqbT; blocks 768..1791 -> kv GEMM with
// fused K/V assembly (LDS-staged coalesced writes; TS_S=139 kills bank alias).
// ---------------------------------------------------------------------------
#define TS_S 139
__global__ __launch_bounds__(256) void gemm_dual(
    const bf16* __restrict__ ckq, const bf16* __restrict__ wqbT, bf16* __restrict__ q,
    const bf16* __restrict__ kvns, const bf16* __restrict__ wkvbT,
    bf16* __restrict__ Kf, bf16* __restrict__ Vt)
{
  __shared__ __align__(16) short LDSU[128 * TS_S];   // 35.6 KB
  short* As = LDSU;
  short* Bs = LDSU + 8192;
  const int bid = blockIdx.x;
  if (bid < 768) {
    gemm_core<false>(As, Bs, ckq, wqbT, q, 3072, 1536, 1536, 1536, 3072, nullptr, 0,
                     24, 768, bid);
    return;
  }
  const int lin = bid - 768;
  const int tid = threadIdx.x, lane = tid & 63, w = tid >> 6;
  const int l15 = lane & 15, l4 = lane >> 4;
  const int wr = w >> 1, wc = w & 1;
  const int sl = (lin & 7) * 128 + (lin >> 3);   // nwg=1024
  const long bm = (long)(sl / 32) * 128, bn = (long)(sl % 32) * 128;
  f32x4 acc[4][4] = {};
  const int srow = tid >> 3;
  const int scs = (tid & 7) ^ (srow & 7);
  const int rsw = l15 & 7;

  for (int k0 = 0; k0 < 512; k0 += 64) {
    __syncthreads();
    #pragma unroll
    for (int j = 0; j < 4; ++j) {
      const unsigned lb = __builtin_amdgcn_readfirstlane((j * 256 + w * 64) * 16);
      gload16(kvns + (bm + j * 32 + srow) * 640L + k0 + scs * 8, (char*)As + lb);
      gload16(wkvbT + (bn + j * 32 + srow) * 512L + k0 + scs * 8, (char*)Bs + lb);
    }
    __syncthreads();
    #pragma unroll
    for (int kk = 0; kk < 2; ++kk) {
      bf16x8 a[4], b[4];
      const int slot = (kk * 4 + l4) ^ rsw;
      #pragma unroll
      for (int mi = 0; mi < 4; ++mi)
        a[mi] = *(const bf16x8*)&As[(wr * 64 + mi * 16 + l15) * 64 + slot * 8];
      #pragma unroll
      for (int ni = 0; ni < 4; ++ni)
        b[ni] = *(const bf16x8*)&Bs[(wc * 64 + ni * 16 + l15) * 64 + slot * 8];
      #pragma unroll
      for (int mi = 0; mi < 4; ++mi)
        #pragma unroll
        for (int ni = 0; ni < 4; ++ni)
          acc[mi][ni] = MFMA16(a[mi], b[ni], acc[mi][ni]);
    }
  }

  const int h = (int)(bn >> 8);
  const int lc = (int)(bn & 255);                // 0 = k_nope, 128 = v
  const int bh = (int)(bm >> 11) * 16 + h;
  const int tsb = (int)(bm & 2047);

  __syncthreads();
  #pragma unroll
  for (int mi = 0; mi < 4; ++mi)
    #pragma unroll
    for (int ni = 0; ni < 4; ++ni)
      #pragma unroll
      for (int r = 0; r < 4; ++r)
        LDSU[(wr * 64 + mi * 16 + l4 * 4 + r) * TS_S + wc * 64 + ni * 16 + l15] =
            f2bs(acc[mi][ni][r]);
  __syncthreads();

  if (lc == 0) {
    #pragma unroll
    for (int j = 0; j < 8; ++j) {
      int u = j * 256 + tid;
      int tl = u >> 4, cs = u & 15;
      union { uint4 v; short sh[8]; } o;
      #pragma unroll
      for (int i = 0; i < 8; ++i) o.sh[i] = LDSU[tl * TS_S + cs * 8 + i];
      *(uint4*)(Kf + ((size_t)bh * 2048 + tsb + tl) * 192 +
                ((cs ^ (tl & 7)) << 3)) = o.v;
    }
  } else {
    #pragma unroll
    for (int j = 0; j < 8; ++j) {
      int u = j * 256 + tid;
      int d = u >> 4, slo = u & 15;
      int k0l = (slo >> 3) << 6;     // 0 or 64
      int cs = slo & 7;
      int tb = k0l + cs * 8;
      union { uint4 v; short sh[8]; } o;
      #pragma unroll
      for (int i = 0; i < 8; ++i) o.sh[i] = LDSU[(tb + i) * TS_S + d];
      *(uint4*)(Vt + ((size_t)(bh * 128 + d)) * 2048 + tsb + k0l +
                ((cs ^ (d & 7)) << 3)) = o.v;
    }
  }
}

// ---------------------------------------------------------------------------
// rms_pe_dual: blocks 0..4095 -> rms ckq; 4096..8191 -> rms kvns + fused
// k_pe rope -> Kf pe slots (stored 16..23; raw cols 512.. untouched by rms).
// ---------------------------------------------------------------------------
template<int C>
__device__ __forceinline__ void rms_core(bf16* __restrict__ xr,
                                         const bf16* __restrict__ w, float* red)
{
  constexpr int PER = C / 256;
  const int tid = threadIdx.x;
  float v[PER];
  float ss = 0.f;
  #pragma unroll
  for (int k = 0; k < PER; ++k) {
    float f = __bfloat162float(xr[tid + k * 256]);
    v[k] = f; ss += f * f;
  }
  #pragma unroll
  for (int off = 1; off < 64; off <<= 1) ss += __shfl_xor(ss, off);
  if ((tid & 63) == 0) red[tid >> 6] = ss;
  __syncthreads();
  float tot = red[0] + red[1] + red[2] + red[3];
  float scale = rsqrtf(tot / (float)C + 1e-6f);
  #pragma unroll
  for (int k = 0; k < PER; ++k)
    xr[tid + k * 256] =
        __float2bfloat16(v[k] * scale * __bfloat162float(w[tid + k * 256]));
}

__global__ __launch_bounds__(256) void rms_pe_dual(bf16* __restrict__ ckq,
                                                   const bf16* __restrict__ qw,
                                                   bf16* __restrict__ kvns,
                                                   const bf16* __restrict__ kvw,
                                                   bf16* __restrict__ Kf)
{
  __shared__ float red[4];
  __shared__ short pe[64];
  const int bid = blockIdx.x, tid = threadIdx.x;
  if (bid < 4096) {
    rms_core<1536>(ckq + (long)bid * 1536, qw, red);
    return;
  }
  const int t = bid - 4096;
  rms_core<512>(kvns + (long)t * 640, kvw, red);
  if (tid < 32) {
    int i = tid;
    float p = (float)(t & 2047);
    float freq = powf(10000.0f, -(float)i / 32.0f);
    float sn, cs;
    sincosf(p * freq, &sn, &cs);
    float y1 = __bfloat162float(kvns[(long)t * 640 + 512 + 2 * i]);
    float y2 = __bfloat162float(kvns[(long)t * 640 + 512 + 2 * i + 1]);
    pe[2 * i]     = f2bs(y1 * cs - y2 * sn);
    pe[2 * i + 1] = f2bs(y2 * cs + y1 * sn);
  }
  __syncthreads();
  if (tid < 128) {
    const int hh = tid >> 3, j = tid & 7;
    const int swz = t & 7;
    const int b = t >> 11, ts = t & 2047;
    uint4 val = *(const uint4*)&pe[(j ^ swz) * 8];
    *(uint4*)(Kf + ((size_t)(b * 16 + hh) * 2048 + ts) * 192 + (16 + j) * 8) = val;
  }
}

// ---------------------------------------------------------------------------
// attn_v7: v6 + DOUBLE-BUFFERED Ks. K(c+1) and V(c) both issued at chunk
// start -> both drain at mid-barrier under QK+softmax; end-barrier is a pure
// WAR fence (no loads in flight). LDS 72 KB (grid 512 = 2 blocks/CU cap).
// ---------------------------------------------------------------------------
__global__ __launch_bounds__(256) void attn_v7(const bf16* __restrict__ q,
                                               const bf16* __restrict__ Kf,
                                               const bf16* __restrict__ Vt,
                                               bf16* __restrict__ attn)
{
  __shared__ __align__(16) short Ks[2 * 64 * 192];   // 48 KB, double-buffered
  __shared__ __align__(16) short Vs[128 * 64];       // 16 KB
  __shared__ __align__(16) short Ps[4][16 * 64];     // 8 KB
  const float SC2 = 0.10411442245076847f;  // 192^-0.5 * log2(e)
  const int tid = threadIdx.x, lane = tid & 63, w = tid >> 6;
  const int l15 = lane & 15, l4 = lane >> 4;
  const int lin = blockIdx.x;
  const int x = lin & 7, j = lin >> 3;
  const int bh = x * 4 + (j >> 4), p = j & 15;
  const int b = bh >> 4, h = bh & 15;
  const unsigned lbase = __builtin_amdgcn_readfirstlane(w * 64 * 16);

  #pragma unroll
  for (int half = 0; half < 2; ++half) {
    const int qt = half ? (31 - p) : p;
    const long qrow0 = (long)b * 2048 + qt * 64;
    const int rowt = qt * 64 + w * 16 + l15;

    bf16x8 qf[6];
    {
      const short* qrow = (const short*)q + (qrow0 + w * 16 + l15) * 3072 + h * 192;
      #pragma unroll
      for (int kc = 0; kc < 6; ++kc)
        qf[kc] = *(const bf16x8*)(qrow + kc * 32 + l4 * 8);
    }
    {  // fused GPT-J RoPE on pe fragments (cols 128..191 = kc 4,5)
      float pos = (float)rowt;
      #pragma unroll
      for (int kc = 4; kc < 6; ++kc)
        #pragma unroll
        for (int pr = 0; pr < 4; ++pr) {
          int i = (kc - 4) * 16 + l4 * 4 + pr;
          float freq = __expf((float)i * -0.28782313662425572f);  // 10000^(-i/32)
          float sn, cs;
          sincosf(pos * freq, &sn, &cs);
          float x1 = bs2f(qf[kc][2 * pr]), x2 = bs2f(qf[kc][2 * pr + 1]);
          qf[kc][2 * pr]     = f2bs(x1 * cs - x2 * sn);
          qf[kc][2 * pr + 1] = f2bs(x2 * cs + x1 * sn);
        }
    }
    f32x4 o[8] = {};
    float mreg = -1e30f, ls = 0.f;
    const int nch = qt + 1;

    {  // prologue: stage K chunk 0 into Ks buf 0
      const char* ksrc = (const char*)(Kf + (long)bh * 2048 * 192);
      #pragma unroll
      for (int jj = 0; jj < 6; ++jj)
        gload16(ksrc + (jj * 256 + tid) * 16, (char*)Ks + jj * 4096 + lbase);
    }
    __syncthreads();

    for (int c = 0; c < nch; ++c) {
      const int k0 = c * 64;
      const int cb = (c & 1) * 24576;          // current Ks byte offset
      if (c + 1 < nch) {  // issue K(c+1) into other Ks buf — drains at mid-bar
        const char* ksrc = (const char*)(Kf + ((long)bh * 2048 + k0 + 64) * 192);
        const int nb = ((c + 1) & 1) * 24576;
        #pragma unroll
        for (int jj = 0; jj < 6; ++jj)
          gload16(ksrc + (jj * 256 + tid) * 16, (char*)Ks + nb + jj * 4096 + lbase);
      }
      {  // issue V(c) — drains at mid-barrier
        #pragma unroll
        for (int jj = 0; jj < 4; ++jj) {
          int seg = jj * 256 + tid;
          const bf16* vsrc = Vt + ((long)bh * 128 + (seg >> 3)) * 2048 + k0 + (seg & 7) * 8;
          gload16(vsrc, (char*)Vs + jj * 4096 + lbase);
        }
      }
      __builtin_amdgcn_s_setprio(1);
      f32x4 s[4] = {};
      #pragma unroll
      for (int kc = 0; kc < 6; ++kc)
        #pragma unroll
        for (int kg = 0; kg < 4; ++kg) {
          int row = kg * 16 + l15;
          int slot = (kc * 4 + l4) ^ (l15 & 7);
          bf16x8 kb = *(const bf16x8*)((const char*)Ks + cb + (row * 192 + slot * 8) * 2);
          s[kg] = MFMA16(kb, qf[kc], s[kg]);   // SWAPPED: D[key][qrow]
        }
      __builtin_amdgcn_s_setprio(0);

      const bool diag = (c == qt);
      float pk[16];
      #pragma unroll
      for (int kg = 0; kg < 4; ++kg)
        #pragma unroll
        for (int r = 0; r < 4; ++r) {
          float v = s[kg][r];
          if (diag && (k0 + kg * 16 + l4 * 4 + r > rowt)) v = -1e30f;
          pk[kg * 4 + r] = v;
        }
      float cm = pk[0];
      #pragma unroll
      for (int i = 1; i < 16; ++i) cm = fmaxf(cm, pk[i]);
      cm = fmaxf(cm, __shfl_xor(cm, 16));
      cm = fmaxf(cm, __shfl_xor(cm, 32));
      cm *= SC2;  // scale once (monotone)
      if (__ballot(cm > mreg + 12.0f)) {  // defer-max rescale (wave-uniform)
        float mn = fmaxf(mreg, cm);
        float al = exp2f(mreg - mn);
        ls *= al;
        float af[4];
        #pragma unroll
        for (int r = 0; r < 4; ++r) af[r] = __shfl(al, l4 * 4 + r);
        #pragma unroll
        for (int f = 0; f < 8; ++f)
          #pragma unroll
          for (int r = 0; r < 4; ++r) o[f][r] *= af[r];
        mreg = mn;
      }
      float ps = 0.f;
      #pragma unroll
      for (int i = 0; i < 16; ++i) {
        pk[i] = exp2f(fmaf(pk[i], SC2, -mreg));
        ps += pk[i];
      }
      ps += __shfl_xor(ps, 16);
      ps += __shfl_xor(ps, 32);
      ls += ps;
      #pragma unroll
      for (int kg = 0; kg < 4; ++kg)
        #pragma unroll
        for (int pr = 0; pr < 2; ++pr) {
          int key2 = kg * 16 + l4 * 4 + pr * 2;
          int sl = (key2 >> 3) ^ (l15 & 7);
          unsigned lo = (unsigned short)f2bs(pk[kg * 4 + pr * 2]);
          unsigned hi = (unsigned short)f2bs(pk[kg * 4 + pr * 2 + 1]);
          *(unsigned*)&Ps[w][l15 * 64 + sl * 8 + (key2 & 7)] = lo | (hi << 16);
        }
      __syncthreads();  // mid-barrier: V(c) + K(c+1) landed; Ks reads + Ps done

      __builtin_amdgcn_s_setprio(1);
      #pragma unroll
      for (int ks = 0; ks < 2; ++ks) {
        int psl = (ks * 4 + l4) ^ (l15 & 7);
        bf16x8 pa = *(const bf16x8*)&Ps[w][l15 * 64 + psl * 8];
        #pragma unroll
        for (int f = 0; f < 8; ++f) {
          int vrow = f * 16 + l15;
          int vsl = (ks * 4 + l4) ^ (l15 & 7);
          bf16x8 bv = *(const bf16x8*)&Vs[vrow * 64 + vsl * 8];
          o[f] = MFMA16(pa, bv, o[f]);
        }
      }
      __builtin_amdgcn_s_setprio(0);
      __syncthreads();  // end-barrier: pure WAR fence (Vs/Ps); nothing in flight
    }

    #pragma unroll
    for (int r = 0; r < 4; ++r) {
      float lsr = __shfl(ls, l4 * 4 + r);
      float inv = 1.0f / lsr;
      long t = qrow0 + w * 16 + l4 * 4 + r;
      bf16* dst = attn + t * 2048 + h * 128;
      #pragma unroll
      for (int f = 0; f < 8; ++f)
        dst[f * 16 + l15] = __float2bfloat16(o[f][r] * inv);
    }
  }
}

// ---------------------------------------------------------------------------
extern "C" void kernel_launch(void* const* d_in, const int* in_sizes, int n_in,
                              void* d_out, int out_size, void* d_ws, size_t ws_size,
                              hipStream_t stream) {
  const float* hs_f   = (const float*)d_in[1];
  const float* Wqa_f  = (const float*)d_in[2];
  const float* qln_f  = (const float*)d_in[3];
  const float* Wqb_f  = (const float*)d_in[4];
  const float* Wkva_f = (const float*)d_in[5];
  const float* kvln_f = (const float*)d_in[6];
  const float* Wkvb_f = (const float*)d_in[7];
  const float* Wo_f   = (const float*)d_in[8];

  bf16* base = (bf16*)d_ws;
  // [0, 12582912): hs_c + wqaT + wkvaT-head (all dead after gemmA) | q overlay
  bf16* hs_c  = base;                       // 8,388,608
  bf16* wqaT  = base + 8388608;             // 3,145,728
  bf16* wkvaT = base + 11534336;            // 1,179,648 (ends 12,713,984)
  bf16* q     = base;                       // 12,582,912 overlay (gemm_dual+)
  bf16* ckq   = base + 12713984;            // 6,291,456 (dead after gemm_dual)
  bf16* qln_c = base + 19005440;            // 1536
  bf16* kvln_c= base + 19006976;            // 512   (ends 19,007,488)
  bf16* attnb = base + 12713984;            // 8,388,608 overlay over ckq+ln (attn+)
  bf16* wqbT  = base + 21102592;            // 4,718,592
  bf16* wkvbT = base + 25821184;            // 2,097,152
  bf16* woT   = base + 27918336;            // 4,194,304 (alive till gemmW)
  bf16* kvns  = base + 32112640;            // 2,621,440
  bf16* Kf    = base + 34734080;            // 12,582,912
  bf16* Vt    = base + 47316992;            // 8,388,608 (ends 55,705,600 = 111.4 MB)

  // 1) mega-prep: all conversions + all weight transposes
  prep_all<<<7841, 256, 0, stream>>>(hs_f, hs_c, qln_f, qln_c, kvln_f, kvln_c,
                                     Wqa_f, wqaT, Wkva_f, wkvaT,
                                     Wqb_f, wqbT, Wkvb_f, wkvbT, Wo_f, woT);
  // 2) fused: [ckq | kvns] = hs @ [Wqa | Wkva]  (N=2176, split at 1536)
  gemm_v4<false><<<dim3(17, 32), 256, 0, stream>>>(hs_c, wqaT, ckq, 2176, 2048,
                                                   2048, 2048, 1536, kvns, 1536);
  // 3) rmsnorms + fused k_pe rope -> Kf
  rms_pe_dual<<<8192, 256, 0, stream>>>(ckq, qln_c, kvns, kvln_c, Kf);
  // 4) merged: q = ckq@WqbT (over dead hs/wqaT/wkvaT) | {Kf, Vt} = kvns@WkvbT
  gemm_dual<<<1792, 256, 0, stream>>>(ckq, wqbT, q, kvns, wkvbT, Kf, Vt);
  // 5) attention (Ks double-buffered)
  attn_v7<<<512, 256, 0, stream>>>(q, Kf, Vt, attnb);
  // 6) out = attn @ Wo (f32 output)
  gemm_v4<true><<<dim3(16, 32), 256, 0, stream>>>(attnb, woT, d_out, 2048, 2048,
                                                  2048, 2048, 2048, nullptr, 0);
}